// Round 4
// baseline (282.349 us; speedup 1.0000x reference)
//
#include <hip/hip_runtime.h>
#include <hip/hip_bf16.h>
#include <math.h>

#define HW 4096

typedef short bf16x8_t __attribute__((ext_vector_type(8)));   // 8 bf16 (4 VGPRs)
typedef float f32x16_t __attribute__((ext_vector_type(16)));
typedef unsigned int u32;
typedef unsigned int u32x4_t __attribute__((ext_vector_type(4)));

union castu { u32x4_t u; bf16x8_t s; };

static __device__ __forceinline__ unsigned short f2bf(float f){
    union { __bf16 b; unsigned short u; } c; c.b = (__bf16)f; return c.u;
}
static __device__ __forceinline__ u32 pk2(float lo, float hi){
    return ((u32)f2bf(hi) << 16) | (u32)f2bf(lo);
}
static __device__ __forceinline__ bf16x8_t ldb(const unsigned short* p){
    return *reinterpret_cast<const bf16x8_t*>(p);
}
static __device__ __forceinline__ f32x16_t mfma32(bf16x8_t a, bf16x8_t b, f32x16_t c){
    return __builtin_amdgcn_mfma_f32_32x32x16_bf16(a, b, c, 0, 0, 0);
}

// ---------------- K1: front 3x3 convs ----------------------------------------
__global__ __launch_bounds__(256) void k_front(
    const float* __restrict__ x, const float* __restrict__ y,
    const float* __restrict__ conv_w, const float* __restrict__ conv_b,
    const float* __restrict__ c132_w, const float* __restrict__ c132_b,
    float* __restrict__ x1, float* __restrict__ x2)
{
    int pix = blockIdx.x * 256 + threadIdx.x;
    int oc = blockIdx.y;
    int b  = blockIdx.z;
    int h = pix >> 6, w = pix & 63;

    bool hv[3] = {h > 0, true, h < 63};
    bool wv[3] = {w > 0, true, w < 63};
    int  hh[3] = {h - 1, h, h + 1};
    int  wwI[3] = {w - 1, w, w + 1};

    const float* yb = y + b * HW;
    float yw[3][3];
    #pragma unroll
    for (int dy = 0; dy < 3; ++dy)
    #pragma unroll
    for (int dx = 0; dx < 3; ++dx)
        yw[dy][dx] = (hv[dy] && wv[dx]) ? yb[hh[dy] * 64 + wwI[dx]] : 0.f;

    float acc  = conv_b[oc];
    float acc2 = c132_b[oc];
    const float* wb = conv_w + oc * 40 * 9;
    const float* w2 = c132_w + oc * 9;

    #pragma unroll
    for (int t = 0; t < 9; ++t){
        float wy = 0.f;
        #pragma unroll
        for (int g = 0; g < 8; ++g) wy += wb[(5 * g + 4) * 9 + t];
        float yv = yw[t / 3][t % 3];
        acc  += wy * yv;
        acc2 += w2[t] * yv;
    }

    const float* xb = x + b * 32 * HW;
    for (int ic = 0; ic < 32; ++ic){
        const float* xc = xb + ic * HW;
        const float* wc = wb + (5 * (ic >> 2) + (ic & 3)) * 9;
        #pragma unroll
        for (int dy = 0; dy < 3; ++dy)
        #pragma unroll
        for (int dx = 0; dx < 3; ++dx){
            float xv = (hv[dy] && wv[dx]) ? xc[hh[dy] * 64 + wwI[dx]] : 0.f;
            acc = fmaf(wc[dy * 3 + dx], xv, acc);
        }
    }
    int o = (b * 32 + oc) * HW + pix;
    x1[o] = acc > 0.f ? acc : 0.f;
    x2[o] = acc2;
}

// ---------------- K2: six 1x1 projections ------------------------------------
__global__ __launch_bounds__(256) void k_proj(
    const float* __restrict__ x1, const float* __restrict__ x2,
    const float* __restrict__ q1w, const float* __restrict__ q1b,
    const float* __restrict__ k1w, const float* __restrict__ k1b,
    const float* __restrict__ q2w, const float* __restrict__ q2b,
    const float* __restrict__ k2w, const float* __restrict__ k2b,
    const float* __restrict__ q3w, const float* __restrict__ q3b,
    const float* __restrict__ k3w, const float* __restrict__ k3b,
    float* __restrict__ K1, float* __restrict__ Q2, float* __restrict__ YQ,
    unsigned short* __restrict__ Q1t, unsigned short* __restrict__ K2t,
    unsigned short* __restrict__ YKt)
{
    int tid = blockIdx.x * 256 + threadIdx.x;   // 0..32767
    int b = tid >> 12, m = tid & 4095;
    float v1[32], v2[32];
    const float* p1 = x1 + b * 32 * HW + m;
    const float* p2 = x2 + b * 32 * HW + m;
    #pragma unroll
    for (int c = 0; c < 32; ++c){ v1[c] = p1[c * HW]; v2[c] = p2[c * HW]; }

    unsigned short* q1p = Q1t + (size_t)tid * 32;
    unsigned short* k2p = K2t + (size_t)tid * 32;
    unsigned short* ykp = YKt + (size_t)tid * 32;

    for (int oc = 0; oc < 32; ++oc){
        float aq1 = q1b[oc], ak1 = k1b[oc], aq2 = q2b[oc];
        float ak2 = k2b[oc], aq3 = q3b[oc], ak3 = k3b[oc];
        #pragma unroll
        for (int c = 0; c < 32; ++c){
            float v = v1[c], u = v2[c];
            aq1 = fmaf(q1w[oc * 32 + c], v, aq1);
            ak1 = fmaf(k1w[oc * 32 + c], v, ak1);
            aq2 = fmaf(q2w[oc * 32 + c], v, aq2);
            ak2 = fmaf(k2w[oc * 32 + c], v, ak2);
            aq3 = fmaf(q3w[oc * 32 + c], u, aq3);
            ak3 = fmaf(k3w[oc * 32 + c], u, ak3);
        }
        int o = (b * 32 + oc) * HW + m;
        K1[o] = ak1; Q2[o] = aq2; YQ[o] = aq3;
        q1p[oc] = f2bf(aq1);
        k2p[oc] = f2bf(ak2);
        ykp[oc] = f2bf(ak3);
    }
}

// ---------------- K3: channel attention partial sums -------------------------
__global__ __launch_bounds__(256) void k_chan_part(
    const float* __restrict__ K1, const float* __restrict__ Q2,
    float* __restrict__ Scp)
{
    __shared__ float k1s[128 * 33];
    __shared__ float q2s[128 * 33];
    int chunk = blockIdx.x;     // 0..31, 128 n each
    int b = blockIdx.y;
    int n0 = chunk * 128;
    int t = threadIdx.x;
    for (int i = 0; i < 16; ++i){
        int idx = i * 256 + t;
        int c = idx >> 7, nl = idx & 127;
        k1s[nl * 33 + c] = K1[(b * 32 + c) * HW + n0 + nl];
        q2s[nl * 33 + c] = Q2[(b * 32 + c) * HW + n0 + nl];
    }
    __syncthreads();
    float acc[4] = {0.f, 0.f, 0.f, 0.f};
    int d = t & 31, c0 = t >> 5;
    for (int nl = 0; nl < 128; ++nl){
        float qv = q2s[nl * 33 + d];
        #pragma unroll
        for (int i = 0; i < 4; ++i)
            acc[i] = fmaf(k1s[nl * 33 + c0 + 8 * i], qv, acc[i]);
    }
    #pragma unroll
    for (int i = 0; i < 4; ++i)
        Scp[(b * 32 + chunk) * 1024 + (c0 + 8 * i) * 32 + d] = acc[i];
}

// ---------------- K4: channel softmax + fold conv6 W2 into M2 ----------------
__global__ __launch_bounds__(1024) void k_chan_fin(
    const float* __restrict__ Scp, const float* __restrict__ c6w,
    float* __restrict__ M2)
{
    __shared__ float pc[32 * 33];
    int b = blockIdx.x;
    int t = threadIdx.x;
    int c = t >> 5, d = t & 31;
    float s = 0.f;
    for (int k = 0; k < 32; ++k) s += Scp[(b * 32 + k) * 1024 + t];
    float mx = s;
    #pragma unroll
    for (int off = 16; off >= 1; off >>= 1) mx = fmaxf(mx, __shfl_xor(mx, off));
    float e = __expf(s - mx);
    float sum = e;
    #pragma unroll
    for (int off = 16; off >= 1; off >>= 1) sum += __shfl_xor(sum, off);
    pc[c * 33 + d] = e / sum;
    __syncthreads();
    int o = t >> 5, cc = t & 31;
    float m2 = 0.f;
    #pragma unroll
    for (int dd = 0; dd < 32; ++dd)
        m2 = fmaf(c6w[o * 64 + 32 + dd], pc[cc * 33 + dd], m2);
    M2[b * 1024 + o * 32 + cc] = m2;
}

// ---------------- K5: MFMA stats pass: l[n] = sum_m exp(S[n,m]) --------------
__global__ __launch_bounds__(256) void k_stats_mfma(
    const unsigned short* __restrict__ Q1t, const unsigned short* __restrict__ K2t,
    float* __restrict__ lsum)
{
    __shared__ float red[4][16][64];
    int t = threadIdx.x, wid = t >> 6, lane = t & 63;
    int l31 = lane & 31, h = lane >> 5;
    int b = blockIdx.x >> 7, ntile = blockIdx.x & 127;
    int n0 = ntile * 32;
    const unsigned short* q = Q1t + (size_t)b * 131072;
    const unsigned short* k = K2t + (size_t)b * 131072;
    // A-frags (fixed): A[row n][k c]; row = lane&31, k = 8*(lane>>5)+i
    bf16x8_t a0 = ldb(q + (size_t)(n0 + l31) * 32 + 8 * h);
    bf16x8_t a1 = ldb(q + (size_t)(n0 + l31) * 32 + 16 + 8 * h);
    float accl[16];
    #pragma unroll
    for (int r = 0; r < 16; ++r) accl[r] = 0.f;
    for (int mt = wid * 32; mt < wid * 32 + 32; ++mt){
        const unsigned short* kp = k + ((size_t)mt * 32 + l31) * 32 + 8 * h;
        bf16x8_t b0 = ldb(kp);
        bf16x8_t b1 = ldb(kp + 16);
        f32x16_t s;
        #pragma unroll
        for (int r = 0; r < 16; ++r) s[r] = 0.f;
        s = mfma32(a0, b0, s);
        s = mfma32(a1, b1, s);
        #pragma unroll
        for (int r = 0; r < 16; ++r) accl[r] += __expf(s[r]);
    }
    #pragma unroll
    for (int r = 0; r < 16; ++r) red[wid][r][lane] = accl[r];
    __syncthreads();
    if (wid != 0) return;
    #pragma unroll
    for (int r = 0; r < 16; ++r){
        float v = red[0][r][lane] + red[1][r][lane] + red[2][r][lane] + red[3][r][lane];
        #pragma unroll
        for (int off = 16; off >= 1; off >>= 1) v += __shfl_xor(v, off);
        if (l31 == 0)
            lsum[b * HW + n0 + (r & 3) + 8 * (r >> 2) + 4 * h] = v;
    }
}

// ---------------- K6: scale YQ by 1/l, emit bf16 ------------------------------
__global__ __launch_bounds__(256) void k_scale(
    const float* __restrict__ YQ, const float* __restrict__ lsum,
    unsigned short* __restrict__ YQ2)
{
    int tid = blockIdx.x * 256 + threadIdx.x;     // 0..262143
    int base = tid * 4;
    int b = base >> 17;
    int n = base & 4095;
    const float4 yq = *(const float4*)(YQ + base);
    const float4 lv = *(const float4*)(lsum + b * HW + n);
    u32 lo = pk2(yq.x / lv.x, yq.y / lv.y);
    u32 hi = pk2(yq.z / lv.z, yq.w / lv.w);
    *(uint2*)(YQ2 + base) = make_uint2(lo, hi);
}

// ---------------- K7: MFMA value pass + conv6 + residual ----------------------
__global__ __launch_bounds__(256) void k_attn_mfma(
    const unsigned short* __restrict__ Q1t, const unsigned short* __restrict__ K2t,
    const unsigned short* __restrict__ YKt, const unsigned short* __restrict__ YQ2,
    const float* __restrict__ M2, const float* __restrict__ c6w, const float* __restrict__ c6b,
    const float* __restrict__ x, float* __restrict__ xout)
{
    __shared__ float red[4][16][64];
    int t = threadIdx.x, wid = t >> 6, lane = t & 63;
    int l31 = lane & 31, h = lane >> 5;
    int b = blockIdx.x >> 7, mtile = blockIdx.x & 127;
    int m0 = mtile * 32;
    size_t boff = (size_t)b * 131072;
    const unsigned short* qb = Q1t + boff;
    const unsigned short* kb = K2t + boff;
    const unsigned short* yqb = YQ2 + boff;

    // S B-frags (fixed per wave): B[k c][col m]; col = lane&31
    bf16x8_t kb0 = ldb(kb + (size_t)(m0 + l31) * 32 + 8 * h);
    bf16x8_t kb1 = ldb(kb + (size_t)(m0 + l31) * 32 + 16 + 8 * h);

    f32x16_t oacc;
    #pragma unroll
    for (int r = 0; r < 16; ++r) oacc[r] = 0.f;

    const unsigned short* yq_base = yqb + (size_t)l31 * HW + 8 * h;

    for (int nt = wid * 32; nt < wid * 32 + 32; ++nt){
        int n0 = nt * 32;
        // S A-frags: A[row n][k c]
        bf16x8_t a0 = ldb(qb + (size_t)(n0 + l31) * 32 + 8 * h);
        bf16x8_t a1 = ldb(qb + (size_t)(n0 + l31) * 32 + 16 + 8 * h);
        f32x16_t s;
        #pragma unroll
        for (int r = 0; r < 16; ++r) s[r] = 0.f;
        s = mfma32(a0, kb0, s);
        s = mfma32(a1, kb1, s);
        // E = exp(S); convert C/D layout -> B-frag layout (k = n)
        u32 P[8];
        #pragma unroll
        for (int tt = 0; tt < 8; ++tt)
            P[tt] = pk2(__expf(s[2 * tt]), __expf(s[2 * tt + 1]));
        u32 X[8];
        #pragma unroll
        for (int tt = 0; tt < 8; ++tt) X[tt] = (u32)__shfl_xor((int)P[tt], 32);
        castu e0, e1;
        e0.u = (u32x4_t){ h ? X[2] : P[0], h ? X[3] : P[1], h ? P[2] : X[0], h ? P[3] : X[1] };
        e1.u = (u32x4_t){ h ? X[6] : P[4], h ? X[7] : P[5], h ? P[6] : X[4], h ? P[7] : X[5] };
        // PV: out[c][m] += YQ2[c][n-chunk] * E[n-chunk][m]
        bf16x8_t ya0 = ldb(yq_base + n0);
        bf16x8_t ya1 = ldb(yq_base + n0 + 16);
        oacc = mfma32(ya0, e0.s, oacc);
        oacc = mfma32(ya1, e1.s, oacc);
    }
    #pragma unroll
    for (int r = 0; r < 16; ++r) red[wid][r][lane] = oacc[r];
    __syncthreads();
    if (wid != 0) return;
    #pragma unroll
    for (int r = 0; r < 16; ++r)
        oacc[r] = red[0][r][lane] + red[1][r][lane] + red[2][r][lane] + red[3][r][lane];

    // oacc = xy_hw[c rows(regs)][m cols(lanes)] -> B-frags (k = c)
    u32 P[8], X[8];
    #pragma unroll
    for (int tt = 0; tt < 8; ++tt) P[tt] = pk2(oacc[2 * tt], oacc[2 * tt + 1]);
    #pragma unroll
    for (int tt = 0; tt < 8; ++tt) X[tt] = (u32)__shfl_xor((int)P[tt], 32);
    castu xb0, xb1;
    xb0.u = (u32x4_t){ h ? X[2] : P[0], h ? X[3] : P[1], h ? P[2] : X[0], h ? P[3] : X[1] };
    xb1.u = (u32x4_t){ h ? X[6] : P[4], h ? X[7] : P[5], h ? P[6] : X[4], h ? P[7] : X[5] };

    // W1 A-frags: rows o = lane&31, k = c
    const float* w1p = c6w + l31 * 64;
    const float* m2p = M2 + b * 1024 + l31 * 32;
    int cb0 = 8 * h, cb1 = 16 + 8 * h;
    castu wa0, wa1, ma0, ma1;
    wa0.u = (u32x4_t){ pk2(w1p[cb0], w1p[cb0+1]), pk2(w1p[cb0+2], w1p[cb0+3]),
                       pk2(w1p[cb0+4], w1p[cb0+5]), pk2(w1p[cb0+6], w1p[cb0+7]) };
    wa1.u = (u32x4_t){ pk2(w1p[cb1], w1p[cb1+1]), pk2(w1p[cb1+2], w1p[cb1+3]),
                       pk2(w1p[cb1+4], w1p[cb1+5]), pk2(w1p[cb1+6], w1p[cb1+7]) };
    ma0.u = (u32x4_t){ pk2(m2p[cb0], m2p[cb0+1]), pk2(m2p[cb0+2], m2p[cb0+3]),
                       pk2(m2p[cb0+4], m2p[cb0+5]), pk2(m2p[cb0+6], m2p[cb0+7]) };
    ma1.u = (u32x4_t){ pk2(m2p[cb1], m2p[cb1+1]), pk2(m2p[cb1+2], m2p[cb1+3]),
                       pk2(m2p[cb1+4], m2p[cb1+5]), pk2(m2p[cb1+6], m2p[cb1+7]) };
    // YK B-frags: col m = lane&31, k = c
    const unsigned short* ykp = YKt + boff + (size_t)(m0 + l31) * 32;
    bf16x8_t ykb0 = ldb(ykp + 8 * h);
    bf16x8_t ykb1 = ldb(ykp + 16 + 8 * h);

    f32x16_t facc;
    #pragma unroll
    for (int r = 0; r < 16; ++r) facc[r] = c6b[(r & 3) + 8 * (r >> 2) + 4 * h];
    facc = mfma32(wa0.s, xb0.s, facc);
    facc = mfma32(wa1.s, xb1.s, facc);
    facc = mfma32(ma0.s, ykb0, facc);
    facc = mfma32(ma1.s, ykb1, facc);

    #pragma unroll
    for (int r = 0; r < 16; ++r){
        int o = (r & 3) + 8 * (r >> 2) + 4 * h;
        size_t gi = ((size_t)(b * 32 + o) << 12) + m0 + l31;
        xout[gi] = x[gi] + facc[r];
    }
}

// ---------------- K8: score conv + residual on y ------------------------------
__global__ __launch_bounds__(256) void k_score(
    const float* __restrict__ xout, const float* __restrict__ y,
    const float* __restrict__ sw, const float* __restrict__ sb,
    float* __restrict__ yout)
{
    int tid = blockIdx.x * 256 + threadIdx.x;  // 0..32767
    int b = tid >> 12, pix = tid & 4095;
    int h = pix >> 6, w = pix & 63;
    bool hv[3] = {h > 0, true, h < 63};
    bool wv[3] = {w > 0, true, w < 63};
    int  hh[3] = {h - 1, h, h + 1};
    int  wwI[3] = {w - 1, w, w + 1};
    float acc = sb[0];
    const float* xb = xout + b * 32 * HW;
    for (int c = 0; c < 32; ++c){
        const float* xc = xb + c * HW;
        const float* wc = sw + c * 9;
        #pragma unroll
        for (int dy = 0; dy < 3; ++dy)
        #pragma unroll
        for (int dx = 0; dx < 3; ++dx){
            float v = (hv[dy] && wv[dx]) ? xc[hh[dy] * 64 + wwI[dx]] : 0.f;
            acc = fmaf(wc[dy * 3 + dx], v, acc);
        }
    }
    yout[tid] = y[tid] + acc;
}

extern "C" void kernel_launch(void* const* d_in, const int* in_sizes, int n_in,
                              void* d_out, int out_size, void* d_ws, size_t ws_size,
                              hipStream_t stream)
{
    (void)in_sizes; (void)n_in; (void)out_size; (void)ws_size;
    const float* x      = (const float*)d_in[0];
    const float* y      = (const float*)d_in[1];
    const float* conv_w = (const float*)d_in[2];
    const float* conv_b = (const float*)d_in[3];
    const float* score_w= (const float*)d_in[4];
    const float* score_b= (const float*)d_in[5];
    const float* c132_w = (const float*)d_in[6];
    const float* c132_b = (const float*)d_in[7];
    const float* q1w = (const float*)d_in[8];  const float* q1b = (const float*)d_in[9];
    const float* k1w = (const float*)d_in[10]; const float* k1b = (const float*)d_in[11];
    const float* q2w = (const float*)d_in[12]; const float* q2b = (const float*)d_in[13];
    const float* k2w = (const float*)d_in[14]; const float* k2b = (const float*)d_in[15];
    const float* q3w = (const float*)d_in[16]; const float* q3b = (const float*)d_in[17];
    const float* k3w = (const float*)d_in[18]; const float* k3b = (const float*)d_in[19];
    const float* c6w = (const float*)d_in[20]; const float* c6b = (const float*)d_in[21];

    float* ws = (float*)d_ws;
    const size_t SZ = 1048576;            // 8*32*4096
    float* x1  = ws;                      // 1M f32
    float* x2  = ws + SZ;                 // 1M f32
    float* K1  = ws + 2 * SZ;             // 1M f32
    float* Q2  = ws + 3 * SZ;             // 1M f32
    float* YQf = ws + 4 * SZ;             // 1M f32
    unsigned short* Q1t = (unsigned short*)(ws + 5 * SZ);            // 1M bf16
    unsigned short* K2t = (unsigned short*)(ws + 5 * SZ + SZ / 2);   // 1M bf16
    unsigned short* YKt = (unsigned short*)(ws + 6 * SZ);            // 1M bf16
    unsigned short* YQ2 = (unsigned short*)(ws + 6 * SZ + SZ / 2);   // 1M bf16
    float* lsum = ws + 7 * SZ;            // 32768 f32
    // aliases (x1 dead after k_proj)
    float* Scp = x1;                      // 262144 f32
    float* M2  = x1 + 262144;             // 8192 f32

    float* xout = (float*)d_out;
    float* yout = xout + SZ;

    k_front<<<dim3(16, 32, 8), 256, 0, stream>>>(x, y, conv_w, conv_b, c132_w, c132_b, x1, x2);
    k_proj<<<128, 256, 0, stream>>>(x1, x2, q1w, q1b, k1w, k1b, q2w, q2b, k2w, k2b,
                                    q3w, q3b, k3w, k3b, K1, Q2, YQf, Q1t, K2t, YKt);
    k_chan_part<<<dim3(32, 8), 256, 0, stream>>>(K1, Q2, Scp);
    k_chan_fin<<<8, 1024, 0, stream>>>(Scp, c6w, M2);
    k_stats_mfma<<<1024, 256, 0, stream>>>(Q1t, K2t, lsum);
    k_scale<<<1024, 256, 0, stream>>>(YQf, lsum, YQ2);
    k_attn_mfma<<<1024, 256, 0, stream>>>(Q1t, K2t, YKt, YQ2, M2, c6w, c6b, x, xout);
    k_score<<<128, 256, 0, stream>>>(xout, y, score_w, score_b, yout);
}

// Round 5
// 281.356 us; speedup vs baseline: 1.0035x; 1.0035x over previous
//
#include <hip/hip_runtime.h>
#include <hip/hip_bf16.h>
#include <math.h>

#define HW 4096

typedef short bf16x8_t __attribute__((ext_vector_type(8)));   // 8 bf16 (4 VGPRs)
typedef float f32x16_t __attribute__((ext_vector_type(16)));
typedef unsigned int u32;
typedef unsigned int u32x4_t __attribute__((ext_vector_type(4)));

union castu { u32x4_t u; bf16x8_t s; };

static __device__ __forceinline__ unsigned short f2bf(float f){
    union { __bf16 b; unsigned short u; } c; c.b = (__bf16)f; return c.u;
}
static __device__ __forceinline__ u32 pk2(float lo, float hi){
    return ((u32)f2bf(hi) << 16) | (u32)f2bf(lo);
}
static __device__ __forceinline__ bf16x8_t ldb(const unsigned short* p){
    return *reinterpret_cast<const bf16x8_t*>(p);
}
static __device__ __forceinline__ f32x16_t mfma32(bf16x8_t a, bf16x8_t b, f32x16_t c){
    return __builtin_amdgcn_mfma_f32_32x32x16_bf16(a, b, c, 0, 0, 0);
}

// ---------------- K1: front 3x3 convs ----------------------------------------
__global__ __launch_bounds__(256) void k_front(
    const float* __restrict__ x, const float* __restrict__ y,
    const float* __restrict__ conv_w, const float* __restrict__ conv_b,
    const float* __restrict__ c132_w, const float* __restrict__ c132_b,
    float* __restrict__ x1, float* __restrict__ x2)
{
    int pix = blockIdx.x * 256 + threadIdx.x;
    int oc = blockIdx.y;
    int b  = blockIdx.z;
    int h = pix >> 6, w = pix & 63;

    bool hv[3] = {h > 0, true, h < 63};
    bool wv[3] = {w > 0, true, w < 63};
    int  hh[3] = {h - 1, h, h + 1};
    int  wwI[3] = {w - 1, w, w + 1};

    const float* yb = y + b * HW;
    float yw[3][3];
    #pragma unroll
    for (int dy = 0; dy < 3; ++dy)
    #pragma unroll
    for (int dx = 0; dx < 3; ++dx)
        yw[dy][dx] = (hv[dy] && wv[dx]) ? yb[hh[dy] * 64 + wwI[dx]] : 0.f;

    float acc  = conv_b[oc];
    float acc2 = c132_b[oc];
    const float* wb = conv_w + oc * 40 * 9;
    const float* w2 = c132_w + oc * 9;

    #pragma unroll
    for (int t = 0; t < 9; ++t){
        float wy = 0.f;
        #pragma unroll
        for (int g = 0; g < 8; ++g) wy += wb[(5 * g + 4) * 9 + t];
        float yv = yw[t / 3][t % 3];
        acc  += wy * yv;
        acc2 += w2[t] * yv;
    }

    const float* xb = x + b * 32 * HW;
    for (int ic = 0; ic < 32; ++ic){
        const float* xc = xb + ic * HW;
        const float* wc = wb + (5 * (ic >> 2) + (ic & 3)) * 9;
        #pragma unroll
        for (int dy = 0; dy < 3; ++dy)
        #pragma unroll
        for (int dx = 0; dx < 3; ++dx){
            float xv = (hv[dy] && wv[dx]) ? xc[hh[dy] * 64 + wwI[dx]] : 0.f;
            acc = fmaf(wc[dy * 3 + dx], xv, acc);
        }
    }
    int o = (b * 32 + oc) * HW + pix;
    x1[o] = acc > 0.f ? acc : 0.f;
    x2[o] = acc2;
}

// ---------------- K2: six 1x1 projections ------------------------------------
__global__ __launch_bounds__(256) void k_proj(
    const float* __restrict__ x1, const float* __restrict__ x2,
    const float* __restrict__ q1w, const float* __restrict__ q1b,
    const float* __restrict__ k1w, const float* __restrict__ k1b,
    const float* __restrict__ q2w, const float* __restrict__ q2b,
    const float* __restrict__ k2w, const float* __restrict__ k2b,
    const float* __restrict__ q3w, const float* __restrict__ q3b,
    const float* __restrict__ k3w, const float* __restrict__ k3b,
    float* __restrict__ K1, float* __restrict__ Q2, float* __restrict__ YQ,
    unsigned short* __restrict__ Q1t, unsigned short* __restrict__ K2t,
    unsigned short* __restrict__ YKt)
{
    int tid = blockIdx.x * 256 + threadIdx.x;   // 0..32767
    int b = tid >> 12, m = tid & 4095;
    float v1[32], v2[32];
    const float* p1 = x1 + b * 32 * HW + m;
    const float* p2 = x2 + b * 32 * HW + m;
    #pragma unroll
    for (int c = 0; c < 32; ++c){ v1[c] = p1[c * HW]; v2[c] = p2[c * HW]; }

    unsigned short* q1p = Q1t + (size_t)tid * 32;
    unsigned short* k2p = K2t + (size_t)tid * 32;
    unsigned short* ykp = YKt + (size_t)tid * 32;

    for (int oc = 0; oc < 32; ++oc){
        float aq1 = q1b[oc], ak1 = k1b[oc], aq2 = q2b[oc];
        float ak2 = k2b[oc], aq3 = q3b[oc], ak3 = k3b[oc];
        #pragma unroll
        for (int c = 0; c < 32; ++c){
            float v = v1[c], u = v2[c];
            aq1 = fmaf(q1w[oc * 32 + c], v, aq1);
            ak1 = fmaf(k1w[oc * 32 + c], v, ak1);
            aq2 = fmaf(q2w[oc * 32 + c], v, aq2);
            ak2 = fmaf(k2w[oc * 32 + c], v, ak2);
            aq3 = fmaf(q3w[oc * 32 + c], u, aq3);
            ak3 = fmaf(k3w[oc * 32 + c], u, ak3);
        }
        int o = (b * 32 + oc) * HW + m;
        K1[o] = ak1; Q2[o] = aq2; YQ[o] = aq3;
        q1p[oc] = f2bf(aq1);
        k2p[oc] = f2bf(ak2);
        ykp[oc] = f2bf(ak3);
    }
}

// ---------------- K3: channel attention partial sums -------------------------
__global__ __launch_bounds__(256) void k_chan_part(
    const float* __restrict__ K1, const float* __restrict__ Q2,
    float* __restrict__ Scp)
{
    __shared__ float k1s[128 * 33];
    __shared__ float q2s[128 * 33];
    int chunk = blockIdx.x;     // 0..31, 128 n each
    int b = blockIdx.y;
    int n0 = chunk * 128;
    int t = threadIdx.x;
    for (int i = 0; i < 16; ++i){
        int idx = i * 256 + t;
        int c = idx >> 7, nl = idx & 127;
        k1s[nl * 33 + c] = K1[(b * 32 + c) * HW + n0 + nl];
        q2s[nl * 33 + c] = Q2[(b * 32 + c) * HW + n0 + nl];
    }
    __syncthreads();
    float acc[4] = {0.f, 0.f, 0.f, 0.f};
    int d = t & 31, c0 = t >> 5;
    for (int nl = 0; nl < 128; ++nl){
        float qv = q2s[nl * 33 + d];
        #pragma unroll
        for (int i = 0; i < 4; ++i)
            acc[i] = fmaf(k1s[nl * 33 + c0 + 8 * i], qv, acc[i]);
    }
    #pragma unroll
    for (int i = 0; i < 4; ++i)
        Scp[(b * 32 + chunk) * 1024 + (c0 + 8 * i) * 32 + d] = acc[i];
}

// ---------------- K4: channel softmax + fold conv6 W2 into M2 ----------------
__global__ __launch_bounds__(1024) void k_chan_fin(
    const float* __restrict__ Scp, const float* __restrict__ c6w,
    float* __restrict__ M2)
{
    __shared__ float pc[32 * 33];
    int b = blockIdx.x;
    int t = threadIdx.x;
    int c = t >> 5, d = t & 31;
    float s = 0.f;
    for (int k = 0; k < 32; ++k) s += Scp[(b * 32 + k) * 1024 + t];
    float mx = s;
    #pragma unroll
    for (int off = 16; off >= 1; off >>= 1) mx = fmaxf(mx, __shfl_xor(mx, off));
    float e = __expf(s - mx);
    float sum = e;
    #pragma unroll
    for (int off = 16; off >= 1; off >>= 1) sum += __shfl_xor(sum, off);
    pc[c * 33 + d] = e / sum;
    __syncthreads();
    int o = t >> 5, cc = t & 31;
    float m2 = 0.f;
    #pragma unroll
    for (int dd = 0; dd < 32; ++dd)
        m2 = fmaf(c6w[o * 64 + 32 + dd], pc[cc * 33 + dd], m2);
    M2[b * 1024 + o * 32 + cc] = m2;
}

// ---------------- K5: MFMA stats pass: l[n] = sum_m exp(S[n,m]) --------------
__global__ __launch_bounds__(256) void k_stats_mfma(
    const unsigned short* __restrict__ Q1t, const unsigned short* __restrict__ K2t,
    float* __restrict__ lsum)
{
    __shared__ float red[4][16][64];
    int t = threadIdx.x, wid = t >> 6, lane = t & 63;
    int l31 = lane & 31, h = lane >> 5;
    int b = blockIdx.x >> 7, ntile = blockIdx.x & 127;
    int n0 = ntile * 32;
    const unsigned short* q = Q1t + (size_t)b * 131072;
    const unsigned short* k = K2t + (size_t)b * 131072;
    // A-frags (fixed): A[row n][k c]; row = lane&31, k = 8*(lane>>5)+i
    bf16x8_t a0 = ldb(q + (size_t)(n0 + l31) * 32 + 8 * h);
    bf16x8_t a1 = ldb(q + (size_t)(n0 + l31) * 32 + 16 + 8 * h);
    float accl[16];
    #pragma unroll
    for (int r = 0; r < 16; ++r) accl[r] = 0.f;
    for (int mt = wid * 32; mt < wid * 32 + 32; ++mt){
        const unsigned short* kp = k + ((size_t)mt * 32 + l31) * 32 + 8 * h;
        bf16x8_t b0 = ldb(kp);
        bf16x8_t b1 = ldb(kp + 16);
        f32x16_t s;
        #pragma unroll
        for (int r = 0; r < 16; ++r) s[r] = 0.f;
        s = mfma32(a0, b0, s);
        s = mfma32(a1, b1, s);
        #pragma unroll
        for (int r = 0; r < 16; ++r) accl[r] += __expf(s[r]);
    }
    #pragma unroll
    for (int r = 0; r < 16; ++r) red[wid][r][lane] = accl[r];
    __syncthreads();
    if (wid != 0) return;
    #pragma unroll
    for (int r = 0; r < 16; ++r){
        float v = red[0][r][lane] + red[1][r][lane] + red[2][r][lane] + red[3][r][lane];
        #pragma unroll
        for (int off = 16; off >= 1; off >>= 1) v += __shfl_xor(v, off);
        if (l31 == 0)
            lsum[b * HW + n0 + (r & 3) + 8 * (r >> 2) + 4 * h] = v;
    }
}

// ---------------- K6: scale YQ by 1/l, emit bf16 ------------------------------
__global__ __launch_bounds__(256) void k_scale(
    const float* __restrict__ YQ, const float* __restrict__ lsum,
    unsigned short* __restrict__ YQ2)
{
    int tid = blockIdx.x * 256 + threadIdx.x;     // 0..262143
    int base = tid * 4;
    int b = base >> 17;
    int n = base & 4095;
    const float4 yq = *(const float4*)(YQ + base);
    const float4 lv = *(const float4*)(lsum + b * HW + n);
    u32 lo = pk2(yq.x / lv.x, yq.y / lv.y);
    u32 hi = pk2(yq.z / lv.z, yq.w / lv.w);
    *(uint2*)(YQ2 + base) = make_uint2(lo, hi);
}

// ---------------- K7: MFMA value pass + conv6 + residual ----------------------
__global__ __launch_bounds__(256) void k_attn_mfma(
    const unsigned short* __restrict__ Q1t, const unsigned short* __restrict__ K2t,
    const unsigned short* __restrict__ YKt, const unsigned short* __restrict__ YQ2,
    const float* __restrict__ M2, const float* __restrict__ c6w, const float* __restrict__ c6b,
    const float* __restrict__ x, float* __restrict__ xout)
{
    __shared__ float red[4][16][64];
    int t = threadIdx.x, wid = t >> 6, lane = t & 63;
    int l31 = lane & 31, h = lane >> 5;
    int b = blockIdx.x >> 7, mtile = blockIdx.x & 127;
    int m0 = mtile * 32;
    size_t boff = (size_t)b * 131072;
    const unsigned short* qb = Q1t + boff;
    const unsigned short* kb = K2t + boff;
    const unsigned short* yqb = YQ2 + boff;

    // S B-frags (fixed per wave): B[k c][col m]; col = lane&31
    bf16x8_t kb0 = ldb(kb + (size_t)(m0 + l31) * 32 + 8 * h);
    bf16x8_t kb1 = ldb(kb + (size_t)(m0 + l31) * 32 + 16 + 8 * h);

    f32x16_t oacc;
    #pragma unroll
    for (int r = 0; r < 16; ++r) oacc[r] = 0.f;

    const unsigned short* yq_base = yqb + (size_t)l31 * HW + 8 * h;

    for (int nt = wid * 32; nt < wid * 32 + 32; ++nt){
        int n0 = nt * 32;
        // S A-frags: A[row n][k c]
        bf16x8_t a0 = ldb(qb + (size_t)(n0 + l31) * 32 + 8 * h);
        bf16x8_t a1 = ldb(qb + (size_t)(n0 + l31) * 32 + 16 + 8 * h);
        f32x16_t s;
        #pragma unroll
        for (int r = 0; r < 16; ++r) s[r] = 0.f;
        s = mfma32(a0, kb0, s);
        s = mfma32(a1, kb1, s);
        // E = exp(S); convert C/D layout -> B-frag layout (k = n)
        u32 P[8];
        #pragma unroll
        for (int tt = 0; tt < 8; ++tt)
            P[tt] = pk2(__expf(s[2 * tt]), __expf(s[2 * tt + 1]));
        u32 X[8];
        #pragma unroll
        for (int tt = 0; tt < 8; ++tt) X[tt] = (u32)__shfl_xor((int)P[tt], 32);
        castu e0, e1;
        e0.u = (u32x4_t){ h ? X[2] : P[0], h ? X[3] : P[1], h ? P[2] : X[0], h ? P[3] : X[1] };
        e1.u = (u32x4_t){ h ? X[6] : P[4], h ? X[7] : P[5], h ? P[6] : X[4], h ? P[7] : X[5] };
        // PV: out[c][m] += YQ2[c][n-chunk] * E[n-chunk][m]
        bf16x8_t ya0 = ldb(yq_base + n0);
        bf16x8_t ya1 = ldb(yq_base + n0 + 16);
        oacc = mfma32(ya0, e0.s, oacc);
        oacc = mfma32(ya1, e1.s, oacc);
    }
    #pragma unroll
    for (int r = 0; r < 16; ++r) red[wid][r][lane] = oacc[r];
    __syncthreads();
    if (wid != 0) return;
    #pragma unroll
    for (int r = 0; r < 16; ++r)
        oacc[r] = red[0][r][lane] + red[1][r][lane] + red[2][r][lane] + red[3][r][lane];

    // oacc = xy_hw[c rows(regs)][m cols(lanes)] -> B-frags (k = c)
    u32 P[8], X[8];
    #pragma unroll
    for (int tt = 0; tt < 8; ++tt) P[tt] = pk2(oacc[2 * tt], oacc[2 * tt + 1]);
    #pragma unroll
    for (int tt = 0; tt < 8; ++tt) X[tt] = (u32)__shfl_xor((int)P[tt], 32);
    castu xb0, xb1;
    xb0.u = (u32x4_t){ h ? X[2] : P[0], h ? X[3] : P[1], h ? P[2] : X[0], h ? P[3] : X[1] };
    xb1.u = (u32x4_t){ h ? X[6] : P[4], h ? X[7] : P[5], h ? P[6] : X[4], h ? P[7] : X[5] };

    // W1 A-frags: rows o = lane&31, k = c
    const float* w1p = c6w + l31 * 64;
    const float* m2p = M2 + b * 1024 + l31 * 32;
    int cb0 = 8 * h, cb1 = 16 + 8 * h;
    castu wa0, wa1, ma0, ma1;
    wa0.u = (u32x4_t){ pk2(w1p[cb0], w1p[cb0+1]), pk2(w1p[cb0+2], w1p[cb0+3]),
                       pk2(w1p[cb0+4], w1p[cb0+5]), pk2(w1p[cb0+6], w1p[cb0+7]) };
    wa1.u = (u32x4_t){ pk2(w1p[cb1], w1p[cb1+1]), pk2(w1p[cb1+2], w1p[cb1+3]),
                       pk2(w1p[cb1+4], w1p[cb1+5]), pk2(w1p[cb1+6], w1p[cb1+7]) };
    ma0.u = (u32x4_t){ pk2(m2p[cb0], m2p[cb0+1]), pk2(m2p[cb0+2], m2p[cb0+3]),
                       pk2(m2p[cb0+4], m2p[cb0+5]), pk2(m2p[cb0+6], m2p[cb0+7]) };
    ma1.u = (u32x4_t){ pk2(m2p[cb1], m2p[cb1+1]), pk2(m2p[cb1+2], m2p[cb1+3]),
                       pk2(m2p[cb1+4], m2p[cb1+5]), pk2(m2p[cb1+6], m2p[cb1+7]) };
    // YK B-frags: col m = lane&31, k = c
    const unsigned short* ykp = YKt + boff + (size_t)(m0 + l31) * 32;
    bf16x8_t ykb0 = ldb(ykp + 8 * h);
    bf16x8_t ykb1 = ldb(ykp + 16 + 8 * h);

    f32x16_t facc;
    #pragma unroll
    for (int r = 0; r < 16; ++r) facc[r] = c6b[(r & 3) + 8 * (r >> 2) + 4 * h];
    facc = mfma32(wa0.s, xb0.s, facc);
    facc = mfma32(wa1.s, xb1.s, facc);
    facc = mfma32(ma0.s, ykb0, facc);
    facc = mfma32(ma1.s, ykb1, facc);

    #pragma unroll
    for (int r = 0; r < 16; ++r){
        int o = (r & 3) + 8 * (r >> 2) + 4 * h;
        size_t gi = ((size_t)(b * 32 + o) << 12) + m0 + l31;
        xout[gi] = x[gi] + facc[r];
    }
}

// ---------------- K8: score conv + residual on y ------------------------------
__global__ __launch_bounds__(256) void k_score(
    const float* __restrict__ xout, const float* __restrict__ y,
    const float* __restrict__ sw, const float* __restrict__ sb,
    float* __restrict__ yout)
{
    int tid = blockIdx.x * 256 + threadIdx.x;  // 0..32767
    int b = tid >> 12, pix = tid & 4095;
    int h = pix >> 6, w = pix & 63;
    bool hv[3] = {h > 0, true, h < 63};
    bool wv[3] = {w > 0, true, w < 63};
    int  hh[3] = {h - 1, h, h + 1};
    int  wwI[3] = {w - 1, w, w + 1};
    float acc = sb[0];
    const float* xb = xout + b * 32 * HW;
    for (int c = 0; c < 32; ++c){
        const float* xc = xb + c * HW;
        const float* wc = sw + c * 9;
        #pragma unroll
        for (int dy = 0; dy < 3; ++dy)
        #pragma unroll
        for (int dx = 0; dx < 3; ++dx){
            float v = (hv[dy] && wv[dx]) ? xc[hh[dy] * 64 + wwI[dx]] : 0.f;
            acc = fmaf(wc[dy * 3 + dx], v, acc);
        }
    }
    yout[tid] = y[tid] + acc;
}

extern "C" void kernel_launch(void* const* d_in, const int* in_sizes, int n_in,
                              void* d_out, int out_size, void* d_ws, size_t ws_size,
                              hipStream_t stream)
{
    (void)in_sizes; (void)n_in; (void)out_size; (void)ws_size;
    const float* x      = (const float*)d_in[0];
    const float* y      = (const float*)d_in[1];
    const float* conv_w = (const float*)d_in[2];
    const float* conv_b = (const float*)d_in[3];
    const float* score_w= (const float*)d_in[4];
    const float* score_b= (const float*)d_in[5];
    const float* c132_w = (const float*)d_in[6];
    const float* c132_b = (const float*)d_in[7];
    const float* q1w = (const float*)d_in[8];  const float* q1b = (const float*)d_in[9];
    const float* k1w = (const float*)d_in[10]; const float* k1b = (const float*)d_in[11];
    const float* q2w = (const float*)d_in[12]; const float* q2b = (const float*)d_in[13];
    const float* k2w = (const float*)d_in[14]; const float* k2b = (const float*)d_in[15];
    const float* q3w = (const float*)d_in[16]; const float* q3b = (const float*)d_in[17];
    const float* k3w = (const float*)d_in[18]; const float* k3b = (const float*)d_in[19];
    const float* c6w = (const float*)d_in[20]; const float* c6b = (const float*)d_in[21];

    float* ws = (float*)d_ws;
    const size_t SZ = 1048576;            // 8*32*4096
    float* x1  = ws;                      // 1M f32
    float* x2  = ws + SZ;                 // 1M f32
    float* K1  = ws + 2 * SZ;             // 1M f32
    float* Q2  = ws + 3 * SZ;             // 1M f32
    float* YQf = ws + 4 * SZ;             // 1M f32
    unsigned short* Q1t = (unsigned short*)(ws + 5 * SZ);            // 1M bf16
    unsigned short* K2t = (unsigned short*)(ws + 5 * SZ + SZ / 2);   // 1M bf16
    unsigned short* YKt = (unsigned short*)(ws + 6 * SZ);            // 1M bf16
    unsigned short* YQ2 = (unsigned short*)(ws + 6 * SZ + SZ / 2);   // 1M bf16
    float* lsum = ws + 7 * SZ;            // 32768 f32
    // aliases (x1 dead after k_proj)
    float* Scp = x1;                      // 262144 f32
    float* M2  = x1 + 262144;             // 8192 f32

    float* xout = (float*)d_out;
    float* yout = xout + SZ;

    k_front<<<dim3(16, 32, 8), 256, 0, stream>>>(x, y, conv_w, conv_b, c132_w, c132_b, x1, x2);
    k_proj<<<128, 256, 0, stream>>>(x1, x2, q1w, q1b, k1w, k1b, q2w, q2b, k2w, k2b,
                                    q3w, q3b, k3w, k3b, K1, Q2, YQf, Q1t, K2t, YKt);
    k_chan_part<<<dim3(32, 8), 256, 0, stream>>>(K1, Q2, Scp);
    k_chan_fin<<<8, 1024, 0, stream>>>(Scp, c6w, M2);
    k_stats_mfma<<<1024, 256, 0, stream>>>(Q1t, K2t, lsum);
    k_scale<<<1024, 256, 0, stream>>>(YQf, lsum, YQ2);
    k_attn_mfma<<<1024, 256, 0, stream>>>(Q1t, K2t, YKt, YQ2, M2, c6w, c6b, x, xout);
    k_score<<<128, 256, 0, stream>>>(xout, y, score_w, score_b, yout);
}

// Round 6
// 186.365 us; speedup vs baseline: 1.5150x; 1.5097x over previous
//
#include <hip/hip_runtime.h>
#include <hip/hip_bf16.h>
#include <math.h>

#define HW 4096

typedef short bf16x8_t __attribute__((ext_vector_type(8)));   // 8 bf16 (4 VGPRs)
typedef float f32x16_t __attribute__((ext_vector_type(16)));
typedef unsigned int u32;
typedef unsigned int u32x4_t __attribute__((ext_vector_type(4)));

union castu { u32x4_t u; bf16x8_t s; };

static __device__ __forceinline__ unsigned short f2bf(float f){
    union { __bf16 b; unsigned short u; } c; c.b = (__bf16)f; return c.u;
}
static __device__ __forceinline__ u32 pk2(float lo, float hi){
    return ((u32)f2bf(hi) << 16) | (u32)f2bf(lo);
}
static __device__ __forceinline__ bf16x8_t ldb(const unsigned short* p){
    return *reinterpret_cast<const bf16x8_t*>(p);
}
static __device__ __forceinline__ f32x16_t mfma32(bf16x8_t a, bf16x8_t b, f32x16_t c){
    return __builtin_amdgcn_mfma_f32_32x32x16_bf16(a, b, c, 0, 0, 0);
}

// ---------------- K1: fused front convs + six 1x1 projections ----------------
__global__ __launch_bounds__(256) void k_front_proj(
    const float* __restrict__ x, const float* __restrict__ y,
    const float* __restrict__ conv_w, const float* __restrict__ conv_b,
    const float* __restrict__ c132_w, const float* __restrict__ c132_b,
    const float* __restrict__ q1w, const float* __restrict__ q1b,
    const float* __restrict__ k1w, const float* __restrict__ k1b,
    const float* __restrict__ q2w, const float* __restrict__ q2b,
    const float* __restrict__ k2w, const float* __restrict__ k2b,
    const float* __restrict__ q3w, const float* __restrict__ q3b,
    const float* __restrict__ k3w, const float* __restrict__ k3b,
    float* __restrict__ K1, float* __restrict__ Q2, float* __restrict__ YQ,
    unsigned short* __restrict__ Q1t, unsigned short* __restrict__ K2t,
    unsigned short* __restrict__ YKt)
{
    __shared__ float xs[3][32][66];   // [dr][ic][1+w], zero borders
    __shared__ float ys[3][66];
    __shared__ float wyl[32][9];      // summed y-weights of conv40
    __shared__ float x1s[32][64];
    __shared__ float x2s[32][64];
    int tid = threadIdx.x;
    int h = blockIdx.x, b = blockIdx.y;

    for (int i = 0; i < 24; ++i){
        int idx = i * 256 + tid;
        int w = idx & 63, ic = (idx >> 6) & 31, dr = idx >> 11;
        int hr = h + dr - 1;
        xs[dr][ic][1 + w] = (hr >= 0 && hr < 64) ? x[((b * 32 + ic) << 12) + (hr << 6) + w] : 0.f;
    }
    if (tid < 192){
        int dr = tid >> 6, w = tid & 63;
        int hr = h + dr - 1;
        ys[dr][1 + w] = (hr >= 0 && hr < 64) ? y[(b << 12) + (hr << 6) + w] : 0.f;
    }
    if (tid < 96){ xs[tid >> 5][tid & 31][0] = 0.f; }
    else if (tid < 192){ int u = tid - 96; xs[u >> 5][u & 31][65] = 0.f; }
    if (tid < 3){ ys[tid][0] = 0.f; ys[tid][65] = 0.f; }
    for (int idx = tid; idx < 288; idx += 256){
        int oc = idx / 9, tap = idx - oc * 9;
        float s = 0.f;
        #pragma unroll
        for (int g = 0; g < 8; ++g) s += conv_w[oc * 360 + (5 * g + 4) * 9 + tap];
        wyl[oc][tap] = s;
    }
    __syncthreads();

    int w = tid & 63, oc0 = (tid >> 6) * 8;

    float acc1[8], acc2[8];
    #pragma unroll
    for (int o = 0; o < 8; ++o){ acc1[o] = conv_b[oc0 + o]; acc2[o] = c132_b[oc0 + o]; }
    #pragma unroll
    for (int tap = 0; tap < 9; ++tap){
        float yv = ys[tap / 3][w + tap % 3];
        #pragma unroll
        for (int o = 0; o < 8; ++o){
            acc1[o] = fmaf(wyl[oc0 + o][tap], yv, acc1[o]);
            acc2[o] = fmaf(c132_w[(oc0 + o) * 9 + tap], yv, acc2[o]);
        }
    }
    #pragma unroll 2
    for (int ic = 0; ic < 32; ++ic){
        int icoff = 5 * (ic >> 2) + (ic & 3);
        #pragma unroll
        for (int tap = 0; tap < 9; ++tap){
            float xv = xs[tap / 3][ic][w + tap % 3];
            #pragma unroll
            for (int o = 0; o < 8; ++o)
                acc1[o] = fmaf(conv_w[(oc0 + o) * 360 + icoff * 9 + tap], xv, acc1[o]);
        }
    }
    #pragma unroll
    for (int o = 0; o < 8; ++o){
        x1s[oc0 + o][w] = acc1[o] > 0.f ? acc1[o] : 0.f;
        x2s[oc0 + o][w] = acc2[o];
    }
    __syncthreads();

    float v1r[32], v2r[32];
    #pragma unroll
    for (int ic = 0; ic < 32; ++ic){ v1r[ic] = x1s[ic][w]; v2r[ic] = x2s[ic][w]; }
    int px = (h << 6) + w;
    float r_q1[8], r_k2[8], r_k3[8];
    #pragma unroll
    for (int o = 0; o < 8; ++o){
        int oc = oc0 + o;
        float aq1 = q1b[oc], ak1 = k1b[oc], aq2 = q2b[oc];
        float ak2 = k2b[oc], aq3 = q3b[oc], ak3 = k3b[oc];
        #pragma unroll
        for (int ic = 0; ic < 32; ++ic){
            float v = v1r[ic], u = v2r[ic];
            aq1 = fmaf(q1w[oc * 32 + ic], v, aq1);
            ak1 = fmaf(k1w[oc * 32 + ic], v, ak1);
            aq2 = fmaf(q2w[oc * 32 + ic], v, aq2);
            ak2 = fmaf(k2w[oc * 32 + ic], v, ak2);
            aq3 = fmaf(q3w[oc * 32 + ic], u, aq3);
            ak3 = fmaf(k3w[oc * 32 + ic], u, ak3);
        }
        int go = (b * 32 + oc) * HW + px;
        K1[go] = ak1; Q2[go] = aq2; YQ[go] = aq3;
        r_q1[o] = aq1; r_k2[o] = ak2; r_k3[o] = ak3;
    }
    size_t pbase = ((size_t)b * HW + px) * 32 + oc0;
    u32x4_t vq1 = { pk2(r_q1[0], r_q1[1]), pk2(r_q1[2], r_q1[3]),
                    pk2(r_q1[4], r_q1[5]), pk2(r_q1[6], r_q1[7]) };
    u32x4_t vk2 = { pk2(r_k2[0], r_k2[1]), pk2(r_k2[2], r_k2[3]),
                    pk2(r_k2[4], r_k2[5]), pk2(r_k2[6], r_k2[7]) };
    u32x4_t vk3 = { pk2(r_k3[0], r_k3[1]), pk2(r_k3[2], r_k3[3]),
                    pk2(r_k3[4], r_k3[5]), pk2(r_k3[6], r_k3[7]) };
    *(u32x4_t*)(Q1t + pbase) = vq1;
    *(u32x4_t*)(K2t + pbase) = vk2;
    *(u32x4_t*)(YKt + pbase) = vk3;
}

// ---------------- K3: channel attention partial sums -------------------------
__global__ __launch_bounds__(256) void k_chan_part(
    const float* __restrict__ K1, const float* __restrict__ Q2,
    float* __restrict__ Scp)
{
    __shared__ float k1s[128 * 33];
    __shared__ float q2s[128 * 33];
    int chunk = blockIdx.x;
    int b = blockIdx.y;
    int n0 = chunk * 128;
    int t = threadIdx.x;
    for (int i = 0; i < 16; ++i){
        int idx = i * 256 + t;
        int c = idx >> 7, nl = idx & 127;
        k1s[nl * 33 + c] = K1[(b * 32 + c) * HW + n0 + nl];
        q2s[nl * 33 + c] = Q2[(b * 32 + c) * HW + n0 + nl];
    }
    __syncthreads();
    float acc[4] = {0.f, 0.f, 0.f, 0.f};
    int d = t & 31, c0 = t >> 5;
    for (int nl = 0; nl < 128; ++nl){
        float qv = q2s[nl * 33 + d];
        #pragma unroll
        for (int i = 0; i < 4; ++i)
            acc[i] = fmaf(k1s[nl * 33 + c0 + 8 * i], qv, acc[i]);
    }
    #pragma unroll
    for (int i = 0; i < 4; ++i)
        Scp[(b * 32 + chunk) * 1024 + (c0 + 8 * i) * 32 + d] = acc[i];
}

// ---------------- K4: channel softmax + fold conv6 W2 into M2 ----------------
__global__ __launch_bounds__(1024) void k_chan_fin(
    const float* __restrict__ Scp, const float* __restrict__ c6w,
    float* __restrict__ M2)
{
    __shared__ float pc[32 * 33];
    int b = blockIdx.x;
    int t = threadIdx.x;
    int c = t >> 5, d = t & 31;
    float s = 0.f;
    for (int k = 0; k < 32; ++k) s += Scp[(b * 32 + k) * 1024 + t];
    float mx = s;
    #pragma unroll
    for (int off = 16; off >= 1; off >>= 1) mx = fmaxf(mx, __shfl_xor(mx, off));
    float e = __expf(s - mx);
    float sum = e;
    #pragma unroll
    for (int off = 16; off >= 1; off >>= 1) sum += __shfl_xor(sum, off);
    pc[c * 33 + d] = e / sum;
    __syncthreads();
    int o = t >> 5, cc = t & 31;
    float m2 = 0.f;
    #pragma unroll
    for (int dd = 0; dd < 32; ++dd)
        m2 = fmaf(c6w[o * 64 + 32 + dd], pc[cc * 33 + dd], m2);
    M2[b * 1024 + o * 32 + cc] = m2;
}

// ---------------- K5: MFMA stats pass: l[n] = sum_m exp(S[n,m]) --------------
__global__ __launch_bounds__(256) void k_stats_mfma(
    const unsigned short* __restrict__ Q1t, const unsigned short* __restrict__ K2t,
    float* __restrict__ lsum)
{
    __shared__ float red[4][16][64];
    int t = threadIdx.x, wid = t >> 6, lane = t & 63;
    int l31 = lane & 31, h = lane >> 5;
    int b = blockIdx.x >> 7, ntile = blockIdx.x & 127;
    int n0 = ntile * 32;
    const unsigned short* q = Q1t + (size_t)b * 131072;
    const unsigned short* k = K2t + (size_t)b * 131072;
    bf16x8_t a0 = ldb(q + (size_t)(n0 + l31) * 32 + 8 * h);
    bf16x8_t a1 = ldb(q + (size_t)(n0 + l31) * 32 + 16 + 8 * h);
    float accl[16];
    #pragma unroll
    for (int r = 0; r < 16; ++r) accl[r] = 0.f;
    for (int mt = wid * 32; mt < wid * 32 + 32; ++mt){
        const unsigned short* kp = k + ((size_t)mt * 32 + l31) * 32 + 8 * h;
        bf16x8_t b0 = ldb(kp);
        bf16x8_t b1 = ldb(kp + 16);
        f32x16_t s;
        #pragma unroll
        for (int r = 0; r < 16; ++r) s[r] = 0.f;
        s = mfma32(a0, b0, s);
        s = mfma32(a1, b1, s);
        #pragma unroll
        for (int r = 0; r < 16; ++r) accl[r] += __expf(s[r]);
    }
    #pragma unroll
    for (int r = 0; r < 16; ++r) red[wid][r][lane] = accl[r];
    __syncthreads();
    if (wid != 0) return;
    #pragma unroll
    for (int r = 0; r < 16; ++r){
        float v = red[0][r][lane] + red[1][r][lane] + red[2][r][lane] + red[3][r][lane];
        #pragma unroll
        for (int off = 16; off >= 1; off >>= 1) v += __shfl_xor(v, off);
        if (l31 == 0)
            lsum[b * HW + n0 + (r & 3) + 8 * (r >> 2) + 4 * h] = v;
    }
}

// ---------------- K6: scale YQ by 1/l, emit bf16 ------------------------------
__global__ __launch_bounds__(256) void k_scale(
    const float* __restrict__ YQ, const float* __restrict__ lsum,
    unsigned short* __restrict__ YQ2)
{
    int tid = blockIdx.x * 256 + threadIdx.x;
    int base = tid * 4;
    int b = base >> 17;
    int n = base & 4095;
    const float4 yq = *(const float4*)(YQ + base);
    const float4 lv = *(const float4*)(lsum + b * HW + n);
    u32 lo = pk2(yq.x / lv.x, yq.y / lv.y);
    u32 hi = pk2(yq.z / lv.z, yq.w / lv.w);
    *(uint2*)(YQ2 + base) = make_uint2(lo, hi);
}

// ---------------- K7: MFMA value pass + conv6 + residual ----------------------
__global__ __launch_bounds__(256) void k_attn_mfma(
    const unsigned short* __restrict__ Q1t, const unsigned short* __restrict__ K2t,
    const unsigned short* __restrict__ YKt, const unsigned short* __restrict__ YQ2,
    const float* __restrict__ M2, const float* __restrict__ c6w, const float* __restrict__ c6b,
    const float* __restrict__ x, float* __restrict__ xout)
{
    __shared__ float red[4][16][64];
    int t = threadIdx.x, wid = t >> 6, lane = t & 63;
    int l31 = lane & 31, h = lane >> 5;
    int b = blockIdx.x >> 7, mtile = blockIdx.x & 127;
    int m0 = mtile * 32;
    size_t boff = (size_t)b * 131072;
    const unsigned short* qb = Q1t + boff;
    const unsigned short* kb = K2t + boff;
    const unsigned short* yqb = YQ2 + boff;

    bf16x8_t kb0 = ldb(kb + (size_t)(m0 + l31) * 32 + 8 * h);
    bf16x8_t kb1 = ldb(kb + (size_t)(m0 + l31) * 32 + 16 + 8 * h);

    f32x16_t oacc;
    #pragma unroll
    for (int r = 0; r < 16; ++r) oacc[r] = 0.f;

    const unsigned short* yq_base = yqb + (size_t)l31 * HW + 8 * h;

    for (int nt = wid * 32; nt < wid * 32 + 32; ++nt){
        int n0 = nt * 32;
        bf16x8_t a0 = ldb(qb + (size_t)(n0 + l31) * 32 + 8 * h);
        bf16x8_t a1 = ldb(qb + (size_t)(n0 + l31) * 32 + 16 + 8 * h);
        f32x16_t s;
        #pragma unroll
        for (int r = 0; r < 16; ++r) s[r] = 0.f;
        s = mfma32(a0, kb0, s);
        s = mfma32(a1, kb1, s);
        u32 P[8];
        #pragma unroll
        for (int tt = 0; tt < 8; ++tt)
            P[tt] = pk2(__expf(s[2 * tt]), __expf(s[2 * tt + 1]));
        u32 X[8];
        #pragma unroll
        for (int tt = 0; tt < 8; ++tt) X[tt] = (u32)__shfl_xor((int)P[tt], 32);
        castu e0, e1;
        e0.u = (u32x4_t){ h ? X[2] : P[0], h ? X[3] : P[1], h ? P[2] : X[0], h ? P[3] : X[1] };
        e1.u = (u32x4_t){ h ? X[6] : P[4], h ? X[7] : P[5], h ? P[6] : X[4], h ? P[7] : X[5] };
        bf16x8_t ya0 = ldb(yq_base + n0);
        bf16x8_t ya1 = ldb(yq_base + n0 + 16);
        oacc = mfma32(ya0, e0.s, oacc);
        oacc = mfma32(ya1, e1.s, oacc);
    }
    #pragma unroll
    for (int r = 0; r < 16; ++r) red[wid][r][lane] = oacc[r];
    __syncthreads();
    if (wid != 0) return;
    #pragma unroll
    for (int r = 0; r < 16; ++r)
        oacc[r] = red[0][r][lane] + red[1][r][lane] + red[2][r][lane] + red[3][r][lane];

    u32 P[8], X[8];
    #pragma unroll
    for (int tt = 0; tt < 8; ++tt) P[tt] = pk2(oacc[2 * tt], oacc[2 * tt + 1]);
    #pragma unroll
    for (int tt = 0; tt < 8; ++tt) X[tt] = (u32)__shfl_xor((int)P[tt], 32);
    castu xb0, xb1;
    xb0.u = (u32x4_t){ h ? X[2] : P[0], h ? X[3] : P[1], h ? P[2] : X[0], h ? P[3] : X[1] };
    xb1.u = (u32x4_t){ h ? X[6] : P[4], h ? X[7] : P[5], h ? P[6] : X[4], h ? P[7] : X[5] };

    const float* w1p = c6w + l31 * 64;
    const float* m2p = M2 + b * 1024 + l31 * 32;
    int cb0 = 8 * h, cb1 = 16 + 8 * h;
    castu wa0, wa1, ma0, ma1;
    wa0.u = (u32x4_t){ pk2(w1p[cb0], w1p[cb0+1]), pk2(w1p[cb0+2], w1p[cb0+3]),
                       pk2(w1p[cb0+4], w1p[cb0+5]), pk2(w1p[cb0+6], w1p[cb0+7]) };
    wa1.u = (u32x4_t){ pk2(w1p[cb1], w1p[cb1+1]), pk2(w1p[cb1+2], w1p[cb1+3]),
                       pk2(w1p[cb1+4], w1p[cb1+5]), pk2(w1p[cb1+6], w1p[cb1+7]) };
    ma0.u = (u32x4_t){ pk2(m2p[cb0], m2p[cb0+1]), pk2(m2p[cb0+2], m2p[cb0+3]),
                       pk2(m2p[cb0+4], m2p[cb0+5]), pk2(m2p[cb0+6], m2p[cb0+7]) };
    ma1.u = (u32x4_t){ pk2(m2p[cb1], m2p[cb1+1]), pk2(m2p[cb1+2], m2p[cb1+3]),
                       pk2(m2p[cb1+4], m2p[cb1+5]), pk2(m2p[cb1+6], m2p[cb1+7]) };
    const unsigned short* ykp = YKt + boff + (size_t)(m0 + l31) * 32;
    bf16x8_t ykb0 = ldb(ykp + 8 * h);
    bf16x8_t ykb1 = ldb(ykp + 16 + 8 * h);

    f32x16_t facc;
    #pragma unroll
    for (int r = 0; r < 16; ++r) facc[r] = c6b[(r & 3) + 8 * (r >> 2) + 4 * h];
    facc = mfma32(wa0.s, xb0.s, facc);
    facc = mfma32(wa1.s, xb1.s, facc);
    facc = mfma32(ma0.s, ykb0, facc);
    facc = mfma32(ma1.s, ykb1, facc);

    #pragma unroll
    for (int r = 0; r < 16; ++r){
        int o = (r & 3) + 8 * (r >> 2) + 4 * h;
        size_t gi = ((size_t)(b * 32 + o) << 12) + m0 + l31;
        xout[gi] = x[gi] + facc[r];
    }
}

// ---------------- K8: score conv + residual on y (LDS-staged) -----------------
__global__ __launch_bounds__(256) void k_score(
    const float* __restrict__ xout, const float* __restrict__ y,
    const float* __restrict__ sw, const float* __restrict__ sb,
    float* __restrict__ yout)
{
    __shared__ float xs[3][32][66];
    __shared__ float red[4][64];
    int tid = threadIdx.x;
    int h = blockIdx.x, b = blockIdx.y;
    for (int i = 0; i < 24; ++i){
        int idx = i * 256 + tid;
        int w = idx & 63, ic = (idx >> 6) & 31, dr = idx >> 11;
        int hr = h + dr - 1;
        xs[dr][ic][1 + w] = (hr >= 0 && hr < 64) ? xout[((b * 32 + ic) << 12) + (hr << 6) + w] : 0.f;
    }
    if (tid < 96){ xs[tid >> 5][tid & 31][0] = 0.f; }
    else if (tid < 192){ int u = tid - 96; xs[u >> 5][u & 31][65] = 0.f; }
    __syncthreads();
    int w = tid & 63, icg = tid >> 6;
    float p = 0.f;
    #pragma unroll
    for (int i = 0; i < 8; ++i){
        int ic = icg * 8 + i;
        #pragma unroll
        for (int tap = 0; tap < 9; ++tap)
            p = fmaf(sw[ic * 9 + tap], xs[tap / 3][ic][w + tap % 3], p);
    }
    red[icg][w] = p;
    __syncthreads();
    if (tid < 64){
        int px = (h << 6) + tid;
        yout[b * HW + px] = y[b * HW + px] + sb[0]
                          + red[0][tid] + red[1][tid] + red[2][tid] + red[3][tid];
    }
}

extern "C" void kernel_launch(void* const* d_in, const int* in_sizes, int n_in,
                              void* d_out, int out_size, void* d_ws, size_t ws_size,
                              hipStream_t stream)
{
    (void)in_sizes; (void)n_in; (void)out_size; (void)ws_size;
    const float* x      = (const float*)d_in[0];
    const float* y      = (const float*)d_in[1];
    const float* conv_w = (const float*)d_in[2];
    const float* conv_b = (const float*)d_in[3];
    const float* score_w= (const float*)d_in[4];
    const float* score_b= (const float*)d_in[5];
    const float* c132_w = (const float*)d_in[6];
    const float* c132_b = (const float*)d_in[7];
    const float* q1w = (const float*)d_in[8];  const float* q1b = (const float*)d_in[9];
    const float* k1w = (const float*)d_in[10]; const float* k1b = (const float*)d_in[11];
    const float* q2w = (const float*)d_in[12]; const float* q2b = (const float*)d_in[13];
    const float* k2w = (const float*)d_in[14]; const float* k2b = (const float*)d_in[15];
    const float* q3w = (const float*)d_in[16]; const float* q3b = (const float*)d_in[17];
    const float* k3w = (const float*)d_in[18]; const float* k3b = (const float*)d_in[19];
    const float* c6w = (const float*)d_in[20]; const float* c6b = (const float*)d_in[21];

    float* ws = (float*)d_ws;
    const size_t SZ = 1048576;            // 8*32*4096
    float* Scp = ws;                      // 262144 f32
    float* M2  = ws + 262144;             // 8192 f32
    float* K1  = ws + 2 * SZ;             // 1M f32
    float* Q2  = ws + 3 * SZ;             // 1M f32
    float* YQf = ws + 4 * SZ;             // 1M f32
    unsigned short* Q1t = (unsigned short*)(ws + 5 * SZ);            // 1M bf16
    unsigned short* K2t = (unsigned short*)(ws + 5 * SZ + SZ / 2);   // 1M bf16
    unsigned short* YKt = (unsigned short*)(ws + 6 * SZ);            // 1M bf16
    unsigned short* YQ2 = (unsigned short*)(ws + 6 * SZ + SZ / 2);   // 1M bf16
    float* lsum = ws + 7 * SZ;            // 32768 f32

    float* xout = (float*)d_out;
    float* yout = xout + SZ;

    k_front_proj<<<dim3(64, 8), 256, 0, stream>>>(
        x, y, conv_w, conv_b, c132_w, c132_b,
        q1w, q1b, k1w, k1b, q2w, q2b, k2w, k2b, q3w, q3b, k3w, k3b,
        K1, Q2, YQf, Q1t, K2t, YKt);
    k_chan_part<<<dim3(32, 8), 256, 0, stream>>>(K1, Q2, Scp);
    k_chan_fin<<<8, 1024, 0, stream>>>(Scp, c6w, M2);
    k_stats_mfma<<<1024, 256, 0, stream>>>(Q1t, K2t, lsum);
    k_scale<<<1024, 256, 0, stream>>>(YQf, lsum, YQ2);
    k_attn_mfma<<<1024, 256, 0, stream>>>(Q1t, K2t, YKt, YQ2, M2, c6w, c6b, x, xout);
    k_score<<<dim3(64, 8), 256, 0, stream>>>(xout, y, score_w, score_b, yout);
}

// Round 7
// 134.403 us; speedup vs baseline: 2.1008x; 1.3866x over previous
//
#include <hip/hip_runtime.h>
#include <hip/hip_bf16.h>
#include <math.h>

#define HW 4096

typedef short bf16x8_t __attribute__((ext_vector_type(8)));   // 8 bf16 (4 VGPRs)
typedef float f32x16_t __attribute__((ext_vector_type(16)));
typedef unsigned int u32;
typedef unsigned int u32x4_t __attribute__((ext_vector_type(4)));

union castu { u32x4_t u; bf16x8_t s; };

static __device__ __forceinline__ unsigned short f2bf(float f){
    union { __bf16 b; unsigned short u; } c; c.b = (__bf16)f; return c.u;
}
static __device__ __forceinline__ u32 pk2(float lo, float hi){
    return ((u32)f2bf(hi) << 16) | (u32)f2bf(lo);
}
static __device__ __forceinline__ bf16x8_t ldb(const unsigned short* p){
    return *reinterpret_cast<const bf16x8_t*>(p);
}
static __device__ __forceinline__ bf16x8_t ld_xs(const unsigned short* p){
    uint2 lo = *(const uint2*)(p);
    uint2 hi = *(const uint2*)(p + 4);
    castu c; c.u = (u32x4_t){lo.x, lo.y, hi.x, hi.y};
    return c.s;
}
static __device__ __forceinline__ f32x16_t mfma32(bf16x8_t a, bf16x8_t b, f32x16_t c){
    return __builtin_amdgcn_mfma_f32_32x32x16_bf16(a, b, c, 0, 0, 0);
}

// ---------------- K1: MFMA front convs + six 1x1 projections -----------------
// block = 2 rows (4 waves, 1 wave = 32-px tile); grid = (32 row-pairs, 8 b)
__global__ __launch_bounds__(256, 1) void k_front_mfma(
    const float* __restrict__ x, const float* __restrict__ y,
    const float* __restrict__ conv_w, const float* __restrict__ conv_b,
    const float* __restrict__ c132_w, const float* __restrict__ c132_b,
    const float* __restrict__ q1w, const float* __restrict__ q1b,
    const float* __restrict__ k1w, const float* __restrict__ k1b,
    const float* __restrict__ q2w, const float* __restrict__ q2b,
    const float* __restrict__ k2w, const float* __restrict__ k2b,
    const float* __restrict__ q3w, const float* __restrict__ q3b,
    const float* __restrict__ k3w, const float* __restrict__ k3b,
    float* __restrict__ K1, float* __restrict__ Q2, float* __restrict__ YQ,
    unsigned short* __restrict__ Q1t, unsigned short* __restrict__ K2t,
    unsigned short* __restrict__ YKt)
{
    // xs: [4 rows][68 wp][36 ic-stride] bf16 (wp = w+1, zero borders)
    __shared__ unsigned short xs[4 * 68 * 36];
    __shared__ float ys[4 * 68];
    __shared__ u32 wplane[18 * 4 * 64];   // conv A-frags: [t*2+j][word][lane]
    __shared__ u32 wyplane[4 * 64];       // summed-y-weight A-frag planes
    __shared__ u32 c1plane[4 * 64];       // c132 A-frag planes

    int tid = threadIdx.x;
    int h0 = blockIdx.x * 2, b = blockIdx.y;

    // ---- stage x window (rows h0-1..h0+2) as bf16, ic-contiguous ----
    #pragma unroll
    for (int i = 0; i < 32; ++i){
        int idx = i * 256 + tid;
        int w = idx & 63, ic = (idx >> 6) & 31, dr = idx >> 11;
        int hr = h0 - 1 + dr;
        float v = (hr >= 0 && hr < 64) ? x[((b * 32 + ic) << 12) + (hr << 6) + w] : 0.f;
        xs[(dr * 68 + w + 1) * 36 + ic] = f2bf(v);
    }
    { // zero w-borders (wp=0 and wp=65)
        int dr = tid >> 6, ic = tid & 31, side = (tid >> 5) & 1;
        xs[(dr * 68 + (side ? 65 : 0)) * 36 + ic] = 0;
    }
    // ---- stage y rows (f32, zero borders) ----
    for (int idx = tid; idx < 272; idx += 256){
        int dr = idx / 68, wp = idx % 68;
        int hr = h0 - 1 + dr, w = wp - 1;
        ys[idx] = (hr >= 0 && hr < 64 && w >= 0 && w < 64) ? y[(b << 12) + (hr << 6) + w] : 0.f;
    }
    // ---- pre-pack conv40 x-weight A-fragments into LDS planes ----
    for (int e = tid; e < 4608; e += 256){
        int f = e >> 8, wi = (e >> 6) & 3, ln = e & 63;
        int t = f >> 1, j = f & 1, hh = ln >> 5, ll = ln & 31;
        int ic0 = 16 * j + 8 * hh + 2 * wi;
        int co0 = 5 * (ic0 >> 2) + (ic0 & 3);
        int ic1 = ic0 + 1;
        int co1 = 5 * (ic1 >> 2) + (ic1 & 3);
        wplane[e] = pk2(conv_w[ll * 360 + co0 * 9 + t], conv_w[ll * 360 + co1 * 9 + t]);
    }
    // ---- pre-pack summed-y-weight + c132 A-fragments (k = tap, 9 used) ----
    {
        int wi = tid >> 6, ln = tid & 63, hh = ln >> 5, ll = ln & 31;
        u32 vy = 0, vc = 0;
        if (hh == 0){
            int t0 = 2 * wi, t1 = 2 * wi + 1;
            float s0 = 0.f, s1 = 0.f;
            #pragma unroll
            for (int g = 0; g < 8; ++g){
                s0 += conv_w[ll * 360 + (5 * g + 4) * 9 + t0];
                s1 += conv_w[ll * 360 + (5 * g + 4) * 9 + t1];
            }
            vy = pk2(s0, s1);
            vc = pk2(c132_w[ll * 9 + t0], c132_w[ll * 9 + t1]);
        } else if (wi == 0){
            float s0 = 0.f;
            #pragma unroll
            for (int g = 0; g < 8; ++g) s0 += conv_w[ll * 360 + (5 * g + 4) * 9 + 8];
            vy = pk2(s0, 0.f);
            vc = pk2(c132_w[ll * 9 + 8], 0.f);
        }
        wyplane[wi * 64 + ln] = vy;
        c1plane[wi * 64 + ln] = vc;
    }
    __syncthreads();

    int lane = tid & 63, wid = tid >> 6;
    int l31 = lane & 31, h = lane >> 5;
    int wr = wid >> 1, toff = (wid & 1) * 32;
    int wpB = toff + l31;

    // conv A-frags from planes (conflict-free b32 reads)
    bf16x8_t wA[18];
    #pragma unroll
    for (int f = 0; f < 18; ++f){
        castu c;
        c.u = (u32x4_t){ wplane[(f * 4 + 0) * 64 + lane], wplane[(f * 4 + 1) * 64 + lane],
                         wplane[(f * 4 + 2) * 64 + lane], wplane[(f * 4 + 3) * 64 + lane] };
        wA[f] = c.s;
    }
    castu wyf, c1f;
    wyf.u = (u32x4_t){ wyplane[lane], wyplane[64 + lane], wyplane[128 + lane], wyplane[192 + lane] };
    c1f.u = (u32x4_t){ c1plane[lane], c1plane[64 + lane], c1plane[128 + lane], c1plane[192 + lane] };

    // y-window B-frag (k = tap)
    float yv[8];
    #pragma unroll
    for (int i = 0; i < 8; ++i){
        int tt = 8 * h + i;
        yv[i] = (tt < 9) ? ys[(wr + tt / 3) * 68 + wpB + (tt % 3)] : 0.f;
    }
    castu yf;
    yf.u = (u32x4_t){ pk2(yv[0], yv[1]), pk2(yv[2], yv[3]), pk2(yv[4], yv[5]), pk2(yv[6], yv[7]) };

    // accumulators (C-layout row oc = (r&3)+8*(r>>2)+4h, col px = l31)
    f32x16_t accE, accO, accY, acc2;
    #pragma unroll
    for (int r = 0; r < 16; ++r){
        int oc = (r & 3) + 8 * (r >> 2) + 4 * h;
        accE[r] = 0.f; accO[r] = 0.f;
        accY[r] = conv_b[oc]; acc2[r] = c132_b[oc];
    }
    // conv40 x-part: 9 taps x 2 k-halves, two independent chains
    #pragma unroll
    for (int t = 0; t < 9; ++t){
        int base = ((wr + t / 3) * 68 + wpB + (t % 3)) * 36 + 8 * h;
        bf16x8_t b0 = ld_xs(xs + base);
        bf16x8_t b1 = ld_xs(xs + base + 16);
        if (t & 1){
            accO = mfma32(wA[t * 2 + 0], b0, accO);
            accO = mfma32(wA[t * 2 + 1], b1, accO);
        } else {
            accE = mfma32(wA[t * 2 + 0], b0, accE);
            accE = mfma32(wA[t * 2 + 1], b1, accE);
        }
    }
    accY = mfma32(wyf.s, yf.s, accY);   // conv40 y-part + bias
    acc2 = mfma32(c1f.s, yf.s, acc2);   // c132 conv + bias

    // x1 = relu(conv);  x1, x2 -> B-frags (k = channel) via pk2 + shfl trick
    f32x16_t x1v;
    #pragma unroll
    for (int r = 0; r < 16; ++r){
        float v = accE[r] + accO[r] + accY[r];
        x1v[r] = v > 0.f ? v : 0.f;
    }
    u32 P[8], X[8];
    #pragma unroll
    for (int t2 = 0; t2 < 8; ++t2) P[t2] = pk2(x1v[2 * t2], x1v[2 * t2 + 1]);
    #pragma unroll
    for (int t2 = 0; t2 < 8; ++t2) X[t2] = (u32)__shfl_xor((int)P[t2], 32);
    castu x1b0, x1b1;
    x1b0.u = (u32x4_t){ h ? X[2] : P[0], h ? X[3] : P[1], h ? P[2] : X[0], h ? P[3] : X[1] };
    x1b1.u = (u32x4_t){ h ? X[6] : P[4], h ? X[7] : P[5], h ? P[6] : X[4], h ? P[7] : X[5] };
    #pragma unroll
    for (int t2 = 0; t2 < 8; ++t2) P[t2] = pk2(acc2[2 * t2], acc2[2 * t2 + 1]);
    #pragma unroll
    for (int t2 = 0; t2 < 8; ++t2) X[t2] = (u32)__shfl_xor((int)P[t2], 32);
    castu x2b0, x2b1;
    x2b0.u = (u32x4_t){ h ? X[2] : P[0], h ? X[3] : P[1], h ? P[2] : X[0], h ? P[3] : X[1] };
    x2b1.u = (u32x4_t){ h ? X[6] : P[4], h ? X[7] : P[5], h ? P[6] : X[4], h ? P[7] : X[5] };

    int pxg = (h0 + wr) * 64 + toff + l31;
    size_t bf_base = ((size_t)b * HW + pxg) * 32;

    // q1 -> Q1t (bf16 pixel-major)
    {
        f32x16_t a;
        #pragma unroll
        for (int r = 0; r < 16; ++r) a[r] = q1b[(r & 3) + 8 * (r >> 2) + 4 * h];
        const float* p0 = q1w + l31 * 32 + 8 * h;
        castu w0, w1;
        w0.u = (u32x4_t){ pk2(p0[0],p0[1]), pk2(p0[2],p0[3]), pk2(p0[4],p0[5]), pk2(p0[6],p0[7]) };
        w1.u = (u32x4_t){ pk2(p0[16],p0[17]), pk2(p0[18],p0[19]), pk2(p0[20],p0[21]), pk2(p0[22],p0[23]) };
        a = mfma32(w0.s, x1b0.s, a);
        a = mfma32(w1.s, x1b1.s, a);
        u32 Q[8];
        #pragma unroll
        for (int t2 = 0; t2 < 8; ++t2) Q[t2] = pk2(a[2 * t2], a[2 * t2 + 1]);
        *(uint2*)(Q1t + bf_base + 4 * h)      = make_uint2(Q[0], Q[1]);
        *(uint2*)(Q1t + bf_base + 8 + 4 * h)  = make_uint2(Q[2], Q[3]);
        *(uint2*)(Q1t + bf_base + 16 + 4 * h) = make_uint2(Q[4], Q[5]);
        *(uint2*)(Q1t + bf_base + 24 + 4 * h) = make_uint2(Q[6], Q[7]);
    }
    // k1 -> K1 (f32 channel-major)
    {
        f32x16_t a;
        #pragma unroll
        for (int r = 0; r < 16; ++r) a[r] = k1b[(r & 3) + 8 * (r >> 2) + 4 * h];
        const float* p0 = k1w + l31 * 32 + 8 * h;
        castu w0, w1;
        w0.u = (u32x4_t){ pk2(p0[0],p0[1]), pk2(p0[2],p0[3]), pk2(p0[4],p0[5]), pk2(p0[6],p0[7]) };
        w1.u = (u32x4_t){ pk2(p0[16],p0[17]), pk2(p0[18],p0[19]), pk2(p0[20],p0[21]), pk2(p0[22],p0[23]) };
        a = mfma32(w0.s, x1b0.s, a);
        a = mfma32(w1.s, x1b1.s, a);
        #pragma unroll
        for (int r = 0; r < 16; ++r)
            K1[(b * 32 + (r & 3) + 8 * (r >> 2) + 4 * h) * HW + pxg] = a[r];
    }
    // q2 -> Q2 (f32 channel-major)
    {
        f32x16_t a;
        #pragma unroll
        for (int r = 0; r < 16; ++r) a[r] = q2b[(r & 3) + 8 * (r >> 2) + 4 * h];
        const float* p0 = q2w + l31 * 32 + 8 * h;
        castu w0, w1;
        w0.u = (u32x4_t){ pk2(p0[0],p0[1]), pk2(p0[2],p0[3]), pk2(p0[4],p0[5]), pk2(p0[6],p0[7]) };
        w1.u = (u32x4_t){ pk2(p0[16],p0[17]), pk2(p0[18],p0[19]), pk2(p0[20],p0[21]), pk2(p0[22],p0[23]) };
        a = mfma32(w0.s, x1b0.s, a);
        a = mfma32(w1.s, x1b1.s, a);
        #pragma unroll
        for (int r = 0; r < 16; ++r)
            Q2[(b * 32 + (r & 3) + 8 * (r >> 2) + 4 * h) * HW + pxg] = a[r];
    }
    // k2 -> K2t (bf16 pixel-major)
    {
        f32x16_t a;
        #pragma unroll
        for (int r = 0; r < 16; ++r) a[r] = k2b[(r & 3) + 8 * (r >> 2) + 4 * h];
        const float* p0 = k2w + l31 * 32 + 8 * h;
        castu w0, w1;
        w0.u = (u32x4_t){ pk2(p0[0],p0[1]), pk2(p0[2],p0[3]), pk2(p0[4],p0[5]), pk2(p0[6],p0[7]) };
        w1.u = (u32x4_t){ pk2(p0[16],p0[17]), pk2(p0[18],p0[19]), pk2(p0[20],p0[21]), pk2(p0[22],p0[23]) };
        a = mfma32(w0.s, x1b0.s, a);
        a = mfma32(w1.s, x1b1.s, a);
        u32 Q[8];
        #pragma unroll
        for (int t2 = 0; t2 < 8; ++t2) Q[t2] = pk2(a[2 * t2], a[2 * t2 + 1]);
        *(uint2*)(K2t + bf_base + 4 * h)      = make_uint2(Q[0], Q[1]);
        *(uint2*)(K2t + bf_base + 8 + 4 * h)  = make_uint2(Q[2], Q[3]);
        *(uint2*)(K2t + bf_base + 16 + 4 * h) = make_uint2(Q[4], Q[5]);
        *(uint2*)(K2t + bf_base + 24 + 4 * h) = make_uint2(Q[6], Q[7]);
    }
    // q3 (x2) -> YQ (f32 channel-major)
    {
        f32x16_t a;
        #pragma unroll
        for (int r = 0; r < 16; ++r) a[r] = q3b[(r & 3) + 8 * (r >> 2) + 4 * h];
        const float* p0 = q3w + l31 * 32 + 8 * h;
        castu w0, w1;
        w0.u = (u32x4_t){ pk2(p0[0],p0[1]), pk2(p0[2],p0[3]), pk2(p0[4],p0[5]), pk2(p0[6],p0[7]) };
        w1.u = (u32x4_t){ pk2(p0[16],p0[17]), pk2(p0[18],p0[19]), pk2(p0[20],p0[21]), pk2(p0[22],p0[23]) };
        a = mfma32(w0.s, x2b0.s, a);
        a = mfma32(w1.s, x2b1.s, a);
        #pragma unroll
        for (int r = 0; r < 16; ++r)
            YQ[(b * 32 + (r & 3) + 8 * (r >> 2) + 4 * h) * HW + pxg] = a[r];
    }
    // k3 (x2) -> YKt (bf16 pixel-major)
    {
        f32x16_t a;
        #pragma unroll
        for (int r = 0; r < 16; ++r) a[r] = k3b[(r & 3) + 8 * (r >> 2) + 4 * h];
        const float* p0 = k3w + l31 * 32 + 8 * h;
        castu w0, w1;
        w0.u = (u32x4_t){ pk2(p0[0],p0[1]), pk2(p0[2],p0[3]), pk2(p0[4],p0[5]), pk2(p0[6],p0[7]) };
        w1.u = (u32x4_t){ pk2(p0[16],p0[17]), pk2(p0[18],p0[19]), pk2(p0[20],p0[21]), pk2(p0[22],p0[23]) };
        a = mfma32(w0.s, x2b0.s, a);
        a = mfma32(w1.s, x2b1.s, a);
        u32 Q[8];
        #pragma unroll
        for (int t2 = 0; t2 < 8; ++t2) Q[t2] = pk2(a[2 * t2], a[2 * t2 + 1]);
        *(uint2*)(YKt + bf_base + 4 * h)      = make_uint2(Q[0], Q[1]);
        *(uint2*)(YKt + bf_base + 8 + 4 * h)  = make_uint2(Q[2], Q[3]);
        *(uint2*)(YKt + bf_base + 16 + 4 * h) = make_uint2(Q[4], Q[5]);
        *(uint2*)(YKt + bf_base + 24 + 4 * h) = make_uint2(Q[6], Q[7]);
    }
}

// ---------------- K3: channel attention partial sums -------------------------
__global__ __launch_bounds__(256) void k_chan_part(
    const float* __restrict__ K1, const float* __restrict__ Q2,
    float* __restrict__ Scp)
{
    __shared__ float k1s[128 * 33];
    __shared__ float q2s[128 * 33];
    int chunk = blockIdx.x;
    int b = blockIdx.y;
    int n0 = chunk * 128;
    int t = threadIdx.x;
    for (int i = 0; i < 16; ++i){
        int idx = i * 256 + t;
        int c = idx >> 7, nl = idx & 127;
        k1s[nl * 33 + c] = K1[(b * 32 + c) * HW + n0 + nl];
        q2s[nl * 33 + c] = Q2[(b * 32 + c) * HW + n0 + nl];
    }
    __syncthreads();
    float acc[4] = {0.f, 0.f, 0.f, 0.f};
    int d = t & 31, c0 = t >> 5;
    for (int nl = 0; nl < 128; ++nl){
        float qv = q2s[nl * 33 + d];
        #pragma unroll
        for (int i = 0; i < 4; ++i)
            acc[i] = fmaf(k1s[nl * 33 + c0 + 8 * i], qv, acc[i]);
    }
    #pragma unroll
    for (int i = 0; i < 4; ++i)
        Scp[(b * 32 + chunk) * 1024 + (c0 + 8 * i) * 32 + d] = acc[i];
}

// ---------------- K4: channel softmax + fold conv6 W2 into M2 ----------------
__global__ __launch_bounds__(1024) void k_chan_fin(
    const float* __restrict__ Scp, const float* __restrict__ c6w,
    float* __restrict__ M2)
{
    __shared__ float pc[32 * 33];
    int b = blockIdx.x;
    int t = threadIdx.x;
    int c = t >> 5, d = t & 31;
    float s = 0.f;
    for (int k = 0; k < 32; ++k) s += Scp[(b * 32 + k) * 1024 + t];
    float mx = s;
    #pragma unroll
    for (int off = 16; off >= 1; off >>= 1) mx = fmaxf(mx, __shfl_xor(mx, off));
    float e = __expf(s - mx);
    float sum = e;
    #pragma unroll
    for (int off = 16; off >= 1; off >>= 1) sum += __shfl_xor(sum, off);
    pc[c * 33 + d] = e / sum;
    __syncthreads();
    int o = t >> 5, cc = t & 31;
    float m2 = 0.f;
    #pragma unroll
    for (int dd = 0; dd < 32; ++dd)
        m2 = fmaf(c6w[o * 64 + 32 + dd], pc[cc * 33 + dd], m2);
    M2[b * 1024 + o * 32 + cc] = m2;
}

// ---------------- K5: MFMA stats pass: l[n] = sum_m exp(S[n,m]) --------------
__global__ __launch_bounds__(256) void k_stats_mfma(
    const unsigned short* __restrict__ Q1t, const unsigned short* __restrict__ K2t,
    float* __restrict__ lsum)
{
    __shared__ float red[4][16][64];
    int t = threadIdx.x, wid = t >> 6, lane = t & 63;
    int l31 = lane & 31, h = lane >> 5;
    int b = blockIdx.x >> 7, ntile = blockIdx.x & 127;
    int n0 = ntile * 32;
    const unsigned short* q = Q1t + (size_t)b * 131072;
    const unsigned short* k = K2t + (size_t)b * 131072;
    bf16x8_t a0 = ldb(q + (size_t)(n0 + l31) * 32 + 8 * h);
    bf16x8_t a1 = ldb(q + (size_t)(n0 + l31) * 32 + 16 + 8 * h);
    float accl[16];
    #pragma unroll
    for (int r = 0; r < 16; ++r) accl[r] = 0.f;
    for (int mt = wid * 32; mt < wid * 32 + 32; ++mt){
        const unsigned short* kp = k + ((size_t)mt * 32 + l31) * 32 + 8 * h;
        bf16x8_t b0 = ldb(kp);
        bf16x8_t b1 = ldb(kp + 16);
        f32x16_t s;
        #pragma unroll
        for (int r = 0; r < 16; ++r) s[r] = 0.f;
        s = mfma32(a0, b0, s);
        s = mfma32(a1, b1, s);
        #pragma unroll
        for (int r = 0; r < 16; ++r) accl[r] += __expf(s[r]);
    }
    #pragma unroll
    for (int r = 0; r < 16; ++r) red[wid][r][lane] = accl[r];
    __syncthreads();
    if (wid != 0) return;
    #pragma unroll
    for (int r = 0; r < 16; ++r){
        float v = red[0][r][lane] + red[1][r][lane] + red[2][r][lane] + red[3][r][lane];
        #pragma unroll
        for (int off = 16; off >= 1; off >>= 1) v += __shfl_xor(v, off);
        if (l31 == 0)
            lsum[b * HW + n0 + (r & 3) + 8 * (r >> 2) + 4 * h] = v;
    }
}

// ---------------- K6: scale YQ by 1/l, emit bf16 ------------------------------
__global__ __launch_bounds__(256) void k_scale(
    const float* __restrict__ YQ, const float* __restrict__ lsum,
    unsigned short* __restrict__ YQ2)
{
    int tid = blockIdx.x * 256 + threadIdx.x;
    int base = tid * 4;
    int b = base >> 17;
    int n = base & 4095;
    const float4 yq = *(const float4*)(YQ + base);
    const float4 lv = *(const float4*)(lsum + b * HW + n);
    u32 lo = pk2(yq.x / lv.x, yq.y / lv.y);
    u32 hi = pk2(yq.z / lv.z, yq.w / lv.w);
    *(uint2*)(YQ2 + base) = make_uint2(lo, hi);
}

// ---------------- K7: MFMA value pass + conv6 + residual ----------------------
__global__ __launch_bounds__(256) void k_attn_mfma(
    const unsigned short* __restrict__ Q1t, const unsigned short* __restrict__ K2t,
    const unsigned short* __restrict__ YKt, const unsigned short* __restrict__ YQ2,
    const float* __restrict__ M2, const float* __restrict__ c6w, const float* __restrict__ c6b,
    const float* __restrict__ x, float* __restrict__ xout)
{
    __shared__ float red[4][16][64];
    int t = threadIdx.x, wid = t >> 6, lane = t & 63;
    int l31 = lane & 31, h = lane >> 5;
    int b = blockIdx.x >> 7, mtile = blockIdx.x & 127;
    int m0 = mtile * 32;
    size_t boff = (size_t)b * 131072;
    const unsigned short* qb = Q1t + boff;
    const unsigned short* kb = K2t + boff;
    const unsigned short* yqb = YQ2 + boff;

    bf16x8_t kb0 = ldb(kb + (size_t)(m0 + l31) * 32 + 8 * h);
    bf16x8_t kb1 = ldb(kb + (size_t)(m0 + l31) * 32 + 16 + 8 * h);

    f32x16_t oacc;
    #pragma unroll
    for (int r = 0; r < 16; ++r) oacc[r] = 0.f;

    const unsigned short* yq_base = yqb + (size_t)l31 * HW + 8 * h;

    for (int nt = wid * 32; nt < wid * 32 + 32; ++nt){
        int n0 = nt * 32;
        bf16x8_t a0 = ldb(qb + (size_t)(n0 + l31) * 32 + 8 * h);
        bf16x8_t a1 = ldb(qb + (size_t)(n0 + l31) * 32 + 16 + 8 * h);
        f32x16_t s;
        #pragma unroll
        for (int r = 0; r < 16; ++r) s[r] = 0.f;
        s = mfma32(a0, kb0, s);
        s = mfma32(a1, kb1, s);
        u32 P[8];
        #pragma unroll
        for (int tt = 0; tt < 8; ++tt)
            P[tt] = pk2(__expf(s[2 * tt]), __expf(s[2 * tt + 1]));
        u32 X[8];
        #pragma unroll
        for (int tt = 0; tt < 8; ++tt) X[tt] = (u32)__shfl_xor((int)P[tt], 32);
        castu e0, e1;
        e0.u = (u32x4_t){ h ? X[2] : P[0], h ? X[3] : P[1], h ? P[2] : X[0], h ? P[3] : X[1] };
        e1.u = (u32x4_t){ h ? X[6] : P[4], h ? X[7] : P[5], h ? P[6] : X[4], h ? P[7] : X[5] };
        bf16x8_t ya0 = ldb(yq_base + n0);
        bf16x8_t ya1 = ldb(yq_base + n0 + 16);
        oacc = mfma32(ya0, e0.s, oacc);
        oacc = mfma32(ya1, e1.s, oacc);
    }
    #pragma unroll
    for (int r = 0; r < 16; ++r) red[wid][r][lane] = oacc[r];
    __syncthreads();
    if (wid != 0) return;
    #pragma unroll
    for (int r = 0; r < 16; ++r)
        oacc[r] = red[0][r][lane] + red[1][r][lane] + red[2][r][lane] + red[3][r][lane];

    u32 P[8], X[8];
    #pragma unroll
    for (int tt = 0; tt < 8; ++tt) P[tt] = pk2(oacc[2 * tt], oacc[2 * tt + 1]);
    #pragma unroll
    for (int tt = 0; tt < 8; ++tt) X[tt] = (u32)__shfl_xor((int)P[tt], 32);
    castu xb0, xb1;
    xb0.u = (u32x4_t){ h ? X[2] : P[0], h ? X[3] : P[1], h ? P[2] : X[0], h ? P[3] : X[1] };
    xb1.u = (u32x4_t){ h ? X[6] : P[4], h ? X[7] : P[5], h ? P[6] : X[4], h ? P[7] : X[5] };

    const float* w1p = c6w + l31 * 64;
    const float* m2p = M2 + b * 1024 + l31 * 32;
    int cb0 = 8 * h, cb1 = 16 + 8 * h;
    castu wa0, wa1, ma0, ma1;
    wa0.u = (u32x4_t){ pk2(w1p[cb0], w1p[cb0+1]), pk2(w1p[cb0+2], w1p[cb0+3]),
                       pk2(w1p[cb0+4], w1p[cb0+5]), pk2(w1p[cb0+6], w1p[cb0+7]) };
    wa1.u = (u32x4_t){ pk2(w1p[cb1], w1p[cb1+1]), pk2(w1p[cb1+2], w1p[cb1+3]),
                       pk2(w1p[cb1+4], w1p[cb1+5]), pk2(w1p[cb1+6], w1p[cb1+7]) };
    ma0.u = (u32x4_t){ pk2(m2p[cb0], m2p[cb0+1]), pk2(m2p[cb0+2], m2p[cb0+3]),
                       pk2(m2p[cb0+4], m2p[cb0+5]), pk2(m2p[cb0+6], m2p[cb0+7]) };
    ma1.u = (u32x4_t){ pk2(m2p[cb1], m2p[cb1+1]), pk2(m2p[cb1+2], m2p[cb1+3]),
                       pk2(m2p[cb1+4], m2p[cb1+5]), pk2(m2p[cb1+6], m2p[cb1+7]) };
    const unsigned short* ykp = YKt + boff + (size_t)(m0 + l31) * 32;
    bf16x8_t ykb0 = ldb(ykp + 8 * h);
    bf16x8_t ykb1 = ldb(ykp + 16 + 8 * h);

    f32x16_t facc;
    #pragma unroll
    for (int r = 0; r < 16; ++r) facc[r] = c6b[(r & 3) + 8 * (r >> 2) + 4 * h];
    facc = mfma32(wa0.s, xb0.s, facc);
    facc = mfma32(wa1.s, xb1.s, facc);
    facc = mfma32(ma0.s, ykb0, facc);
    facc = mfma32(ma1.s, ykb1, facc);

    #pragma unroll
    for (int r = 0; r < 16; ++r){
        int o = (r & 3) + 8 * (r >> 2) + 4 * h;
        size_t gi = ((size_t)(b * 32 + o) << 12) + m0 + l31;
        xout[gi] = x[gi] + facc[r];
    }
}

// ---------------- K8: score conv + residual on y (LDS-staged) -----------------
__global__ __launch_bounds__(256) void k_score(
    const float* __restrict__ xout, const float* __restrict__ y,
    const float* __restrict__ sw, const float* __restrict__ sb,
    float* __restrict__ yout)
{
    __shared__ float xs[3][32][66];
    __shared__ float red[4][64];
    int tid = threadIdx.x;
    int h = blockIdx.x, b = blockIdx.y;
    for (int i = 0; i < 24; ++i){
        int idx = i * 256 + tid;
        int w = idx & 63, ic = (idx >> 6) & 31, dr = idx >> 11;
        int hr = h + dr - 1;
        xs[dr][ic][1 + w] = (hr >= 0 && hr < 64) ? xout[((b * 32 + ic) << 12) + (hr << 6) + w] : 0.f;
    }
    if (tid < 96){ xs[tid >> 5][tid & 31][0] = 0.f; }
    else if (tid < 192){ int u = tid - 96; xs[u >> 5][u & 31][65] = 0.f; }
    __syncthreads();
    int w = tid & 63, icg = tid >> 6;
    float p = 0.f;
    #pragma unroll
    for (int i = 0; i < 8; ++i){
        int ic = icg * 8 + i;
        #pragma unroll
        for (int tap = 0; tap < 9; ++tap)
            p = fmaf(sw[ic * 9 + tap], xs[tap / 3][ic][w + tap % 3], p);
    }
    red[icg][w] = p;
    __syncthreads();
    if (tid < 64){
        int px = (h << 6) + tid;
        yout[b * HW + px] = y[b * HW + px] + sb[0]
                          + red[0][tid] + red[1][tid] + red[2][tid] + red[3][tid];
    }
}

extern "C" void kernel_launch(void* const* d_in, const int* in_sizes, int n_in,
                              void* d_out, int out_size, void* d_ws, size_t ws_size,
                              hipStream_t stream)
{
    (void)in_sizes; (void)n_in; (void)out_size; (void)ws_size;
    const float* x      = (const float*)d_in[0];
    const float* y      = (const float*)d_in[1];
    const float* conv_w = (const float*)d_in[2];
    const float* conv_b = (const float*)d_in[3];
    const float* score_w= (const float*)d_in[4];
    const float* score_b= (const float*)d_in[5];
    const float* c132_w = (const float*)d_in[6];
    const float* c132_b = (const float*)d_in[7];
    const float* q1w = (const float*)d_in[8];  const float* q1b = (const float*)d_in[9];
    const float* k1w = (const float*)d_in[10]; const float* k1b = (const float*)d_in[11];
    const float* q2w = (const float*)d_in[12]; const float* q2b = (const float*)d_in[13];
    const float* k2w = (const float*)d_in[14]; const float* k2b = (const float*)d_in[15];
    const float* q3w = (const float*)d_in[16]; const float* q3b = (const float*)d_in[17];
    const float* k3w = (const float*)d_in[18]; const float* k3b = (const float*)d_in[19];
    const float* c6w = (const float*)d_in[20]; const float* c6b = (const float*)d_in[21];

    float* ws = (float*)d_ws;
    const size_t SZ = 1048576;            // 8*32*4096
    float* Scp = ws;                      // 262144 f32
    float* M2  = ws + 262144;             // 8192 f32
    float* K1  = ws + 2 * SZ;             // 1M f32
    float* Q2  = ws + 3 * SZ;             // 1M f32
    float* YQf = ws + 4 * SZ;             // 1M f32
    unsigned short* Q1t = (unsigned short*)(ws + 5 * SZ);            // 1M bf16
    unsigned short* K2t = (unsigned short*)(ws + 5 * SZ + SZ / 2);   // 1M bf16
    unsigned short* YKt = (unsigned short*)(ws + 6 * SZ);            // 1M bf16
    unsigned short* YQ2 = (unsigned short*)(ws + 6 * SZ + SZ / 2);   // 1M bf16
    float* lsum = ws + 7 * SZ;            // 32768 f32

    float* xout = (float*)d_out;
    float* yout = xout + SZ;

    k_front_mfma<<<dim3(32, 8), 256, 0, stream>>>(
        x, y, conv_w, conv_b, c132_w, c132_b,
        q1w, q1b, k1w, k1b, q2w, q2b, k2w, k2b, q3w, q3b, k3w, k3b,
        K1, Q2, YQf, Q1t, K2t, YKt);
    k_chan_part<<<dim3(32, 8), 256, 0, stream>>>(K1, Q2, Scp);
    k_chan_fin<<<8, 1024, 0, stream>>>(Scp, c6w, M2);
    k_stats_mfma<<<1024, 256, 0, stream>>>(Q1t, K2t, lsum);
    k_scale<<<1024, 256, 0, stream>>>(YQf, lsum, YQ2);
    k_attn_mfma<<<1024, 256, 0, stream>>>(Q1t, K2t, YKt, YQ2, M2, c6w, c6b, x, xout);
    k_score<<<dim3(64, 8), 256, 0, stream>>>(xout, y, score_w, score_b, yout);
}

// Round 8
// 122.591 us; speedup vs baseline: 2.3032x; 1.0964x over previous
//
#include <hip/hip_runtime.h>
#include <hip/hip_bf16.h>
#include <math.h>

#define HW 4096

typedef short bf16x8_t __attribute__((ext_vector_type(8)));   // 8 bf16 (4 VGPRs)
typedef float f32x16_t __attribute__((ext_vector_type(16)));
typedef unsigned int u32;
typedef unsigned int u32x4_t __attribute__((ext_vector_type(4)));
typedef int i32x2_t __attribute__((ext_vector_type(2)));

union castu { u32x4_t u; bf16x8_t s; };

static __device__ __forceinline__ unsigned short f2bf(float f){
    union { __bf16 b; unsigned short u; } c; c.b = (__bf16)f; return c.u;
}
static __device__ __forceinline__ u32 pk2(float lo, float hi){
    return ((u32)f2bf(hi) << 16) | (u32)f2bf(lo);
}
static __device__ __forceinline__ bf16x8_t ldb(const unsigned short* p){
    return *reinterpret_cast<const bf16x8_t*>(p);
}
static __device__ __forceinline__ bf16x8_t ld_xs(const unsigned short* p){
    uint2 lo = *(const uint2*)(p);
    uint2 hi = *(const uint2*)(p + 4);
    castu c; c.u = (u32x4_t){lo.x, lo.y, hi.x, hi.y};
    return c.s;
}
static __device__ __forceinline__ f32x16_t mfma32(bf16x8_t a, bf16x8_t b, f32x16_t c){
    return __builtin_amdgcn_mfma_f32_32x32x16_bf16(a, b, c, 0, 0, 0);
}
static __device__ __forceinline__ float ex2(float x){
    return __builtin_amdgcn_exp2f(x);
}
// C/D-layout (32x32) -> B-frag conversion via permlane32_swap:
// word pairs (P0,P2)(P1,P3) -> b0, (P4,P6)(P5,P7) -> b1.
// swap(a,b) returns { {a_lo,b_lo}, {a_hi,b_hi} } across the lane<32/lane>=32 split.
static __device__ __forceinline__ void cd2bfrag(const u32 P[8], bf16x8_t& b0, bf16x8_t& b1){
    i32x2_t s02 = __builtin_amdgcn_permlane32_swap((int)P[0], (int)P[2], false, false);
    i32x2_t s13 = __builtin_amdgcn_permlane32_swap((int)P[1], (int)P[3], false, false);
    i32x2_t s46 = __builtin_amdgcn_permlane32_swap((int)P[4], (int)P[6], false, false);
    i32x2_t s57 = __builtin_amdgcn_permlane32_swap((int)P[5], (int)P[7], false, false);
    castu c0, c1;
    c0.u = (u32x4_t){ (u32)s02[0], (u32)s13[0], (u32)s02[1], (u32)s13[1] };
    c1.u = (u32x4_t){ (u32)s46[0], (u32)s57[0], (u32)s46[1], (u32)s57[1] };
    b0 = c0.s; b1 = c1.s;
}

#define LOG2E 1.44269504088896340736f

// ---------------- K1: MFMA front convs + six 1x1 projections -----------------
__global__ __launch_bounds__(256, 1) void k_front_mfma(
    const float* __restrict__ x, const float* __restrict__ y,
    const float* __restrict__ conv_w, const float* __restrict__ conv_b,
    const float* __restrict__ c132_w, const float* __restrict__ c132_b,
    const float* __restrict__ q1w, const float* __restrict__ q1b,
    const float* __restrict__ k1w, const float* __restrict__ k1b,
    const float* __restrict__ q2w, const float* __restrict__ q2b,
    const float* __restrict__ k2w, const float* __restrict__ k2b,
    const float* __restrict__ q3w, const float* __restrict__ q3b,
    const float* __restrict__ k3w, const float* __restrict__ k3b,
    float* __restrict__ K1, float* __restrict__ Q2, float* __restrict__ YQ,
    unsigned short* __restrict__ Q1t, unsigned short* __restrict__ K2t,
    unsigned short* __restrict__ YKt)
{
    __shared__ unsigned short xs[4 * 68 * 36];
    __shared__ float ys[4 * 68];
    __shared__ u32 wplane[18 * 4 * 64];
    __shared__ u32 wyplane[4 * 64];
    __shared__ u32 c1plane[4 * 64];

    int tid = threadIdx.x;
    int h0 = blockIdx.x * 2, b = blockIdx.y;

    #pragma unroll
    for (int i = 0; i < 32; ++i){
        int idx = i * 256 + tid;
        int w = idx & 63, ic = (idx >> 6) & 31, dr = idx >> 11;
        int hr = h0 - 1 + dr;
        float v = (hr >= 0 && hr < 64) ? x[((b * 32 + ic) << 12) + (hr << 6) + w] : 0.f;
        xs[(dr * 68 + w + 1) * 36 + ic] = f2bf(v);
    }
    {
        int dr = tid >> 6, ic = tid & 31, side = (tid >> 5) & 1;
        xs[(dr * 68 + (side ? 65 : 0)) * 36 + ic] = 0;
    }
    for (int idx = tid; idx < 272; idx += 256){
        int dr = idx / 68, wp = idx % 68;
        int hr = h0 - 1 + dr, w = wp - 1;
        ys[idx] = (hr >= 0 && hr < 64 && w >= 0 && w < 64) ? y[(b << 12) + (hr << 6) + w] : 0.f;
    }
    for (int e = tid; e < 4608; e += 256){
        int f = e >> 8, wi = (e >> 6) & 3, ln = e & 63;
        int t = f >> 1, j = f & 1, hh = ln >> 5, ll = ln & 31;
        int ic0 = 16 * j + 8 * hh + 2 * wi;
        int co0 = 5 * (ic0 >> 2) + (ic0 & 3);
        int ic1 = ic0 + 1;
        int co1 = 5 * (ic1 >> 2) + (ic1 & 3);
        wplane[e] = pk2(conv_w[ll * 360 + co0 * 9 + t], conv_w[ll * 360 + co1 * 9 + t]);
    }
    {
        int wi = tid >> 6, ln = tid & 63, hh = ln >> 5, ll = ln & 31;
        u32 vy = 0, vc = 0;
        if (hh == 0){
            int t0 = 2 * wi, t1 = 2 * wi + 1;
            float s0 = 0.f, s1 = 0.f;
            #pragma unroll
            for (int g = 0; g < 8; ++g){
                s0 += conv_w[ll * 360 + (5 * g + 4) * 9 + t0];
                s1 += conv_w[ll * 360 + (5 * g + 4) * 9 + t1];
            }
            vy = pk2(s0, s1);
            vc = pk2(c132_w[ll * 9 + t0], c132_w[ll * 9 + t1]);
        } else if (wi == 0){
            float s0 = 0.f;
            #pragma unroll
            for (int g = 0; g < 8; ++g) s0 += conv_w[ll * 360 + (5 * g + 4) * 9 + 8];
            vy = pk2(s0, 0.f);
            vc = pk2(c132_w[ll * 9 + 8], 0.f);
        }
        wyplane[wi * 64 + ln] = vy;
        c1plane[wi * 64 + ln] = vc;
    }
    __syncthreads();

    int lane = tid & 63, wid = tid >> 6;
    int l31 = lane & 31, h = lane >> 5;
    int wr = wid >> 1, toff = (wid & 1) * 32;
    int wpB = toff + l31;

    bf16x8_t wA[18];
    #pragma unroll
    for (int f = 0; f < 18; ++f){
        castu c;
        c.u = (u32x4_t){ wplane[(f * 4 + 0) * 64 + lane], wplane[(f * 4 + 1) * 64 + lane],
                         wplane[(f * 4 + 2) * 64 + lane], wplane[(f * 4 + 3) * 64 + lane] };
        wA[f] = c.s;
    }
    castu wyf, c1f;
    wyf.u = (u32x4_t){ wyplane[lane], wyplane[64 + lane], wyplane[128 + lane], wyplane[192 + lane] };
    c1f.u = (u32x4_t){ c1plane[lane], c1plane[64 + lane], c1plane[128 + lane], c1plane[192 + lane] };

    float yv[8];
    #pragma unroll
    for (int i = 0; i < 8; ++i){
        int tt = 8 * h + i;
        yv[i] = (tt < 9) ? ys[(wr + tt / 3) * 68 + wpB + (tt % 3)] : 0.f;
    }
    castu yf;
    yf.u = (u32x4_t){ pk2(yv[0], yv[1]), pk2(yv[2], yv[3]), pk2(yv[4], yv[5]), pk2(yv[6], yv[7]) };

    f32x16_t accE, accO, accY, acc2;
    #pragma unroll
    for (int r = 0; r < 16; ++r){
        int oc = (r & 3) + 8 * (r >> 2) + 4 * h;
        accE[r] = 0.f; accO[r] = 0.f;
        accY[r] = conv_b[oc]; acc2[r] = c132_b[oc];
    }
    #pragma unroll
    for (int t = 0; t < 9; ++t){
        int base = ((wr + t / 3) * 68 + wpB + (t % 3)) * 36 + 8 * h;
        bf16x8_t b0 = ld_xs(xs + base);
        bf16x8_t b1 = ld_xs(xs + base + 16);
        if (t & 1){
            accO = mfma32(wA[t * 2 + 0], b0, accO);
            accO = mfma32(wA[t * 2 + 1], b1, accO);
        } else {
            accE = mfma32(wA[t * 2 + 0], b0, accE);
            accE = mfma32(wA[t * 2 + 1], b1, accE);
        }
    }
    accY = mfma32(wyf.s, yf.s, accY);
    acc2 = mfma32(c1f.s, yf.s, acc2);

    f32x16_t x1v;
    #pragma unroll
    for (int r = 0; r < 16; ++r){
        float v = accE[r] + accO[r] + accY[r];
        x1v[r] = v > 0.f ? v : 0.f;
    }
    u32 P[8];
    bf16x8_t x1b0, x1b1, x2b0, x2b1;
    #pragma unroll
    for (int t2 = 0; t2 < 8; ++t2) P[t2] = pk2(x1v[2 * t2], x1v[2 * t2 + 1]);
    cd2bfrag(P, x1b0, x1b1);
    #pragma unroll
    for (int t2 = 0; t2 < 8; ++t2) P[t2] = pk2(acc2[2 * t2], acc2[2 * t2 + 1]);
    cd2bfrag(P, x2b0, x2b1);

    int pxg = (h0 + wr) * 64 + toff + l31;
    size_t bf_base = ((size_t)b * HW + pxg) * 32;

    // q1 -> Q1t (bf16 pixel-major, pre-scaled by log2e)
    {
        f32x16_t a;
        #pragma unroll
        for (int r = 0; r < 16; ++r) a[r] = q1b[(r & 3) + 8 * (r >> 2) + 4 * h];
        const float* p0 = q1w + l31 * 32 + 8 * h;
        castu w0, w1;
        w0.u = (u32x4_t){ pk2(p0[0],p0[1]), pk2(p0[2],p0[3]), pk2(p0[4],p0[5]), pk2(p0[6],p0[7]) };
        w1.u = (u32x4_t){ pk2(p0[16],p0[17]), pk2(p0[18],p0[19]), pk2(p0[20],p0[21]), pk2(p0[22],p0[23]) };
        a = mfma32(w0.s, x1b0, a);
        a = mfma32(w1.s, x1b1, a);
        u32 Q[8];
        #pragma unroll
        for (int t2 = 0; t2 < 8; ++t2) Q[t2] = pk2(a[2 * t2] * LOG2E, a[2 * t2 + 1] * LOG2E);
        *(uint2*)(Q1t + bf_base + 4 * h)      = make_uint2(Q[0], Q[1]);
        *(uint2*)(Q1t + bf_base + 8 + 4 * h)  = make_uint2(Q[2], Q[3]);
        *(uint2*)(Q1t + bf_base + 16 + 4 * h) = make_uint2(Q[4], Q[5]);
        *(uint2*)(Q1t + bf_base + 24 + 4 * h) = make_uint2(Q[6], Q[7]);
    }
    // k1 -> K1 (f32 channel-major)
    {
        f32x16_t a;
        #pragma unroll
        for (int r = 0; r < 16; ++r) a[r] = k1b[(r & 3) + 8 * (r >> 2) + 4 * h];
        const float* p0 = k1w + l31 * 32 + 8 * h;
        castu w0, w1;
        w0.u = (u32x4_t){ pk2(p0[0],p0[1]), pk2(p0[2],p0[3]), pk2(p0[4],p0[5]), pk2(p0[6],p0[7]) };
        w1.u = (u32x4_t){ pk2(p0[16],p0[17]), pk2(p0[18],p0[19]), pk2(p0[20],p0[21]), pk2(p0[22],p0[23]) };
        a = mfma32(w0.s, x1b0, a);
        a = mfma32(w1.s, x1b1, a);
        #pragma unroll
        for (int r = 0; r < 16; ++r)
            K1[(b * 32 + (r & 3) + 8 * (r >> 2) + 4 * h) * HW + pxg] = a[r];
    }
    // q2 -> Q2 (f32 channel-major)
    {
        f32x16_t a;
        #pragma unroll
        for (int r = 0; r < 16; ++r) a[r] = q2b[(r & 3) + 8 * (r >> 2) + 4 * h];
        const float* p0 = q2w + l31 * 32 + 8 * h;
        castu w0, w1;
        w0.u = (u32x4_t){ pk2(p0[0],p0[1]), pk2(p0[2],p0[3]), pk2(p0[4],p0[5]), pk2(p0[6],p0[7]) };
        w1.u = (u32x4_t){ pk2(p0[16],p0[17]), pk2(p0[18],p0[19]), pk2(p0[20],p0[21]), pk2(p0[22],p0[23]) };
        a = mfma32(w0.s, x1b0, a);
        a = mfma32(w1.s, x1b1, a);
        #pragma unroll
        for (int r = 0; r < 16; ++r)
            Q2[(b * 32 + (r & 3) + 8 * (r >> 2) + 4 * h) * HW + pxg] = a[r];
    }
    // k2 -> K2t (bf16 pixel-major)
    {
        f32x16_t a;
        #pragma unroll
        for (int r = 0; r < 16; ++r) a[r] = k2b[(r & 3) + 8 * (r >> 2) + 4 * h];
        const float* p0 = k2w + l31 * 32 + 8 * h;
        castu w0, w1;
        w0.u = (u32x4_t){ pk2(p0[0],p0[1]), pk2(p0[2],p0[3]), pk2(p0[4],p0[5]), pk2(p0[6],p0[7]) };
        w1.u = (u32x4_t){ pk2(p0[16],p0[17]), pk2(p0[18],p0[19]), pk2(p0[20],p0[21]), pk2(p0[22],p0[23]) };
        a = mfma32(w0.s, x1b0, a);
        a = mfma32(w1.s, x1b1, a);
        u32 Q[8];
        #pragma unroll
        for (int t2 = 0; t2 < 8; ++t2) Q[t2] = pk2(a[2 * t2], a[2 * t2 + 1]);
        *(uint2*)(K2t + bf_base + 4 * h)      = make_uint2(Q[0], Q[1]);
        *(uint2*)(K2t + bf_base + 8 + 4 * h)  = make_uint2(Q[2], Q[3]);
        *(uint2*)(K2t + bf_base + 16 + 4 * h) = make_uint2(Q[4], Q[5]);
        *(uint2*)(K2t + bf_base + 24 + 4 * h) = make_uint2(Q[6], Q[7]);
    }
    // q3 (x2) -> YQ (f32 channel-major)
    {
        f32x16_t a;
        #pragma unroll
        for (int r = 0; r < 16; ++r) a[r] = q3b[(r & 3) + 8 * (r >> 2) + 4 * h];
        const float* p0 = q3w + l31 * 32 + 8 * h;
        castu w0, w1;
        w0.u = (u32x4_t){ pk2(p0[0],p0[1]), pk2(p0[2],p0[3]), pk2(p0[4],p0[5]), pk2(p0[6],p0[7]) };
        w1.u = (u32x4_t){ pk2(p0[16],p0[17]), pk2(p0[18],p0[19]), pk2(p0[20],p0[21]), pk2(p0[22],p0[23]) };
        a = mfma32(w0.s, x2b0, a);
        a = mfma32(w1.s, x2b1, a);
        #pragma unroll
        for (int r = 0; r < 16; ++r)
            YQ[(b * 32 + (r & 3) + 8 * (r >> 2) + 4 * h) * HW + pxg] = a[r];
    }
    // k3 (x2) -> YKt (bf16 pixel-major)
    {
        f32x16_t a;
        #pragma unroll
        for (int r = 0; r < 16; ++r) a[r] = k3b[(r & 3) + 8 * (r >> 2) + 4 * h];
        const float* p0 = k3w + l31 * 32 + 8 * h;
        castu w0, w1;
        w0.u = (u32x4_t){ pk2(p0[0],p0[1]), pk2(p0[2],p0[3]), pk2(p0[4],p0[5]), pk2(p0[6],p0[7]) };
        w1.u = (u32x4_t){ pk2(p0[16],p0[17]), pk2(p0[18],p0[19]), pk2(p0[20],p0[21]), pk2(p0[22],p0[23]) };
        a = mfma32(w0.s, x2b0, a);
        a = mfma32(w1.s, x2b1, a);
        u32 Q[8];
        #pragma unroll
        for (int t2 = 0; t2 < 8; ++t2) Q[t2] = pk2(a[2 * t2], a[2 * t2 + 1]);
        *(uint2*)(YKt + bf_base + 4 * h)      = make_uint2(Q[0], Q[1]);
        *(uint2*)(YKt + bf_base + 8 + 4 * h)  = make_uint2(Q[2], Q[3]);
        *(uint2*)(YKt + bf_base + 16 + 4 * h) = make_uint2(Q[4], Q[5]);
        *(uint2*)(YKt + bf_base + 24 + 4 * h) = make_uint2(Q[6], Q[7]);
    }
}

// ---------------- K3: channel attention partial sums -------------------------
__global__ __launch_bounds__(256) void k_chan_part(
    const float* __restrict__ K1, const float* __restrict__ Q2,
    float* __restrict__ Scp)
{
    __shared__ float k1s[128 * 33];
    __shared__ float q2s[128 * 33];
    int chunk = blockIdx.x;
    int b = blockIdx.y;
    int n0 = chunk * 128;
    int t = threadIdx.x;
    for (int i = 0; i < 16; ++i){
        int idx = i * 256 + t;
        int c = idx >> 7, nl = idx & 127;
        k1s[nl * 33 + c] = K1[(b * 32 + c) * HW + n0 + nl];
        q2s[nl * 33 + c] = Q2[(b * 32 + c) * HW + n0 + nl];
    }
    __syncthreads();
    float acc[4] = {0.f, 0.f, 0.f, 0.f};
    int d = t & 31, c0 = t >> 5;
    for (int nl = 0; nl < 128; ++nl){
        float qv = q2s[nl * 33 + d];
        #pragma unroll
        for (int i = 0; i < 4; ++i)
            acc[i] = fmaf(k1s[nl * 33 + c0 + 8 * i], qv, acc[i]);
    }
    #pragma unroll
    for (int i = 0; i < 4; ++i)
        Scp[(b * 32 + chunk) * 1024 + (c0 + 8 * i) * 32 + d] = acc[i];
}

// ---------------- K4: channel softmax + fold conv6 W2 into M2 ----------------
__global__ __launch_bounds__(1024) void k_chan_fin(
    const float* __restrict__ Scp, const float* __restrict__ c6w,
    float* __restrict__ M2)
{
    __shared__ float pc[32 * 33];
    int b = blockIdx.x;
    int t = threadIdx.x;
    int c = t >> 5, d = t & 31;
    float s = 0.f;
    for (int k = 0; k < 32; ++k) s += Scp[(b * 32 + k) * 1024 + t];
    float mx = s;
    #pragma unroll
    for (int off = 16; off >= 1; off >>= 1) mx = fmaxf(mx, __shfl_xor(mx, off));
    float e = __expf(s - mx);
    float sum = e;
    #pragma unroll
    for (int off = 16; off >= 1; off >>= 1) sum += __shfl_xor(sum, off);
    pc[c * 33 + d] = e / sum;
    __syncthreads();
    int o = t >> 5, cc = t & 31;
    float m2 = 0.f;
    #pragma unroll
    for (int dd = 0; dd < 32; ++dd)
        m2 = fmaf(c6w[o * 64 + 32 + dd], pc[cc * 33 + dd], m2);
    M2[b * 1024 + o * 32 + cc] = m2;
}

// -------- K5: MFMA stats pass (l = sum exp) + fused YQ scale -> YQ2 ----------
__global__ __launch_bounds__(256, 4) void k_stats_mfma(
    const unsigned short* __restrict__ Q1t, const unsigned short* __restrict__ K2t,
    const float* __restrict__ YQ, unsigned short* __restrict__ YQ2)
{
    __shared__ float red[4][16][64];
    __shared__ float ls[32];
    int t = threadIdx.x, wid = t >> 6, lane = t & 63;
    int l31 = lane & 31, h = lane >> 5;
    int b = blockIdx.x >> 7, ntile = blockIdx.x & 127;
    int n0 = ntile * 32;
    const unsigned short* q = Q1t + (size_t)b * 131072;
    const unsigned short* k = K2t + (size_t)b * 131072;
    bf16x8_t a0 = ldb(q + (size_t)(n0 + l31) * 32 + 8 * h);
    bf16x8_t a1 = ldb(q + (size_t)(n0 + l31) * 32 + 16 + 8 * h);
    float accl[16];
    #pragma unroll
    for (int r = 0; r < 16; ++r) accl[r] = 0.f;

    const unsigned short* kp = k + ((size_t)(wid << 10) + l31) * 32 + 8 * h;
    bf16x8_t b0 = ldb(kp);
    bf16x8_t b1 = ldb(kp + 16);
    for (int i = 0; i < 32; ++i){
        f32x16_t s;
        #pragma unroll
        for (int r = 0; r < 16; ++r) s[r] = 0.f;
        s = mfma32(a0, b0, s);
        s = mfma32(a1, b1, s);
        if (i != 31) kp += 1024;
        bf16x8_t nb0 = ldb(kp);
        bf16x8_t nb1 = ldb(kp + 16);
        #pragma unroll
        for (int r = 0; r < 16; ++r) accl[r] += ex2(s[r]);
        b0 = nb0; b1 = nb1;
    }
    #pragma unroll
    for (int r = 0; r < 16; ++r) red[wid][r][lane] = accl[r];
    __syncthreads();
    if (wid == 0){
        #pragma unroll
        for (int r = 0; r < 16; ++r){
            float v = red[0][r][lane] + red[1][r][lane] + red[2][r][lane] + red[3][r][lane];
            #pragma unroll
            for (int off = 16; off >= 1; off >>= 1) v += __shfl_xor(v, off);
            if (l31 == 0)
                ls[(r & 3) + 8 * (r >> 2) + 4 * h] = 1.0f / v;
        }
    }
    __syncthreads();
    // fused scale: YQ2[c][n] = bf16(YQ[c][n] / l[n]), channel-major
    #pragma unroll
    for (int p = 0; p < 4; ++p){
        int idx = (p << 8) + t;
        int c = idx >> 5, n = idx & 31;
        size_t g = (size_t)(b * 32 + c) * HW + n0 + n;
        YQ2[g] = f2bf(YQ[g] * ls[n]);
    }
}

// ---------------- K7: MFMA value pass + conv6 + residual ----------------------
__global__ __launch_bounds__(256, 4) void k_attn_mfma(
    const unsigned short* __restrict__ Q1t, const unsigned short* __restrict__ K2t,
    const unsigned short* __restrict__ YKt, const unsigned short* __restrict__ YQ2,
    const float* __restrict__ M2, const float* __restrict__ c6w, const float* __restrict__ c6b,
    const float* __restrict__ x, float* __restrict__ xout)
{
    __shared__ float red[4][16][64];
    int t = threadIdx.x, wid = t >> 6, lane = t & 63;
    int l31 = lane & 31, h = lane >> 5;
    int b = blockIdx.x >> 7, mtile = blockIdx.x & 127;
    int m0 = mtile * 32;
    size_t boff = (size_t)b * 131072;
    const unsigned short* qb = Q1t + boff;
    const unsigned short* kb = K2t + boff;
    const unsigned short* yqb = YQ2 + boff;

    bf16x8_t kb0 = ldb(kb + (size_t)(m0 + l31) * 32 + 8 * h);
    bf16x8_t kb1 = ldb(kb + (size_t)(m0 + l31) * 32 + 16 + 8 * h);

    f32x16_t oacc;
    #pragma unroll
    for (int r = 0; r < 16; ++r) oacc[r] = 0.f;

    const unsigned short* qp = qb + ((size_t)(wid << 10) + l31) * 32 + 8 * h;
    const unsigned short* yp = yqb + (size_t)l31 * HW + 8 * h + (wid << 10);
    bf16x8_t a0 = ldb(qp), a1 = ldb(qp + 16);
    bf16x8_t y0 = ldb(yp), y1 = ldb(yp + 16);

    for (int i = 0; i < 32; ++i){
        f32x16_t s;
        #pragma unroll
        for (int r = 0; r < 16; ++r) s[r] = 0.f;
        s = mfma32(a0, kb0, s);
        s = mfma32(a1, kb1, s);
        // prefetch next iteration's fragments (hides L2 latency under exp/pack)
        if (i != 31){ qp += 1024; yp += 32; }
        bf16x8_t na0 = ldb(qp), na1 = ldb(qp + 16);
        bf16x8_t ny0 = ldb(yp), ny1 = ldb(yp + 16);
        // E = exp2(S'); C-layout -> B-frag via permlane32_swap
        u32 P[8];
        #pragma unroll
        for (int tt = 0; tt < 8; ++tt)
            P[tt] = pk2(ex2(s[2 * tt]), ex2(s[2 * tt + 1]));
        bf16x8_t e0, e1;
        cd2bfrag(P, e0, e1);
        oacc = mfma32(y0, e0, oacc);
        oacc = mfma32(y1, e1, oacc);
        a0 = na0; a1 = na1; y0 = ny0; y1 = ny1;
    }
    #pragma unroll
    for (int r = 0; r < 16; ++r) red[wid][r][lane] = oacc[r];
    __syncthreads();
    if (wid != 0) return;
    #pragma unroll
    for (int r = 0; r < 16; ++r)
        oacc[r] = red[0][r][lane] + red[1][r][lane] + red[2][r][lane] + red[3][r][lane];

    u32 P[8];
    #pragma unroll
    for (int tt = 0; tt < 8; ++tt) P[tt] = pk2(oacc[2 * tt], oacc[2 * tt + 1]);
    bf16x8_t xb0, xb1;
    cd2bfrag(P, xb0, xb1);

    const float* w1p = c6w + l31 * 64;
    const float* m2p = M2 + b * 1024 + l31 * 32;
    int cb0 = 8 * h, cb1 = 16 + 8 * h;
    castu wa0, wa1, ma0, ma1;
    wa0.u = (u32x4_t){ pk2(w1p[cb0], w1p[cb0+1]), pk2(w1p[cb0+2], w1p[cb0+3]),
                       pk2(w1p[cb0+4], w1p[cb0+5]), pk2(w1p[cb0+6], w1p[cb0+7]) };
    wa1.u = (u32x4_t){ pk2(w1p[cb1], w1p[cb1+1]), pk2(w1p[cb1+2], w1p[cb1+3]),
                       pk2(w1p[cb1+4], w1p[cb1+5]), pk2(w1p[cb1+6], w1p[cb1+7]) };
    ma0.u = (u32x4_t){ pk2(m2p[cb0], m2p[cb0+1]), pk2(m2p[cb0+2], m2p[cb0+3]),
                       pk2(m2p[cb0+4], m2p[cb0+5]), pk2(m2p[cb0+6], m2p[cb0+7]) };
    ma1.u = (u32x4_t){ pk2(m2p[cb1], m2p[cb1+1]), pk2(m2p[cb1+2], m2p[cb1+3]),
                       pk2(m2p[cb1+4], m2p[cb1+5]), pk2(m2p[cb1+6], m2p[cb1+7]) };
    const unsigned short* ykp = YKt + boff + (size_t)(m0 + l31) * 32;
    bf16x8_t ykb0 = ldb(ykp + 8 * h);
    bf16x8_t ykb1 = ldb(ykp + 16 + 8 * h);

    f32x16_t facc;
    #pragma unroll
    for (int r = 0; r < 16; ++r) facc[r] = c6b[(r & 3) + 8 * (r >> 2) + 4 * h];
    facc = mfma32(wa0.s, xb0, facc);
    facc = mfma32(wa1.s, xb1, facc);
    facc = mfma32(ma0.s, ykb0, facc);
    facc = mfma32(ma1.s, ykb1, facc);

    #pragma unroll
    for (int r = 0; r < 16; ++r){
        int o = (r & 3) + 8 * (r >> 2) + 4 * h;
        size_t gi = ((size_t)(b * 32 + o) << 12) + m0 + l31;
        xout[gi] = x[gi] + facc[r];
    }
}

// ---------------- K8: score conv + residual on y (LDS-staged) -----------------
__global__ __launch_bounds__(256) void k_score(
    const float* __restrict__ xout, const float* __restrict__ y,
    const float* __restrict__ sw, const float* __restrict__ sb,
    float* __restrict__ yout)
{
    __shared__ float xs[3][32][66];
    __shared__ float red[4][64];
    int tid = threadIdx.x;
    int h = blockIdx.x, b = blockIdx.y;
    for (int i = 0; i < 24; ++i){
        int idx = i * 256 + tid;
        int w = idx & 63, ic = (idx >> 6) & 31, dr = idx >> 11;
        int hr = h + dr - 1;
        xs[dr][ic][1 + w] = (hr >= 0 && hr < 64) ? xout[((b * 32 + ic) << 12) + (hr << 6) + w] : 0.f;
    }
    if (tid < 96){ xs[tid >> 5][tid & 31][0] = 0.f; }
    else if (tid < 192){ int u = tid - 96; xs[u >> 5][u & 31][65] = 0.f; }
    __syncthreads();
    int w = tid & 63, icg = tid >> 6;
    float p = 0.f;
    #pragma unroll
    for (int i = 0; i < 8; ++i){
        int ic = icg * 8 + i;
        #pragma unroll
        for (int tap = 0; tap < 9; ++tap)
            p = fmaf(sw[ic * 9 + tap], xs[tap / 3][ic][w + tap % 3], p);
    }
    red[icg][w] = p;
    __syncthreads();
    if (tid < 64){
        int px = (h << 6) + tid;
        yout[b * HW + px] = y[b * HW + px] + sb[0]
                          + red[0][tid] + red[1][tid] + red[2][tid] + red[3][tid];
    }
}

extern "C" void kernel_launch(void* const* d_in, const int* in_sizes, int n_in,
                              void* d_out, int out_size, void* d_ws, size_t ws_size,
                              hipStream_t stream)
{
    (void)in_sizes; (void)n_in; (void)out_size; (void)ws_size;
    const float* x      = (const float*)d_in[0];
    const float* y      = (const float*)d_in[1];
    const float* conv_w = (const float*)d_in[2];
    const float* conv_b = (const float*)d_in[3];
    const float* score_w= (const float*)d_in[4];
    const float* score_b= (const float*)d_in[5];
    const float* c132_w = (const float*)d_in[6];
    const float* c132_b = (const float*)d_in[7];
    const float* q1w = (const float*)d_in[8];  const float* q1b = (const float*)d_in[9];
    const float* k1w = (const float*)d_in[10]; const float* k1b = (const float*)d_in[11];
    const float* q2w = (const float*)d_in[12]; const float* q2b = (const float*)d_in[13];
    const float* k2w = (const float*)d_in[14]; const float* k2b = (const float*)d_in[15];
    const float* q3w = (const float*)d_in[16]; const float* q3b = (const float*)d_in[17];
    const float* k3w = (const float*)d_in[18]; const float* k3b = (const float*)d_in[19];
    const float* c6w = (const float*)d_in[20]; const float* c6b = (const float*)d_in[21];

    float* ws = (float*)d_ws;
    const size_t SZ = 1048576;            // 8*32*4096
    float* Scp = ws;                      // 262144 f32
    float* M2  = ws + 262144;             // 8192 f32
    float* K1  = ws + 2 * SZ;             // 1M f32
    float* Q2  = ws + 3 * SZ;             // 1M f32
    float* YQf = ws + 4 * SZ;             // 1M f32
    unsigned short* Q1t = (unsigned short*)(ws + 5 * SZ);            // 1M bf16
    unsigned short* K2t = (unsigned short*)(ws + 5 * SZ + SZ / 2);   // 1M bf16
    unsigned short* YKt = (unsigned short*)(ws + 6 * SZ);            // 1M bf16
    unsigned short* YQ2 = (unsigned short*)(ws + 6 * SZ + SZ / 2);   // 1M bf16

    float* xout = (float*)d_out;
    float* yout = xout + SZ;

    k_front_mfma<<<dim3(32, 8), 256, 0, stream>>>(
        x, y, conv_w, conv_b, c132_w, c132_b,
        q1w, q1b, k1w, k1b, q2w, q2b, k2w, k2b, q3w, q3b, k3w, k3b,
        K1, Q2, YQf, Q1t, K2t, YKt);
    k_chan_part<<<dim3(32, 8), 256, 0, stream>>>(K1, Q2, Scp);
    k_chan_fin<<<8, 1024, 0, stream>>>(Scp, c6w, M2);
    k_stats_mfma<<<1024, 256, 0, stream>>>(Q1t, K2t, YQf, YQ2);
    k_attn_mfma<<<1024, 256, 0, stream>>>(Q1t, K2t, YKt, YQ2, M2, c6w, c6b, x, xout);
    k_score<<<dim3(64, 8), 256, 0, stream>>>(xout, y, score_w, score_b, yout);
}

// Round 9
// 109.092 us; speedup vs baseline: 2.5882x; 1.1237x over previous
//
#include <hip/hip_runtime.h>
#include <hip/hip_bf16.h>
#include <math.h>

#define HW 4096

typedef short bf16x8_t __attribute__((ext_vector_type(8)));   // 8 bf16 (4 VGPRs)
typedef float f32x16_t __attribute__((ext_vector_type(16)));
typedef unsigned int u32;
typedef unsigned int u32x4_t __attribute__((ext_vector_type(4)));
typedef int i32x2_t __attribute__((ext_vector_type(2)));

union castu { u32x4_t u; bf16x8_t s; };

static __device__ __forceinline__ unsigned short f2bf(float f){
    union { __bf16 b; unsigned short u; } c; c.b = (__bf16)f; return c.u;
}
static __device__ __forceinline__ u32 pk2(float lo, float hi){
    return ((u32)f2bf(hi) << 16) | (u32)f2bf(lo);
}
static __device__ __forceinline__ bf16x8_t ldb(const unsigned short* p){
    return *reinterpret_cast<const bf16x8_t*>(p);
}
static __device__ __forceinline__ bf16x8_t ld_xs(const unsigned short* p){
    uint2 lo = *(const uint2*)(p);
    uint2 hi = *(const uint2*)(p + 4);
    castu c; c.u = (u32x4_t){lo.x, lo.y, hi.x, hi.y};
    return c.s;
}
static __device__ __forceinline__ f32x16_t mfma32(bf16x8_t a, bf16x8_t b, f32x16_t c){
    return __builtin_amdgcn_mfma_f32_32x32x16_bf16(a, b, c, 0, 0, 0);
}
static __device__ __forceinline__ float ex2(float x){
    return __builtin_amdgcn_exp2f(x);
}
// C/D-layout (32x32) -> B-frag conversion via permlane32_swap.
static __device__ __forceinline__ void cd2bfrag(const u32 P[8], bf16x8_t& b0, bf16x8_t& b1){
    i32x2_t s02 = __builtin_amdgcn_permlane32_swap((int)P[0], (int)P[2], false, false);
    i32x2_t s13 = __builtin_amdgcn_permlane32_swap((int)P[1], (int)P[3], false, false);
    i32x2_t s46 = __builtin_amdgcn_permlane32_swap((int)P[4], (int)P[6], false, false);
    i32x2_t s57 = __builtin_amdgcn_permlane32_swap((int)P[5], (int)P[7], false, false);
    castu c0, c1;
    c0.u = (u32x4_t){ (u32)s02[0], (u32)s13[0], (u32)s02[1], (u32)s13[1] };
    c1.u = (u32x4_t){ (u32)s46[0], (u32)s57[0], (u32)s46[1], (u32)s57[1] };
    b0 = c0.s; b1 = c1.s;
}

#define LOG2E 1.44269504088896340736f

// ---------------- K1: MFMA front convs + six 1x1 projections -----------------
__global__ __launch_bounds__(256, 1) void k_front_mfma(
    const float* __restrict__ x, const float* __restrict__ y,
    const float* __restrict__ conv_w, const float* __restrict__ conv_b,
    const float* __restrict__ c132_w, const float* __restrict__ c132_b,
    const float* __restrict__ q1w, const float* __restrict__ q1b,
    const float* __restrict__ k1w, const float* __restrict__ k1b,
    const float* __restrict__ q2w, const float* __restrict__ q2b,
    const float* __restrict__ k2w, const float* __restrict__ k2b,
    const float* __restrict__ q3w, const float* __restrict__ q3b,
    const float* __restrict__ k3w, const float* __restrict__ k3b,
    float* __restrict__ K1, float* __restrict__ Q2, float* __restrict__ YQ,
    unsigned short* __restrict__ Q1t, unsigned short* __restrict__ K2t,
    unsigned short* __restrict__ YKt)
{
    __shared__ unsigned short xs[4 * 68 * 36];
    __shared__ float ys[4 * 68];
    __shared__ u32 wplane[18 * 4 * 64];
    __shared__ u32 wyplane[4 * 64];
    __shared__ u32 c1plane[4 * 64];

    int tid = threadIdx.x;
    int h0 = blockIdx.x * 2, b = blockIdx.y;

    #pragma unroll
    for (int i = 0; i < 32; ++i){
        int idx = i * 256 + tid;
        int w = idx & 63, ic = (idx >> 6) & 31, dr = idx >> 11;
        int hr = h0 - 1 + dr;
        float v = (hr >= 0 && hr < 64) ? x[((b * 32 + ic) << 12) + (hr << 6) + w] : 0.f;
        xs[(dr * 68 + w + 1) * 36 + ic] = f2bf(v);
    }
    {
        int dr = tid >> 6, ic = tid & 31, side = (tid >> 5) & 1;
        xs[(dr * 68 + (side ? 65 : 0)) * 36 + ic] = 0;
    }
    for (int idx = tid; idx < 272; idx += 256){
        int dr = idx / 68, wp = idx % 68;
        int hr = h0 - 1 + dr, w = wp - 1;
        ys[idx] = (hr >= 0 && hr < 64 && w >= 0 && w < 64) ? y[(b << 12) + (hr << 6) + w] : 0.f;
    }
    for (int e = tid; e < 4608; e += 256){
        int f = e >> 8, wi = (e >> 6) & 3, ln = e & 63;
        int t = f >> 1, j = f & 1, hh = ln >> 5, ll = ln & 31;
        int ic0 = 16 * j + 8 * hh + 2 * wi;
        int co0 = 5 * (ic0 >> 2) + (ic0 & 3);
        int ic1 = ic0 + 1;
        int co1 = 5 * (ic1 >> 2) + (ic1 & 3);
        wplane[e] = pk2(conv_w[ll * 360 + co0 * 9 + t], conv_w[ll * 360 + co1 * 9 + t]);
    }
    {
        int wi = tid >> 6, ln = tid & 63, hh = ln >> 5, ll = ln & 31;
        u32 vy = 0, vc = 0;
        if (hh == 0){
            int t0 = 2 * wi, t1 = 2 * wi + 1;
            float s0 = 0.f, s1 = 0.f;
            #pragma unroll
            for (int g = 0; g < 8; ++g){
                s0 += conv_w[ll * 360 + (5 * g + 4) * 9 + t0];
                s1 += conv_w[ll * 360 + (5 * g + 4) * 9 + t1];
            }
            vy = pk2(s0, s1);
            vc = pk2(c132_w[ll * 9 + t0], c132_w[ll * 9 + t1]);
        } else if (wi == 0){
            float s0 = 0.f;
            #pragma unroll
            for (int g = 0; g < 8; ++g) s0 += conv_w[ll * 360 + (5 * g + 4) * 9 + 8];
            vy = pk2(s0, 0.f);
            vc = pk2(c132_w[ll * 9 + 8], 0.f);
        }
        wyplane[wi * 64 + ln] = vy;
        c1plane[wi * 64 + ln] = vc;
    }
    __syncthreads();

    int lane = tid & 63, wid = tid >> 6;
    int l31 = lane & 31, h = lane >> 5;
    int wr = wid >> 1, toff = (wid & 1) * 32;
    int wpB = toff + l31;

    bf16x8_t wA[18];
    #pragma unroll
    for (int f = 0; f < 18; ++f){
        castu c;
        c.u = (u32x4_t){ wplane[(f * 4 + 0) * 64 + lane], wplane[(f * 4 + 1) * 64 + lane],
                         wplane[(f * 4 + 2) * 64 + lane], wplane[(f * 4 + 3) * 64 + lane] };
        wA[f] = c.s;
    }
    castu wyf, c1f;
    wyf.u = (u32x4_t){ wyplane[lane], wyplane[64 + lane], wyplane[128 + lane], wyplane[192 + lane] };
    c1f.u = (u32x4_t){ c1plane[lane], c1plane[64 + lane], c1plane[128 + lane], c1plane[192 + lane] };

    float yv[8];
    #pragma unroll
    for (int i = 0; i < 8; ++i){
        int tt = 8 * h + i;
        yv[i] = (tt < 9) ? ys[(wr + tt / 3) * 68 + wpB + (tt % 3)] : 0.f;
    }
    castu yf;
    yf.u = (u32x4_t){ pk2(yv[0], yv[1]), pk2(yv[2], yv[3]), pk2(yv[4], yv[5]), pk2(yv[6], yv[7]) };

    f32x16_t accE, accO, accY, acc2;
    #pragma unroll
    for (int r = 0; r < 16; ++r){
        int oc = (r & 3) + 8 * (r >> 2) + 4 * h;
        accE[r] = 0.f; accO[r] = 0.f;
        accY[r] = conv_b[oc]; acc2[r] = c132_b[oc];
    }
    #pragma unroll
    for (int t = 0; t < 9; ++t){
        int base = ((wr + t / 3) * 68 + wpB + (t % 3)) * 36 + 8 * h;
        bf16x8_t b0 = ld_xs(xs + base);
        bf16x8_t b1 = ld_xs(xs + base + 16);
        if (t & 1){
            accO = mfma32(wA[t * 2 + 0], b0, accO);
            accO = mfma32(wA[t * 2 + 1], b1, accO);
        } else {
            accE = mfma32(wA[t * 2 + 0], b0, accE);
            accE = mfma32(wA[t * 2 + 1], b1, accE);
        }
    }
    accY = mfma32(wyf.s, yf.s, accY);
    acc2 = mfma32(c1f.s, yf.s, acc2);

    f32x16_t x1v;
    #pragma unroll
    for (int r = 0; r < 16; ++r){
        float v = accE[r] + accO[r] + accY[r];
        x1v[r] = v > 0.f ? v : 0.f;
    }
    u32 P[8];
    bf16x8_t x1b0, x1b1, x2b0, x2b1;
    #pragma unroll
    for (int t2 = 0; t2 < 8; ++t2) P[t2] = pk2(x1v[2 * t2], x1v[2 * t2 + 1]);
    cd2bfrag(P, x1b0, x1b1);
    #pragma unroll
    for (int t2 = 0; t2 < 8; ++t2) P[t2] = pk2(acc2[2 * t2], acc2[2 * t2 + 1]);
    cd2bfrag(P, x2b0, x2b1);

    int pxg = (h0 + wr) * 64 + toff + l31;
    size_t bf_base = ((size_t)b * HW + pxg) * 32;

    // q1 -> Q1t (bf16 pixel-major, pre-scaled by log2e)
    {
        f32x16_t a;
        #pragma unroll
        for (int r = 0; r < 16; ++r) a[r] = q1b[(r & 3) + 8 * (r >> 2) + 4 * h];
        const float* p0 = q1w + l31 * 32 + 8 * h;
        castu w0, w1;
        w0.u = (u32x4_t){ pk2(p0[0],p0[1]), pk2(p0[2],p0[3]), pk2(p0[4],p0[5]), pk2(p0[6],p0[7]) };
        w1.u = (u32x4_t){ pk2(p0[16],p0[17]), pk2(p0[18],p0[19]), pk2(p0[20],p0[21]), pk2(p0[22],p0[23]) };
        a = mfma32(w0.s, x1b0, a);
        a = mfma32(w1.s, x1b1, a);
        u32 Q[8];
        #pragma unroll
        for (int t2 = 0; t2 < 8; ++t2) Q[t2] = pk2(a[2 * t2] * LOG2E, a[2 * t2 + 1] * LOG2E);
        *(uint2*)(Q1t + bf_base + 4 * h)      = make_uint2(Q[0], Q[1]);
        *(uint2*)(Q1t + bf_base + 8 + 4 * h)  = make_uint2(Q[2], Q[3]);
        *(uint2*)(Q1t + bf_base + 16 + 4 * h) = make_uint2(Q[4], Q[5]);
        *(uint2*)(Q1t + bf_base + 24 + 4 * h) = make_uint2(Q[6], Q[7]);
    }
    // k1 -> K1 (f32 channel-major)
    {
        f32x16_t a;
        #pragma unroll
        for (int r = 0; r < 16; ++r) a[r] = k1b[(r & 3) + 8 * (r >> 2) + 4 * h];
        const float* p0 = k1w + l31 * 32 + 8 * h;
        castu w0, w1;
        w0.u = (u32x4_t){ pk2(p0[0],p0[1]), pk2(p0[2],p0[3]), pk2(p0[4],p0[5]), pk2(p0[6],p0[7]) };
        w1.u = (u32x4_t){ pk2(p0[16],p0[17]), pk2(p0[18],p0[19]), pk2(p0[20],p0[21]), pk2(p0[22],p0[23]) };
        a = mfma32(w0.s, x1b0, a);
        a = mfma32(w1.s, x1b1, a);
        #pragma unroll
        for (int r = 0; r < 16; ++r)
            K1[(b * 32 + (r & 3) + 8 * (r >> 2) + 4 * h) * HW + pxg] = a[r];
    }
    // q2 -> Q2 (f32 channel-major)
    {
        f32x16_t a;
        #pragma unroll
        for (int r = 0; r < 16; ++r) a[r] = q2b[(r & 3) + 8 * (r >> 2) + 4 * h];
        const float* p0 = q2w + l31 * 32 + 8 * h;
        castu w0, w1;
        w0.u = (u32x4_t){ pk2(p0[0],p0[1]), pk2(p0[2],p0[3]), pk2(p0[4],p0[5]), pk2(p0[6],p0[7]) };
        w1.u = (u32x4_t){ pk2(p0[16],p0[17]), pk2(p0[18],p0[19]), pk2(p0[20],p0[21]), pk2(p0[22],p0[23]) };
        a = mfma32(w0.s, x1b0, a);
        a = mfma32(w1.s, x1b1, a);
        #pragma unroll
        for (int r = 0; r < 16; ++r)
            Q2[(b * 32 + (r & 3) + 8 * (r >> 2) + 4 * h) * HW + pxg] = a[r];
    }
    // k2 -> K2t (bf16 pixel-major)
    {
        f32x16_t a;
        #pragma unroll
        for (int r = 0; r < 16; ++r) a[r] = k2b[(r & 3) + 8 * (r >> 2) + 4 * h];
        const float* p0 = k2w + l31 * 32 + 8 * h;
        castu w0, w1;
        w0.u = (u32x4_t){ pk2(p0[0],p0[1]), pk2(p0[2],p0[3]), pk2(p0[4],p0[5]), pk2(p0[6],p0[7]) };
        w1.u = (u32x4_t){ pk2(p0[16],p0[17]), pk2(p0[18],p0[19]), pk2(p0[20],p0[21]), pk2(p0[22],p0[23]) };
        a = mfma32(w0.s, x1b0, a);
        a = mfma32(w1.s, x1b1, a);
        u32 Q[8];
        #pragma unroll
        for (int t2 = 0; t2 < 8; ++t2) Q[t2] = pk2(a[2 * t2], a[2 * t2 + 1]);
        *(uint2*)(K2t + bf_base + 4 * h)      = make_uint2(Q[0], Q[1]);
        *(uint2*)(K2t + bf_base + 8 + 4 * h)  = make_uint2(Q[2], Q[3]);
        *(uint2*)(K2t + bf_base + 16 + 4 * h) = make_uint2(Q[4], Q[5]);
        *(uint2*)(K2t + bf_base + 24 + 4 * h) = make_uint2(Q[6], Q[7]);
    }
    // q3 (x2) -> YQ (f32 channel-major)
    {
        f32x16_t a;
        #pragma unroll
        for (int r = 0; r < 16; ++r) a[r] = q3b[(r & 3) + 8 * (r >> 2) + 4 * h];
        const float* p0 = q3w + l31 * 32 + 8 * h;
        castu w0, w1;
        w0.u = (u32x4_t){ pk2(p0[0],p0[1]), pk2(p0[2],p0[3]), pk2(p0[4],p0[5]), pk2(p0[6],p0[7]) };
        w1.u = (u32x4_t){ pk2(p0[16],p0[17]), pk2(p0[18],p0[19]), pk2(p0[20],p0[21]), pk2(p0[22],p0[23]) };
        a = mfma32(w0.s, x2b0, a);
        a = mfma32(w1.s, x2b1, a);
        #pragma unroll
        for (int r = 0; r < 16; ++r)
            YQ[(b * 32 + (r & 3) + 8 * (r >> 2) + 4 * h) * HW + pxg] = a[r];
    }
    // k3 (x2) -> YKt (bf16 pixel-major)
    {
        f32x16_t a;
        #pragma unroll
        for (int r = 0; r < 16; ++r) a[r] = k3b[(r & 3) + 8 * (r >> 2) + 4 * h];
        const float* p0 = k3w + l31 * 32 + 8 * h;
        castu w0, w1;
        w0.u = (u32x4_t){ pk2(p0[0],p0[1]), pk2(p0[2],p0[3]), pk2(p0[4],p0[5]), pk2(p0[6],p0[7]) };
        w1.u = (u32x4_t){ pk2(p0[16],p0[17]), pk2(p0[18],p0[19]), pk2(p0[20],p0[21]), pk2(p0[22],p0[23]) };
        a = mfma32(w0.s, x2b0, a);
        a = mfma32(w1.s, x2b1, a);
        u32 Q[8];
        #pragma unroll
        for (int t2 = 0; t2 < 8; ++t2) Q[t2] = pk2(a[2 * t2], a[2 * t2 + 1]);
        *(uint2*)(YKt + bf_base + 4 * h)      = make_uint2(Q[0], Q[1]);
        *(uint2*)(YKt + bf_base + 8 + 4 * h)  = make_uint2(Q[2], Q[3]);
        *(uint2*)(YKt + bf_base + 16 + 4 * h) = make_uint2(Q[4], Q[5]);
        *(uint2*)(YKt + bf_base + 24 + 4 * h) = make_uint2(Q[6], Q[7]);
    }
}

// ---------------- K3: channel attention partial sums -------------------------
__global__ __launch_bounds__(256) void k_chan_part(
    const float* __restrict__ K1, const float* __restrict__ Q2,
    float* __restrict__ Scp)
{
    __shared__ float k1s[128 * 33];
    __shared__ float q2s[128 * 33];
    int chunk = blockIdx.x;
    int b = blockIdx.y;
    int n0 = chunk * 128;
    int t = threadIdx.x;
    for (int i = 0; i < 16; ++i){
        int idx = i * 256 + t;
        int c = idx >> 7, nl = idx & 127;
        k1s[nl * 33 + c] = K1[(b * 32 + c) * HW + n0 + nl];
        q2s[nl * 33 + c] = Q2[(b * 32 + c) * HW + n0 + nl];
    }
    __syncthreads();
    float acc[4] = {0.f, 0.f, 0.f, 0.f};
    int d = t & 31, c0 = t >> 5;
    for (int nl = 0; nl < 128; ++nl){
        float qv = q2s[nl * 33 + d];
        #pragma unroll
        for (int i = 0; i < 4; ++i)
            acc[i] = fmaf(k1s[nl * 33 + c0 + 8 * i], qv, acc[i]);
    }
    #pragma unroll
    for (int i = 0; i < 4; ++i)
        Scp[(b * 32 + chunk) * 1024 + (c0 + 8 * i) * 32 + d] = acc[i];
}

// ---------------- K4: channel softmax + fold conv6 W2 into M2 ----------------
__global__ __launch_bounds__(1024) void k_chan_fin(
    const float* __restrict__ Scp, const float* __restrict__ c6w,
    float* __restrict__ M2)
{
    __shared__ float pc[32 * 33];
    int b = blockIdx.x;
    int t = threadIdx.x;
    int c = t >> 5, d = t & 31;
    float s = 0.f;
    for (int k = 0; k < 32; ++k) s += Scp[(b * 32 + k) * 1024 + t];
    float mx = s;
    #pragma unroll
    for (int off = 16; off >= 1; off >>= 1) mx = fmaxf(mx, __shfl_xor(mx, off));
    float e = __expf(s - mx);
    float sum = e;
    #pragma unroll
    for (int off = 16; off >= 1; off >>= 1) sum += __shfl_xor(sum, off);
    pc[c * 33 + d] = e / sum;
    __syncthreads();
    int o = t >> 5, cc = t & 31;
    float m2 = 0.f;
    #pragma unroll
    for (int dd = 0; dd < 32; ++dd)
        m2 = fmaf(c6w[o * 64 + 32 + dd], pc[cc * 33 + dd], m2);
    M2[b * 1024 + o * 32 + cc] = m2;
}

// -------- K5: MFMA stats (l = sum exp), pipelined; fused YQ scale -> YQ2 tiled
__global__ __launch_bounds__(256, 4) void k_stats_mfma(
    const unsigned short* __restrict__ Q1t, const unsigned short* __restrict__ K2t,
    const float* __restrict__ YQ, unsigned short* __restrict__ YQ2)
{
    __shared__ float red[4][16][64];
    __shared__ float ls[32];
    int t = threadIdx.x, wid = t >> 6, lane = t & 63;
    int l31 = lane & 31, h = lane >> 5;
    int b = blockIdx.x >> 7, ntile = blockIdx.x & 127;
    int n0 = ntile * 32;
    const unsigned short* q = Q1t + (size_t)b * 131072;
    const unsigned short* k = K2t + (size_t)b * 131072;
    bf16x8_t a0 = ldb(q + (size_t)(n0 + l31) * 32 + 8 * h);
    bf16x8_t a1 = ldb(q + (size_t)(n0 + l31) * 32 + 16 + 8 * h);
    float accl[16];
    #pragma unroll
    for (int r = 0; r < 16; ++r) accl[r] = 0.f;

    const unsigned short* kp = k + ((size_t)(wid << 10) + l31) * 32 + 8 * h;
    // prologue: S for tile 0; frags for tile 1
    bf16x8_t b0 = ldb(kp), b1 = ldb(kp + 16);
    f32x16_t s_cur;
    #pragma unroll
    for (int r = 0; r < 16; ++r) s_cur[r] = 0.f;
    s_cur = mfma32(a0, b0, s_cur);
    s_cur = mfma32(a1, b1, s_cur);
    kp += 1024;
    bf16x8_t b0n = ldb(kp), b1n = ldb(kp + 16);

    #pragma unroll 4
    for (int i = 0; i < 32; ++i){
        // S for tile i+1 (independent of the exp below)
        f32x16_t s_nxt;
        #pragma unroll
        for (int r = 0; r < 16; ++r) s_nxt[r] = 0.f;
        s_nxt = mfma32(a0, b0n, s_nxt);
        s_nxt = mfma32(a1, b1n, s_nxt);
        // prefetch frags for tile i+2
        kp += (i < 30) ? 1024 : 0;
        bf16x8_t b0nn = ldb(kp), b1nn = ldb(kp + 16);
        // exp of tile i
        #pragma unroll
        for (int r = 0; r < 16; ++r) accl[r] += ex2(s_cur[r]);
        s_cur = s_nxt; b0n = b0nn; b1n = b1nn;
    }
    #pragma unroll
    for (int r = 0; r < 16; ++r) red[wid][r][lane] = accl[r];
    __syncthreads();
    if (wid == 0){
        #pragma unroll
        for (int r = 0; r < 16; ++r){
            float v = red[0][r][lane] + red[1][r][lane] + red[2][r][lane] + red[3][r][lane];
            #pragma unroll
            for (int off = 16; off >= 1; off >>= 1) v += __shfl_xor(v, off);
            if (l31 == 0)
                ls[(r & 3) + 8 * (r >> 2) + 4 * h] = 1.0f / v;
        }
    }
    __syncthreads();
    // fused scale: YQ2 tile-blocked [b][ntile][c][n] = bf16(YQ[c][n0+n] / l[n0+n])
    size_t obase = ((size_t)(b * 128 + ntile)) * 1024;
    #pragma unroll
    for (int p = 0; p < 4; ++p){
        int idx = (p << 8) + t;
        int c = idx >> 5, n = idx & 31;
        size_t g = (size_t)(b * 32 + c) * HW + n0 + n;
        YQ2[obase + idx] = f2bf(YQ[g] * ls[n]);
    }
}

// ------- K7: MFMA value pass (pipelined) + conv6 + residual -------------------
__global__ __launch_bounds__(256, 4) void k_attn_mfma(
    const unsigned short* __restrict__ Q1t, const unsigned short* __restrict__ K2t,
    const unsigned short* __restrict__ YKt, const unsigned short* __restrict__ YQ2,
    const float* __restrict__ M2, const float* __restrict__ c6w, const float* __restrict__ c6b,
    const float* __restrict__ x, float* __restrict__ xout)
{
    __shared__ float red[4][16][64];
    int t = threadIdx.x, wid = t >> 6, lane = t & 63;
    int l31 = lane & 31, h = lane >> 5;
    int b = blockIdx.x >> 7, mtile = blockIdx.x & 127;
    int m0 = mtile * 32;
    size_t boff = (size_t)b * 131072;
    const unsigned short* qb = Q1t + boff;
    const unsigned short* kb = K2t + boff;

    bf16x8_t kb0 = ldb(kb + (size_t)(m0 + l31) * 32 + 8 * h);
    bf16x8_t kb1 = ldb(kb + (size_t)(m0 + l31) * 32 + 16 + 8 * h);

    f32x16_t oacc;
    #pragma unroll
    for (int r = 0; r < 16; ++r) oacc[r] = 0.f;

    const unsigned short* qp = qb + ((size_t)(wid << 10) + l31) * 32 + 8 * h;
    // YQ2 tile-blocked: [b][ntile][c=l31][n-in-tile]; wave wid starts at ntile=wid*32
    const unsigned short* yp = YQ2 + ((size_t)(b * 128 + (wid << 5)) * 32 + l31) * 32 + 8 * h;

    // prologue: tile 0 frags + S; tile 1 frags
    bf16x8_t a0 = ldb(qp), a1 = ldb(qp + 16);
    bf16x8_t y0 = ldb(yp), y1 = ldb(yp + 16);
    f32x16_t s_cur;
    #pragma unroll
    for (int r = 0; r < 16; ++r) s_cur[r] = 0.f;
    s_cur = mfma32(a0, kb0, s_cur);
    s_cur = mfma32(a1, kb1, s_cur);
    qp += 1024; yp += 1024;
    bf16x8_t a0n = ldb(qp), a1n = ldb(qp + 16);
    bf16x8_t y0n = ldb(yp), y1n = ldb(yp + 16);

    #pragma unroll 4
    for (int i = 0; i < 32; ++i){
        // S for tile i+1 while converting tile i
        f32x16_t s_nxt;
        #pragma unroll
        for (int r = 0; r < 16; ++r) s_nxt[r] = 0.f;
        s_nxt = mfma32(a0n, kb0, s_nxt);
        s_nxt = mfma32(a1n, kb1, s_nxt);
        // prefetch frags for tile i+2
        int adv = (i < 30) ? 1024 : 0;
        qp += adv; yp += adv;
        bf16x8_t a0nn = ldb(qp), a1nn = ldb(qp + 16);
        bf16x8_t y0nn = ldb(yp), y1nn = ldb(yp + 16);
        // E = exp2(S'); C-layout -> B-frag via permlane32_swap
        u32 P[8];
        #pragma unroll
        for (int tt = 0; tt < 8; ++tt)
            P[tt] = pk2(ex2(s_cur[2 * tt]), ex2(s_cur[2 * tt + 1]));
        bf16x8_t e0, e1;
        cd2bfrag(P, e0, e1);
        oacc = mfma32(y0, e0, oacc);
        oacc = mfma32(y1, e1, oacc);
        s_cur = s_nxt;
        a0n = a0nn; a1n = a1nn;
        y0 = y0n; y1 = y1n; y0n = y0nn; y1n = y1nn;
    }
    #pragma unroll
    for (int r = 0; r < 16; ++r) red[wid][r][lane] = oacc[r];
    __syncthreads();
    if (wid != 0) return;
    #pragma unroll
    for (int r = 0; r < 16; ++r)
        oacc[r] = red[0][r][lane] + red[1][r][lane] + red[2][r][lane] + red[3][r][lane];

    u32 P[8];
    #pragma unroll
    for (int tt = 0; tt < 8; ++tt) P[tt] = pk2(oacc[2 * tt], oacc[2 * tt + 1]);
    bf16x8_t xb0, xb1;
    cd2bfrag(P, xb0, xb1);

    const float* w1p = c6w + l31 * 64;
    const float* m2p = M2 + b * 1024 + l31 * 32;
    int cb0 = 8 * h, cb1 = 16 + 8 * h;
    castu wa0, wa1, ma0, ma1;
    wa0.u = (u32x4_t){ pk2(w1p[cb0], w1p[cb0+1]), pk2(w1p[cb0+2], w1p[cb0+3]),
                       pk2(w1p[cb0+4], w1p[cb0+5]), pk2(w1p[cb0+6], w1p[cb0+7]) };
    wa1.u = (u32x4_t){ pk2(w1p[cb1], w1p[cb1+1]), pk2(w1p[cb1+2], w1p[cb1+3]),
                       pk2(w1p[cb1+4], w1p[cb1+5]), pk2(w1p[cb1+6], w1p[cb1+7]) };
    ma0.u = (u32x4_t){ pk2(m2p[cb0], m2p[cb0+1]), pk2(m2p[cb0+2], m2p[cb0+3]),
                       pk2(m2p[cb0+4], m2p[cb0+5]), pk2(m2p[cb0+6], m2p[cb0+7]) };
    ma1.u = (u32x4_t){ pk2(m2p[cb1], m2p[cb1+1]), pk2(m2p[cb1+2], m2p[cb1+3]),
                       pk2(m2p[cb1+4], m2p[cb1+5]), pk2(m2p[cb1+6], m2p[cb1+7]) };
    const unsigned short* ykp = YKt + boff + (size_t)(m0 + l31) * 32;
    bf16x8_t ykb0 = ldb(ykp + 8 * h);
    bf16x8_t ykb1 = ldb(ykp + 16 + 8 * h);

    f32x16_t facc;
    #pragma unroll
    for (int r = 0; r < 16; ++r) facc[r] = c6b[(r & 3) + 8 * (r >> 2) + 4 * h];
    facc = mfma32(wa0.s, xb0, facc);
    facc = mfma32(wa1.s, xb1, facc);
    facc = mfma32(ma0.s, ykb0, facc);
    facc = mfma32(ma1.s, ykb1, facc);

    #pragma unroll
    for (int r = 0; r < 16; ++r){
        int o = (r & 3) + 8 * (r >> 2) + 4 * h;
        size_t gi = ((size_t)(b * 32 + o) << 12) + m0 + l31;
        xout[gi] = x[gi] + facc[r];
    }
}

// ---------------- K8: score conv + residual on y (LDS-staged) -----------------
__global__ __launch_bounds__(256) void k_score(
    const float* __restrict__ xout, const float* __restrict__ y,
    const float* __restrict__ sw, const float* __restrict__ sb,
    float* __restrict__ yout)
{
    __shared__ float xs[3][32][66];
    __shared__ float red[4][64];
    int tid = threadIdx.x;
    int h = blockIdx.x, b = blockIdx.y;
    for (int i = 0; i < 24; ++i){
        int idx = i * 256 + tid;
        int w = idx & 63, ic = (idx >> 6) & 31, dr = idx >> 11;
        int hr = h + dr - 1;
        xs[dr][ic][1 + w] = (hr >= 0 && hr < 64) ? xout[((b * 32 + ic) << 12) + (hr << 6) + w] : 0.f;
    }
    if (tid < 96){ xs[tid >> 5][tid & 31][0] = 0.f; }
    else if (tid < 192){ int u = tid - 96; xs[u >> 5][u & 31][65] = 0.f; }
    __syncthreads();
    int w = tid & 63, icg = tid >> 6;
    float p = 0.f;
    #pragma unroll
    for (int i = 0; i < 8; ++i){
        int ic = icg * 8 + i;
        #pragma unroll
        for (int tap = 0; tap < 9; ++tap)
            p = fmaf(sw[ic * 9 + tap], xs[tap / 3][ic][w + tap % 3], p);
    }
    red[icg][w] = p;
    __syncthreads();
    if (tid < 64){
        int px = (h << 6) + tid;
        yout[b * HW + px] = y[b * HW + px] + sb[0]
                          + red[0][tid] + red[1][tid] + red[2][tid] + red[3][tid];
    }
}

extern "C" void kernel_launch(void* const* d_in, const int* in_sizes, int n_in,
                              void* d_out, int out_size, void* d_ws, size_t ws_size,
                              hipStream_t stream)
{
    (void)in_sizes; (void)n_in; (void)out_size; (void)ws_size;
    const float* x      = (const float*)d_in[0];
    const float* y      = (const float*)d_in[1];
    const float* conv_w = (const float*)d_in[2];
    const float* conv_b = (const float*)d_in[3];
    const float* score_w= (const float*)d_in[4];
    const float* score_b= (const float*)d_in[5];
    const float* c132_w = (const float*)d_in[6];
    const float* c132_b = (const float*)d_in[7];
    const float* q1w = (const float*)d_in[8];  const float* q1b = (const float*)d_in[9];
    const float* k1w = (const float*)d_in[10]; const float* k1b = (const float*)d_in[11];
    const float* q2w = (const float*)d_in[12]; const float* q2b = (const float*)d_in[13];
    const float* k2w = (const float*)d_in[14]; const float* k2b = (const float*)d_in[15];
    const float* q3w = (const float*)d_in[16]; const float* q3b = (const float*)d_in[17];
    const float* k3w = (const float*)d_in[18]; const float* k3b = (const float*)d_in[19];
    const float* c6w = (const float*)d_in[20]; const float* c6b = (const float*)d_in[21];

    float* ws = (float*)d_ws;
    const size_t SZ = 1048576;            // 8*32*4096
    float* Scp = ws;                      // 262144 f32
    float* M2  = ws + 262144;             // 8192 f32
    float* K1  = ws + 2 * SZ;             // 1M f32
    float* Q2  = ws + 3 * SZ;             // 1M f32
    float* YQf = ws + 4 * SZ;             // 1M f32
    unsigned short* Q1t = (unsigned short*)(ws + 5 * SZ);            // 1M bf16
    unsigned short* K2t = (unsigned short*)(ws + 5 * SZ + SZ / 2);   // 1M bf16
    unsigned short* YKt = (unsigned short*)(ws + 6 * SZ);            // 1M bf16
    unsigned short* YQ2 = (unsigned short*)(ws + 6 * SZ + SZ / 2);   // 1M bf16 (tile-blocked)

    float* xout = (float*)d_out;
    float* yout = xout + SZ;

    k_front_mfma<<<dim3(32, 8), 256, 0, stream>>>(
        x, y, conv_w, conv_b, c132_w, c132_b,
        q1w, q1b, k1w, k1b, q2w, q2b, k2w, k2b, q3w, q3b, k3w, k3b,
        K1, Q2, YQf, Q1t, K2t, YKt);
    k_chan_part<<<dim3(32, 8), 256, 0, stream>>>(K1, Q2, Scp);
    k_chan_fin<<<8, 1024, 0, stream>>>(Scp, c6w, M2);
    k_stats_mfma<<<1024, 256, 0, stream>>>(Q1t, K2t, YQf, YQ2);
    k_attn_mfma<<<1024, 256, 0, stream>>>(Q1t, K2t, YKt, YQ2, M2, c6w, c6b, x, xout);
    k_score<<<dim3(64, 8), 256, 0, stream>>>(xout, y, score_w, score_b, yout);
}

// Round 10
// 107.075 us; speedup vs baseline: 2.6369x; 1.0188x over previous
//
#include <hip/hip_runtime.h>
#include <hip/hip_bf16.h>
#include <math.h>

#define HW 4096

typedef short bf16x8_t __attribute__((ext_vector_type(8)));   // 8 bf16 (4 VGPRs)
typedef float f32x16_t __attribute__((ext_vector_type(16)));
typedef unsigned int u32;
typedef unsigned int u32x4_t __attribute__((ext_vector_type(4)));
typedef int i32x2_t __attribute__((ext_vector_type(2)));

union castu { u32x4_t u; bf16x8_t s; };

static __device__ __forceinline__ unsigned short f2bf(float f){
    union { __bf16 b; unsigned short u; } c; c.b = (__bf16)f; return c.u;
}
static __device__ __forceinline__ u32 pk2(float lo, float hi){
    return ((u32)f2bf(hi) << 16) | (u32)f2bf(lo);
}
static __device__ __forceinline__ bf16x8_t ldb(const unsigned short* p){
    return *reinterpret_cast<const bf16x8_t*>(p);
}
static __device__ __forceinline__ bf16x8_t ld_xs(const unsigned short* p){
    uint2 lo = *(const uint2*)(p);
    uint2 hi = *(const uint2*)(p + 4);
    castu c; c.u = (u32x4_t){lo.x, lo.y, hi.x, hi.y};
    return c.s;
}
static __device__ __forceinline__ f32x16_t mfma32(bf16x8_t a, bf16x8_t b, f32x16_t c){
    return __builtin_amdgcn_mfma_f32_32x32x16_bf16(a, b, c, 0, 0, 0);
}
static __device__ __forceinline__ float ex2(float x){
    return __builtin_amdgcn_exp2f(x);
}
// C/D-layout (32x32) -> B-frag conversion via permlane32_swap.
static __device__ __forceinline__ void cd2bfrag(const u32 P[8], bf16x8_t& b0, bf16x8_t& b1){
    i32x2_t s02 = __builtin_amdgcn_permlane32_swap((int)P[0], (int)P[2], false, false);
    i32x2_t s13 = __builtin_amdgcn_permlane32_swap((int)P[1], (int)P[3], false, false);
    i32x2_t s46 = __builtin_amdgcn_permlane32_swap((int)P[4], (int)P[6], false, false);
    i32x2_t s57 = __builtin_amdgcn_permlane32_swap((int)P[5], (int)P[7], false, false);
    castu c0, c1;
    c0.u = (u32x4_t){ (u32)s02[0], (u32)s13[0], (u32)s02[1], (u32)s13[1] };
    c1.u = (u32x4_t){ (u32)s46[0], (u32)s57[0], (u32)s46[1], (u32)s57[1] };
    b0 = c0.s; b1 = c1.s;
}

#define LOG2E 1.44269504088896340736f

// ---------------- K1: MFMA front convs + six 1x1 projections -----------------
__global__ __launch_bounds__(256, 1) void k_front_mfma(
    const float* __restrict__ x, const float* __restrict__ y,
    const float* __restrict__ conv_w, const float* __restrict__ conv_b,
    const float* __restrict__ c132_w, const float* __restrict__ c132_b,
    const float* __restrict__ q1w, const float* __restrict__ q1b,
    const float* __restrict__ k1w, const float* __restrict__ k1b,
    const float* __restrict__ q2w, const float* __restrict__ q2b,
    const float* __restrict__ k2w, const float* __restrict__ k2b,
    const float* __restrict__ q3w, const float* __restrict__ q3b,
    const float* __restrict__ k3w, const float* __restrict__ k3b,
    float* __restrict__ K1, float* __restrict__ Q2, float* __restrict__ YQ,
    unsigned short* __restrict__ Q1t, unsigned short* __restrict__ K2t,
    unsigned short* __restrict__ YKt)
{
    __shared__ unsigned short xs[4 * 68 * 36];
    __shared__ float ys[4 * 68];
    __shared__ u32 wplane[18 * 4 * 64];
    __shared__ u32 wyplane[4 * 64];
    __shared__ u32 c1plane[4 * 64];

    int tid = threadIdx.x;
    int h0 = blockIdx.x * 2, b = blockIdx.y;

    #pragma unroll
    for (int i = 0; i < 32; ++i){
        int idx = i * 256 + tid;
        int w = idx & 63, ic = (idx >> 6) & 31, dr = idx >> 11;
        int hr = h0 - 1 + dr;
        float v = (hr >= 0 && hr < 64) ? x[((b * 32 + ic) << 12) + (hr << 6) + w] : 0.f;
        xs[(dr * 68 + w + 1) * 36 + ic] = f2bf(v);
    }
    {
        int dr = tid >> 6, ic = tid & 31, side = (tid >> 5) & 1;
        xs[(dr * 68 + (side ? 65 : 0)) * 36 + ic] = 0;
    }
    for (int idx = tid; idx < 272; idx += 256){
        int dr = idx / 68, wp = idx % 68;
        int hr = h0 - 1 + dr, w = wp - 1;
        ys[idx] = (hr >= 0 && hr < 64 && w >= 0 && w < 64) ? y[(b << 12) + (hr << 6) + w] : 0.f;
    }
    for (int e = tid; e < 4608; e += 256){
        int f = e >> 8, wi = (e >> 6) & 3, ln = e & 63;
        int t = f >> 1, j = f & 1, hh = ln >> 5, ll = ln & 31;
        int ic0 = 16 * j + 8 * hh + 2 * wi;
        int co0 = 5 * (ic0 >> 2) + (ic0 & 3);
        int ic1 = ic0 + 1;
        int co1 = 5 * (ic1 >> 2) + (ic1 & 3);
        wplane[e] = pk2(conv_w[ll * 360 + co0 * 9 + t], conv_w[ll * 360 + co1 * 9 + t]);
    }
    {
        int wi = tid >> 6, ln = tid & 63, hh = ln >> 5, ll = ln & 31;
        u32 vy = 0, vc = 0;
        if (hh == 0){
            int t0 = 2 * wi, t1 = 2 * wi + 1;
            float s0 = 0.f, s1 = 0.f;
            #pragma unroll
            for (int g = 0; g < 8; ++g){
                s0 += conv_w[ll * 360 + (5 * g + 4) * 9 + t0];
                s1 += conv_w[ll * 360 + (5 * g + 4) * 9 + t1];
            }
            vy = pk2(s0, s1);
            vc = pk2(c132_w[ll * 9 + t0], c132_w[ll * 9 + t1]);
        } else if (wi == 0){
            float s0 = 0.f;
            #pragma unroll
            for (int g = 0; g < 8; ++g) s0 += conv_w[ll * 360 + (5 * g + 4) * 9 + 8];
            vy = pk2(s0, 0.f);
            vc = pk2(c132_w[ll * 9 + 8], 0.f);
        }
        wyplane[wi * 64 + ln] = vy;
        c1plane[wi * 64 + ln] = vc;
    }
    __syncthreads();

    int lane = tid & 63, wid = tid >> 6;
    int l31 = lane & 31, h = lane >> 5;
    int wr = wid >> 1, toff = (wid & 1) * 32;
    int wpB = toff + l31;

    bf16x8_t wA[18];
    #pragma unroll
    for (int f = 0; f < 18; ++f){
        castu c;
        c.u = (u32x4_t){ wplane[(f * 4 + 0) * 64 + lane], wplane[(f * 4 + 1) * 64 + lane],
                         wplane[(f * 4 + 2) * 64 + lane], wplane[(f * 4 + 3) * 64 + lane] };
        wA[f] = c.s;
    }
    castu wyf, c1f;
    wyf.u = (u32x4_t){ wyplane[lane], wyplane[64 + lane], wyplane[128 + lane], wyplane[192 + lane] };
    c1f.u = (u32x4_t){ c1plane[lane], c1plane[64 + lane], c1plane[128 + lane], c1plane[192 + lane] };

    float yv[8];
    #pragma unroll
    for (int i = 0; i < 8; ++i){
        int tt = 8 * h + i;
        yv[i] = (tt < 9) ? ys[(wr + tt / 3) * 68 + wpB + (tt % 3)] : 0.f;
    }
    castu yf;
    yf.u = (u32x4_t){ pk2(yv[0], yv[1]), pk2(yv[2], yv[3]), pk2(yv[4], yv[5]), pk2(yv[6], yv[7]) };

    f32x16_t accE, accO, accY, acc2;
    #pragma unroll
    for (int r = 0; r < 16; ++r){
        int oc = (r & 3) + 8 * (r >> 2) + 4 * h;
        accE[r] = 0.f; accO[r] = 0.f;
        accY[r] = conv_b[oc]; acc2[r] = c132_b[oc];
    }
    #pragma unroll
    for (int t = 0; t < 9; ++t){
        int base = ((wr + t / 3) * 68 + wpB + (t % 3)) * 36 + 8 * h;
        bf16x8_t b0 = ld_xs(xs + base);
        bf16x8_t b1 = ld_xs(xs + base + 16);
        if (t & 1){
            accO = mfma32(wA[t * 2 + 0], b0, accO);
            accO = mfma32(wA[t * 2 + 1], b1, accO);
        } else {
            accE = mfma32(wA[t * 2 + 0], b0, accE);
            accE = mfma32(wA[t * 2 + 1], b1, accE);
        }
    }
    accY = mfma32(wyf.s, yf.s, accY);
    acc2 = mfma32(c1f.s, yf.s, acc2);

    f32x16_t x1v;
    #pragma unroll
    for (int r = 0; r < 16; ++r){
        float v = accE[r] + accO[r] + accY[r];
        x1v[r] = v > 0.f ? v : 0.f;
    }
    u32 P[8];
    bf16x8_t x1b0, x1b1, x2b0, x2b1;
    #pragma unroll
    for (int t2 = 0; t2 < 8; ++t2) P[t2] = pk2(x1v[2 * t2], x1v[2 * t2 + 1]);
    cd2bfrag(P, x1b0, x1b1);
    #pragma unroll
    for (int t2 = 0; t2 < 8; ++t2) P[t2] = pk2(acc2[2 * t2], acc2[2 * t2 + 1]);
    cd2bfrag(P, x2b0, x2b1);

    int pxg = (h0 + wr) * 64 + toff + l31;
    size_t bf_base = ((size_t)b * HW + pxg) * 32;

    // q1 -> Q1t (bf16 pixel-major, pre-scaled by log2e)
    {
        f32x16_t a;
        #pragma unroll
        for (int r = 0; r < 16; ++r) a[r] = q1b[(r & 3) + 8 * (r >> 2) + 4 * h];
        const float* p0 = q1w + l31 * 32 + 8 * h;
        castu w0, w1;
        w0.u = (u32x4_t){ pk2(p0[0],p0[1]), pk2(p0[2],p0[3]), pk2(p0[4],p0[5]), pk2(p0[6],p0[7]) };
        w1.u = (u32x4_t){ pk2(p0[16],p0[17]), pk2(p0[18],p0[19]), pk2(p0[20],p0[21]), pk2(p0[22],p0[23]) };
        a = mfma32(w0.s, x1b0, a);
        a = mfma32(w1.s, x1b1, a);
        u32 Q[8];
        #pragma unroll
        for (int t2 = 0; t2 < 8; ++t2) Q[t2] = pk2(a[2 * t2] * LOG2E, a[2 * t2 + 1] * LOG2E);
        *(uint2*)(Q1t + bf_base + 4 * h)      = make_uint2(Q[0], Q[1]);
        *(uint2*)(Q1t + bf_base + 8 + 4 * h)  = make_uint2(Q[2], Q[3]);
        *(uint2*)(Q1t + bf_base + 16 + 4 * h) = make_uint2(Q[4], Q[5]);
        *(uint2*)(Q1t + bf_base + 24 + 4 * h) = make_uint2(Q[6], Q[7]);
    }
    // k1 -> K1 (f32 channel-major)
    {
        f32x16_t a;
        #pragma unroll
        for (int r = 0; r < 16; ++r) a[r] = k1b[(r & 3) + 8 * (r >> 2) + 4 * h];
        const float* p0 = k1w + l31 * 32 + 8 * h;
        castu w0, w1;
        w0.u = (u32x4_t){ pk2(p0[0],p0[1]), pk2(p0[2],p0[3]), pk2(p0[4],p0[5]), pk2(p0[6],p0[7]) };
        w1.u = (u32x4_t){ pk2(p0[16],p0[17]), pk2(p0[18],p0[19]), pk2(p0[20],p0[21]), pk2(p0[22],p0[23]) };
        a = mfma32(w0.s, x1b0, a);
        a = mfma32(w1.s, x1b1, a);
        #pragma unroll
        for (int r = 0; r < 16; ++r)
            K1[(b * 32 + (r & 3) + 8 * (r >> 2) + 4 * h) * HW + pxg] = a[r];
    }
    // q2 -> Q2 (f32 channel-major)
    {
        f32x16_t a;
        #pragma unroll
        for (int r = 0; r < 16; ++r) a[r] = q2b[(r & 3) + 8 * (r >> 2) + 4 * h];
        const float* p0 = q2w + l31 * 32 + 8 * h;
        castu w0, w1;
        w0.u = (u32x4_t){ pk2(p0[0],p0[1]), pk2(p0[2],p0[3]), pk2(p0[4],p0[5]), pk2(p0[6],p0[7]) };
        w1.u = (u32x4_t){ pk2(p0[16],p0[17]), pk2(p0[18],p0[19]), pk2(p0[20],p0[21]), pk2(p0[22],p0[23]) };
        a = mfma32(w0.s, x1b0, a);
        a = mfma32(w1.s, x1b1, a);
        #pragma unroll
        for (int r = 0; r < 16; ++r)
            Q2[(b * 32 + (r & 3) + 8 * (r >> 2) + 4 * h) * HW + pxg] = a[r];
    }
    // k2 -> K2t (bf16 pixel-major)
    {
        f32x16_t a;
        #pragma unroll
        for (int r = 0; r < 16; ++r) a[r] = k2b[(r & 3) + 8 * (r >> 2) + 4 * h];
        const float* p0 = k2w + l31 * 32 + 8 * h;
        castu w0, w1;
        w0.u = (u32x4_t){ pk2(p0[0],p0[1]), pk2(p0[2],p0[3]), pk2(p0[4],p0[5]), pk2(p0[6],p0[7]) };
        w1.u = (u32x4_t){ pk2(p0[16],p0[17]), pk2(p0[18],p0[19]), pk2(p0[20],p0[21]), pk2(p0[22],p0[23]) };
        a = mfma32(w0.s, x1b0, a);
        a = mfma32(w1.s, x1b1, a);
        u32 Q[8];
        #pragma unroll
        for (int t2 = 0; t2 < 8; ++t2) Q[t2] = pk2(a[2 * t2], a[2 * t2 + 1]);
        *(uint2*)(K2t + bf_base + 4 * h)      = make_uint2(Q[0], Q[1]);
        *(uint2*)(K2t + bf_base + 8 + 4 * h)  = make_uint2(Q[2], Q[3]);
        *(uint2*)(K2t + bf_base + 16 + 4 * h) = make_uint2(Q[4], Q[5]);
        *(uint2*)(K2t + bf_base + 24 + 4 * h) = make_uint2(Q[6], Q[7]);
    }
    // q3 (x2) -> YQ (f32 channel-major)
    {
        f32x16_t a;
        #pragma unroll
        for (int r = 0; r < 16; ++r) a[r] = q3b[(r & 3) + 8 * (r >> 2) + 4 * h];
        const float* p0 = q3w + l31 * 32 + 8 * h;
        castu w0, w1;
        w0.u = (u32x4_t){ pk2(p0[0],p0[1]), pk2(p0[2],p0[3]), pk2(p0[4],p0[5]), pk2(p0[6],p0[7]) };
        w1.u = (u32x4_t){ pk2(p0[16],p0[17]), pk2(p0[18],p0[19]), pk2(p0[20],p0[21]), pk2(p0[22],p0[23]) };
        a = mfma32(w0.s, x2b0, a);
        a = mfma32(w1.s, x2b1, a);
        #pragma unroll
        for (int r = 0; r < 16; ++r)
            YQ[(b * 32 + (r & 3) + 8 * (r >> 2) + 4 * h) * HW + pxg] = a[r];
    }
    // k3 (x2) -> YKt (bf16 pixel-major)
    {
        f32x16_t a;
        #pragma unroll
        for (int r = 0; r < 16; ++r) a[r] = k3b[(r & 3) + 8 * (r >> 2) + 4 * h];
        const float* p0 = k3w + l31 * 32 + 8 * h;
        castu w0, w1;
        w0.u = (u32x4_t){ pk2(p0[0],p0[1]), pk2(p0[2],p0[3]), pk2(p0[4],p0[5]), pk2(p0[6],p0[7]) };
        w1.u = (u32x4_t){ pk2(p0[16],p0[17]), pk2(p0[18],p0[19]), pk2(p0[20],p0[21]), pk2(p0[22],p0[23]) };
        a = mfma32(w0.s, x2b0, a);
        a = mfma32(w1.s, x2b1, a);
        u32 Q[8];
        #pragma unroll
        for (int t2 = 0; t2 < 8; ++t2) Q[t2] = pk2(a[2 * t2], a[2 * t2 + 1]);
        *(uint2*)(YKt + bf_base + 4 * h)      = make_uint2(Q[0], Q[1]);
        *(uint2*)(YKt + bf_base + 8 + 4 * h)  = make_uint2(Q[2], Q[3]);
        *(uint2*)(YKt + bf_base + 16 + 4 * h) = make_uint2(Q[4], Q[5]);
        *(uint2*)(YKt + bf_base + 24 + 4 * h) = make_uint2(Q[6], Q[7]);
    }
}

// ---------------- K3: channel attention partial sums -------------------------
// grid 256: b = blk & 7 (XCD-resident), chunk = blk >> 3
__global__ __launch_bounds__(256) void k_chan_part(
    const float* __restrict__ K1, const float* __restrict__ Q2,
    float* __restrict__ Scp)
{
    __shared__ float k1s[128 * 33];
    __shared__ float q2s[128 * 33];
    int b = blockIdx.x & 7;
    int chunk = blockIdx.x >> 3;
    int n0 = chunk * 128;
    int t = threadIdx.x;
    for (int i = 0; i < 16; ++i){
        int idx = i * 256 + t;
        int c = idx >> 7, nl = idx & 127;
        k1s[nl * 33 + c] = K1[(b * 32 + c) * HW + n0 + nl];
        q2s[nl * 33 + c] = Q2[(b * 32 + c) * HW + n0 + nl];
    }
    __syncthreads();
    float acc[4] = {0.f, 0.f, 0.f, 0.f};
    int d = t & 31, c0 = t >> 5;
    for (int nl = 0; nl < 128; ++nl){
        float qv = q2s[nl * 33 + d];
        #pragma unroll
        for (int i = 0; i < 4; ++i)
            acc[i] = fmaf(k1s[nl * 33 + c0 + 8 * i], qv, acc[i]);
    }
    #pragma unroll
    for (int i = 0; i < 4; ++i)
        Scp[(b * 32 + chunk) * 1024 + (c0 + 8 * i) * 32 + d] = acc[i];
}

// ---------------- K4: channel softmax + fold conv6 W2 into M2 ----------------
__global__ __launch_bounds__(1024) void k_chan_fin(
    const float* __restrict__ Scp, const float* __restrict__ c6w,
    float* __restrict__ M2)
{
    __shared__ float pc[32 * 33];
    int b = blockIdx.x;
    int t = threadIdx.x;
    int c = t >> 5, d = t & 31;
    float s = 0.f;
    for (int k = 0; k < 32; ++k) s += Scp[(b * 32 + k) * 1024 + t];
    float mx = s;
    #pragma unroll
    for (int off = 16; off >= 1; off >>= 1) mx = fmaxf(mx, __shfl_xor(mx, off));
    float e = __expf(s - mx);
    float sum = e;
    #pragma unroll
    for (int off = 16; off >= 1; off >>= 1) sum += __shfl_xor(sum, off);
    pc[c * 33 + d] = e / sum;
    __syncthreads();
    int o = t >> 5, cc = t & 31;
    float m2 = 0.f;
    #pragma unroll
    for (int dd = 0; dd < 32; ++dd)
        m2 = fmaf(c6w[o * 64 + 32 + dd], pc[cc * 33 + dd], m2);
    M2[b * 1024 + o * 32 + cc] = m2;
}

// -------- K5: MFMA stats (l = sum exp), pipelined; fused YQ scale -> YQ2 tiled
// b = blk & 7 so each XCD keeps one batch's K2t stream L2-resident
__global__ __launch_bounds__(256, 4) void k_stats_mfma(
    const unsigned short* __restrict__ Q1t, const unsigned short* __restrict__ K2t,
    const float* __restrict__ YQ, unsigned short* __restrict__ YQ2)
{
    __shared__ float red[4][16][64];
    __shared__ float ls[32];
    int t = threadIdx.x, wid = t >> 6, lane = t & 63;
    int l31 = lane & 31, h = lane >> 5;
    int b = blockIdx.x & 7, ntile = blockIdx.x >> 3;
    int n0 = ntile * 32;
    const unsigned short* q = Q1t + (size_t)b * 131072;
    const unsigned short* k = K2t + (size_t)b * 131072;
    bf16x8_t a0 = ldb(q + (size_t)(n0 + l31) * 32 + 8 * h);
    bf16x8_t a1 = ldb(q + (size_t)(n0 + l31) * 32 + 16 + 8 * h);
    float accl[16];
    #pragma unroll
    for (int r = 0; r < 16; ++r) accl[r] = 0.f;

    const unsigned short* kp = k + ((size_t)(wid << 10) + l31) * 32 + 8 * h;
    // prologue: S for tile 0; frags for tile 1
    bf16x8_t b0 = ldb(kp), b1 = ldb(kp + 16);
    f32x16_t s_cur;
    #pragma unroll
    for (int r = 0; r < 16; ++r) s_cur[r] = 0.f;
    s_cur = mfma32(a0, b0, s_cur);
    s_cur = mfma32(a1, b1, s_cur);
    kp += 1024;
    bf16x8_t b0n = ldb(kp), b1n = ldb(kp + 16);

    #pragma unroll 4
    for (int i = 0; i < 32; ++i){
        // S for tile i+1 (independent of the exp below)
        f32x16_t s_nxt;
        #pragma unroll
        for (int r = 0; r < 16; ++r) s_nxt[r] = 0.f;
        __builtin_amdgcn_s_setprio(1);
        s_nxt = mfma32(a0, b0n, s_nxt);
        s_nxt = mfma32(a1, b1n, s_nxt);
        __builtin_amdgcn_s_setprio(0);
        // prefetch frags for tile i+2
        kp += (i < 30) ? 1024 : 0;
        bf16x8_t b0nn = ldb(kp), b1nn = ldb(kp + 16);
        // exp of tile i
        #pragma unroll
        for (int r = 0; r < 16; ++r) accl[r] += ex2(s_cur[r]);
        s_cur = s_nxt; b0n = b0nn; b1n = b1nn;
    }
    #pragma unroll
    for (int r = 0; r < 16; ++r) red[wid][r][lane] = accl[r];
    __syncthreads();
    if (wid == 0){
        #pragma unroll
        for (int r = 0; r < 16; ++r){
            float v = red[0][r][lane] + red[1][r][lane] + red[2][r][lane] + red[3][r][lane];
            #pragma unroll
            for (int off = 16; off >= 1; off >>= 1) v += __shfl_xor(v, off);
            if (l31 == 0)
                ls[(r & 3) + 8 * (r >> 2) + 4 * h] = 1.0f / v;
        }
    }
    __syncthreads();
    // fused scale: YQ2 tile-blocked [b][ntile][c][n] = bf16(YQ[c][n0+n] / l[n0+n])
    size_t obase = ((size_t)(b * 128 + ntile)) * 1024;
    #pragma unroll
    for (int p = 0; p < 4; ++p){
        int idx = (p << 8) + t;
        int c = idx >> 5, n = idx & 31;
        size_t g = (size_t)(b * 32 + c) * HW + n0 + n;
        YQ2[obase + idx] = f2bf(YQ[g] * ls[n]);
    }
}

// ------- K7: MFMA value pass (pipelined) + conv6 + residual -------------------
// b = blk & 7 so each XCD keeps one batch's Q1t/YQ2 streams L2-resident
__global__ __launch_bounds__(256, 4) void k_attn_mfma(
    const unsigned short* __restrict__ Q1t, const unsigned short* __restrict__ K2t,
    const unsigned short* __restrict__ YKt, const unsigned short* __restrict__ YQ2,
    const float* __restrict__ M2, const float* __restrict__ c6w, const float* __restrict__ c6b,
    const float* __restrict__ x, float* __restrict__ xout)
{
    __shared__ float red[4][16][64];
    int t = threadIdx.x, wid = t >> 6, lane = t & 63;
    int l31 = lane & 31, h = lane >> 5;
    int b = blockIdx.x & 7, mtile = blockIdx.x >> 3;
    int m0 = mtile * 32;
    size_t boff = (size_t)b * 131072;
    const unsigned short* qb = Q1t + boff;
    const unsigned short* kb = K2t + boff;

    bf16x8_t kb0 = ldb(kb + (size_t)(m0 + l31) * 32 + 8 * h);
    bf16x8_t kb1 = ldb(kb + (size_t)(m0 + l31) * 32 + 16 + 8 * h);

    f32x16_t oacc;
    #pragma unroll
    for (int r = 0; r < 16; ++r) oacc[r] = 0.f;

    const unsigned short* qp = qb + ((size_t)(wid << 10) + l31) * 32 + 8 * h;
    // YQ2 tile-blocked: [b][ntile][c=l31][n-in-tile]; wave wid starts at ntile=wid*32
    const unsigned short* yp = YQ2 + ((size_t)(b * 128 + (wid << 5)) * 32 + l31) * 32 + 8 * h;

    // prologue: tile 0 frags + S; tile 1 frags
    bf16x8_t a0 = ldb(qp), a1 = ldb(qp + 16);
    bf16x8_t y0 = ldb(yp), y1 = ldb(yp + 16);
    f32x16_t s_cur;
    #pragma unroll
    for (int r = 0; r < 16; ++r) s_cur[r] = 0.f;
    s_cur = mfma32(a0, kb0, s_cur);
    s_cur = mfma32(a1, kb1, s_cur);
    qp += 1024; yp += 1024;
    bf16x8_t a0n = ldb(qp), a1n = ldb(qp + 16);
    bf16x8_t y0n = ldb(yp), y1n = ldb(yp + 16);

    #pragma unroll 4
    for (int i = 0; i < 32; ++i){
        // S for tile i+1 while converting tile i
        f32x16_t s_nxt;
        #pragma unroll
        for (int r = 0; r < 16; ++r) s_nxt[r] = 0.f;
        __builtin_amdgcn_s_setprio(1);
        s_nxt = mfma32(a0n, kb0, s_nxt);
        s_nxt = mfma32(a1n, kb1, s_nxt);
        __builtin_amdgcn_s_setprio(0);
        // prefetch frags for tile i+2
        int adv = (i < 30) ? 1024 : 0;
        qp += adv; yp += adv;
        bf16x8_t a0nn = ldb(qp), a1nn = ldb(qp + 16);
        bf16x8_t y0nn = ldb(yp), y1nn = ldb(yp + 16);
        // E = exp2(S'); C-layout -> B-frag via permlane32_swap
        u32 P[8];
        #pragma unroll
        for (int tt = 0; tt < 8; ++tt)
            P[tt] = pk2(ex2(s_cur[2 * tt]), ex2(s_cur[2 * tt + 1]));
        bf16x8_t e0, e1;
        cd2bfrag(P, e0, e1);
        __builtin_amdgcn_s_setprio(1);
        oacc = mfma32(y0, e0, oacc);
        oacc = mfma32(y1, e1, oacc);
        __builtin_amdgcn_s_setprio(0);
        s_cur = s_nxt;
        a0n = a0nn; a1n = a1nn;
        y0 = y0n; y1 = y1n; y0n = y0nn; y1n = y1nn;
    }
    #pragma unroll
    for (int r = 0; r < 16; ++r) red[wid][r][lane] = oacc[r];
    __syncthreads();
    if (wid != 0) return;
    #pragma unroll
    for (int r = 0; r < 16; ++r)
        oacc[r] = red[0][r][lane] + red[1][r][lane] + red[2][r][lane] + red[3][r][lane];

    u32 P[8];
    #pragma unroll
    for (int tt = 0; tt < 8; ++tt) P[tt] = pk2(oacc[2 * tt], oacc[2 * tt + 1]);
    bf16x8_t xb0, xb1;
    cd2bfrag(P, xb0, xb1);

    const float* w1p = c6w + l31 * 64;
    const float* m2p = M2 + b * 1024 + l31 * 32;
    int cb0 = 8 * h, cb1 = 16 + 8 * h;
    castu wa0, wa1, ma0, ma1;
    wa0.u = (u32x4_t){ pk2(w1p[cb0], w1p[cb0+1]), pk2(w1p[cb0+2], w1p[cb0+3]),
                       pk2(w1p[cb0+4], w1p[cb0+5]), pk2(w1p[cb0+6], w1p[cb0+7]) };
    wa1.u = (u32x4_t){ pk2(w1p[cb1], w1p[cb1+1]), pk2(w1p[cb1+2], w1p[cb1+3]),
                       pk2(w1p[cb1+4], w1p[cb1+5]), pk2(w1p[cb1+6], w1p[cb1+7]) };
    ma0.u = (u32x4_t){ pk2(m2p[cb0], m2p[cb0+1]), pk2(m2p[cb0+2], m2p[cb0+3]),
                       pk2(m2p[cb0+4], m2p[cb0+5]), pk2(m2p[cb0+6], m2p[cb0+7]) };
    ma1.u = (u32x4_t){ pk2(m2p[cb1], m2p[cb1+1]), pk2(m2p[cb1+2], m2p[cb1+3]),
                       pk2(m2p[cb1+4], m2p[cb1+5]), pk2(m2p[cb1+6], m2p[cb1+7]) };
    const unsigned short* ykp = YKt + boff + (size_t)(m0 + l31) * 32;
    bf16x8_t ykb0 = ldb(ykp + 8 * h);
    bf16x8_t ykb1 = ldb(ykp + 16 + 8 * h);

    f32x16_t facc;
    #pragma unroll
    for (int r = 0; r < 16; ++r) facc[r] = c6b[(r & 3) + 8 * (r >> 2) + 4 * h];
    facc = mfma32(wa0.s, xb0, facc);
    facc = mfma32(wa1.s, xb1, facc);
    facc = mfma32(ma0.s, ykb0, facc);
    facc = mfma32(ma1.s, ykb1, facc);

    #pragma unroll
    for (int r = 0; r < 16; ++r){
        int o = (r & 3) + 8 * (r >> 2) + 4 * h;
        size_t gi = ((size_t)(b * 32 + o) << 12) + m0 + l31;
        xout[gi] = x[gi] + facc[r];
    }
}

// ---------------- K8: score conv + residual on y (LDS-staged) -----------------
__global__ __launch_bounds__(256) void k_score(
    const float* __restrict__ xout, const float* __restrict__ y,
    const float* __restrict__ sw, const float* __restrict__ sb,
    float* __restrict__ yout)
{
    __shared__ float xs[3][32][66];
    __shared__ float red[4][64];
    int tid = threadIdx.x;
    int b = blockIdx.x & 7, h = blockIdx.x >> 3;
    for (int i = 0; i < 24; ++i){
        int idx = i * 256 + tid;
        int w = idx & 63, ic = (idx >> 6) & 31, dr = idx >> 11;
        int hr = h + dr - 1;
        xs[dr][ic][1 + w] = (hr >= 0 && hr < 64) ? xout[((b * 32 + ic) << 12) + (hr << 6) + w] : 0.f;
    }
    if (tid < 96){ xs[tid >> 5][tid & 31][0] = 0.f; }
    else if (tid < 192){ int u = tid - 96; xs[u >> 5][u & 31][65] = 0.f; }
    __syncthreads();
    int w = tid & 63, icg = tid >> 6;
    float p = 0.f;
    #pragma unroll
    for (int i = 0; i < 8; ++i){
        int ic = icg * 8 + i;
        #pragma unroll
        for (int tap = 0; tap < 9; ++tap)
            p = fmaf(sw[ic * 9 + tap], xs[tap / 3][ic][w + tap % 3], p);
    }
    red[icg][w] = p;
    __syncthreads();
    if (tid < 64){
        int px = (h << 6) + tid;
        yout[b * HW + px] = y[b * HW + px] + sb[0]
                          + red[0][tid] + red[1][tid] + red[2][tid] + red[3][tid];
    }
}

extern "C" void kernel_launch(void* const* d_in, const int* in_sizes, int n_in,
                              void* d_out, int out_size, void* d_ws, size_t ws_size,
                              hipStream_t stream)
{
    (void)in_sizes; (void)n_in; (void)out_size; (void)ws_size;
    const float* x      = (const float*)d_in[0];
    const float* y      = (const float*)d_in[1];
    const float* conv_w = (const float*)d_in[2];
    const float* conv_b = (const float*)d_in[3];
    const float* score_w= (const float*)d_in[4];
    const float* score_b= (const float*)d_in[5];
    const float* c132_w = (const float*)d_in[6];
    const float* c132_b = (const float*)d_in[7];
    const float* q1w = (const float*)d_in[8];  const float* q1b = (const float*)d_in[9];
    const float* k1w = (const float*)d_in[10]; const float* k1b = (const float*)d_in[11];
    const float* q2w = (const float*)d_in[12]; const float* q2b = (const float*)d_in[13];
    const float* k2w = (const float*)d_in[14]; const float* k2b = (const float*)d_in[15];
    const float* q3w = (const float*)d_in[16]; const float* q3b = (const float*)d_in[17];
    const float* k3w = (const float*)d_in[18]; const float* k3b = (const float*)d_in[19];
    const float* c6w = (const float*)d_in[20]; const float* c6b = (const float*)d_in[21];

    float* ws = (float*)d_ws;
    const size_t SZ = 1048576;            // 8*32*4096
    float* Scp = ws;                      // 262144 f32
    float* M2  = ws + 262144;             // 8192 f32
    float* K1  = ws + 2 * SZ;             // 1M f32
    float* Q2  = ws + 3 * SZ;             // 1M f32
    float* YQf = ws + 4 * SZ;             // 1M f32
    unsigned short* Q1t = (unsigned short*)(ws + 5 * SZ);            // 1M bf16
    unsigned short* K2t = (unsigned short*)(ws + 5 * SZ + SZ / 2);   // 1M bf16
    unsigned short* YKt = (unsigned short*)(ws + 6 * SZ);            // 1M bf16
    unsigned short* YQ2 = (unsigned short*)(ws + 6 * SZ + SZ / 2);   // 1M bf16 (tile-blocked)

    float* xout = (float*)d_out;
    float* yout = xout + SZ;

    k_front_mfma<<<dim3(32, 8), 256, 0, stream>>>(
        x, y, conv_w, conv_b, c132_w, c132_b,
        q1w, q1b, k1w, k1b, q2w, q2b, k2w, k2b, q3w, q3b, k3w, k3b,
        K1, Q2, YQf, Q1t, K2t, YKt);
    k_chan_part<<<256, 256, 0, stream>>>(K1, Q2, Scp);
    k_chan_fin<<<8, 1024, 0, stream>>>(Scp, c6w, M2);
    k_stats_mfma<<<1024, 256, 0, stream>>>(Q1t, K2t, YQf, YQ2);
    k_attn_mfma<<<1024, 256, 0, stream>>>(Q1t, K2t, YKt, YQ2, M2, c6w, c6b, x, xout);
    k_score<<<512, 256, 0, stream>>>(xout, y, score_w, score_b, yout);
}